// Round 3
// baseline (640.621 us; speedup 1.0000x reference)
//
#include <hip/hip_runtime.h>
#include <math.h>

// ---------------------------------------------------------------------------
// Problem constants
#define SIZE 128
#define WIN 32
#define HALF 16
#define B 8
#define C 64
#define N (SIZE*SIZE)        // 16384
#define BCN 8388608          // B*C*N
#define BV 97                // box VALID output size (128-32+1)

// Output offsets (floats) — tuple order:
// feat1_apply, feat2_apply, grid1, grid2, feat1_edge, feat2_color,
// f1_attn, f2_attn, feat1, feat2
#define O_APPLY1   0
#define O_APPLY2   8388608
#define O_GRID1    16777216
#define O_GRID2    17039360
#define O_EDGEF    17301504
#define O_COLORF   25690112
#define O_ATTN1    34078720
#define O_ATTN2    34111488
#define O_FEAT1    34144256
#define O_FEAT2    42532864
// total 50921472 floats

// Workspace offsets (floats)
#define WS_C1      0         // 8*16384
#define WS_C2      131072
#define WS_COLSUM  262144    // 8*97*128 = 99328
#define WS_XY      361472    // 32 ints
#define WS_MOM     361600    // 8*9*16384 = 1179648
#define WS_EDGE    1541248   // 8*16384
#define WS_LOG1    1672320   // 32768
#define WS_LOG2    1705088   // 32768
#define WS_BN      1737856   // 256

#define NEGINF (-3.402823466e+38f)

typedef unsigned __int128 u128;

// ---------------------------------------------------------------------------
__global__ void k_init(float* __restrict__ p, int n) {
  int i = blockIdx.x * 256 + threadIdx.x;
  if (i < n) p[i] = 0.f;
}

// bilinear 64->128 upsample of both cams
__global__ __launch_bounds__(256) void k_resize_cam(
    const float* __restrict__ cam1, const float* __restrict__ cam2,
    float* __restrict__ c1, float* __restrict__ c2) {
  int idx = blockIdx.x * 256 + threadIdx.x;      // 2*131072
  int which = idx >> 17;
  int rem = idx & 131071;
  int b = rem >> 14, i = (rem >> 7) & 127, j = rem & 127;
  const float* s = (which ? cam2 : cam1) + b * 4096;
  float fy = fminf(fmaxf(0.5f * (float)i - 0.25f, 0.f), 63.f);
  float fx = fminf(fmaxf(0.5f * (float)j - 0.25f, 0.f), 63.f);
  int y0 = (int)fy; float ty = fy - (float)y0; int y1i = min(y0 + 1, 63);
  int x0 = (int)fx; float tx = fx - (float)x0; int x1i = min(x0 + 1, 63);
  float v00 = s[y0 * 64 + x0],  v01 = s[y0 * 64 + x1i];
  float v10 = s[y1i * 64 + x0], v11 = s[y1i * 64 + x1i];
  float v = (1.f - ty) * ((1.f - tx) * v00 + tx * v01)
          + ty * ((1.f - tx) * v10 + tx * v11);
  (which ? c2 : c1)[rem] = v;
}

// Kogge-Stone occluded fill: all bits of m reachable from g through
// contiguous 1-runs of m (horizontal, both directions). 128-bit row.
__device__ __forceinline__ u128 hfill(u128 g, u128 m) {
  u128 p = m;
  g |= p & (g << 1);  p &= p << 1;
  g |= p & (g << 2);  p &= p << 2;
  g |= p & (g << 4);  p &= p << 4;
  g |= p & (g << 8);  p &= p << 8;
  g |= p & (g << 16); p &= p << 16;
  g |= p & (g << 32); p &= p << 32;
  g |= p & (g << 64);
  p = m;
  g |= p & (g >> 1);  p &= p >> 1;
  g |= p & (g >> 2);  p &= p >> 2;
  g |= p & (g >> 4);  p &= p >> 4;
  g |= p & (g >> 8);  p &= p >> 8;
  g |= p & (g >> 16); p &= p >> 16;
  g |= p & (g >> 32); p &= p >> 32;
  g |= p & (g >> 64);
  return g;
}

// _locate_region per batch: LDS-staged argmax + gradient mask +
// row-parallel Kogge-Stone flood fill + bbox
__global__ __launch_bounds__(256) void k_locate(const float* __restrict__ c1,
                                                int* __restrict__ xy) {
  int b = blockIdx.x;
  const float* c = c1 + b * N;
  int tid = threadIdx.x;
  __shared__ float sc[N];                       // 64 KB cam tile
  __shared__ float sv[256]; __shared__ int si[256];
  __shared__ unsigned int maskw[512];
  __shared__ unsigned long long glo[128], ghi[128];
  __shared__ unsigned long long rowany[2];
  __shared__ int s_changed, s_xm, s_ym, s_ok;

  // ---- load tile into LDS (coalesced float4) + per-thread argmax
  float bv = NEGINF; int bi = 0;
  const float4* c4 = (const float4*)c;
  float4* sc4 = (float4*)sc;
  #pragma unroll
  for (int k = 0; k < 16; ++k) {
    int i4 = k * 256 + tid;
    float4 v = c4[i4];
    sc4[i4] = v;
    int base = i4 * 4;
    if (v.x > bv) { bv = v.x; bi = base; }
    if (v.y > bv) { bv = v.y; bi = base + 1; }
    if (v.z > bv) { bv = v.z; bi = base + 2; }
    if (v.w > bv) { bv = v.w; bi = base + 3; }
  }
  sv[tid] = bv; si[tid] = bi;
  __syncthreads();
  for (int s = 128; s; s >>= 1) {
    if (tid < s) {
      float ov = sv[tid + s]; int oi = si[tid + s];
      if (ov > sv[tid] || (ov == sv[tid] && oi < si[tid])) { sv[tid] = ov; si[tid] = oi; }
    }
    __syncthreads();
  }
  if (tid == 0) { s_xm = si[0] >> 7; s_ym = si[0] & 127; }

  // ---- gradient-magnitude mask, bit-packed (4 words/row), from LDS
  #pragma unroll
  for (int q = 0; q < 2; ++q) {
    int w = tid + q * 256;
    int row = w >> 2, cb = (w & 3) * 32;
    unsigned int m = 0;
    for (int bit = 0; bit < 32; ++bit) {
      int i = row, j = cb + bit;
      float gx_, gy_;
      if (i == 0)        gx_ = sc[128 + j] - sc[j];
      else if (i == 127) gx_ = sc[127 * 128 + j] - sc[126 * 128 + j];
      else               gx_ = 0.5f * (sc[(i + 1) * 128 + j] - sc[(i - 1) * 128 + j]);
      if (j == 0)        gy_ = sc[i * 128 + 1] - sc[i * 128];
      else if (j == 127) gy_ = sc[i * 128 + 127] - sc[i * 128 + 126];
      else               gy_ = 0.5f * (sc[i * 128 + j + 1] - sc[i * 128 + j - 1]);
      if (hypotf(gx_, gy_) < 0.2f) m |= (1u << bit);
    }
    maskw[w] = m;
  }
  __syncthreads();
  if (tid == 0) {
    int w = (s_xm << 2) + (s_ym >> 5), bit = s_ym & 31;
    s_ok = (maskw[w] >> bit) & 1;
  }
  __syncthreads();

  // ---- flood fill: one thread per row, 128-bit row masks
  int r = tid;
  u128 m = 0, g = 0;
  if (tid < 128) {
    m = ((u128)maskw[r * 4])
      | ((u128)maskw[r * 4 + 1] << 32)
      | ((u128)maskw[r * 4 + 2] << 64)
      | ((u128)maskw[r * 4 + 3] << 96);
    if (s_ok && r == s_xm) g = ((u128)1) << s_ym;
    g = hfill(g, m);
  }
  for (;;) {
    if (tid == 0) s_changed = 0;
    if (tid < 128) { glo[r] = (unsigned long long)g; ghi[r] = (unsigned long long)(g >> 64); }
    __syncthreads();
    if (tid < 128) {
      u128 gn = g;
      if (r > 0)   gn |= ((u128)glo[r - 1]) | ((u128)ghi[r - 1] << 64);
      if (r < 127) gn |= ((u128)glo[r + 1]) | ((u128)ghi[r + 1] << 64);
      gn &= m;
      gn = hfill(gn, m);
      if (gn != g) { g = gn; s_changed = 1; }
    }
    __syncthreads();
    if (!s_changed) break;
  }

  // ---- bbox: row extents via ballot, column extents via OR of rows
  if (tid < 128) {
    unsigned long long ba = __ballot(g != 0);   // wave-uniform branch
    if ((tid & 63) == 0) rowany[tid >> 6] = ba;
    glo[r] = (unsigned long long)g; ghi[r] = (unsigned long long)(g >> 64);
  }
  __syncthreads();
  if (tid == 0) {
    unsigned long long r0 = rowany[0], r1 = rowany[1];
    unsigned long long cl = 0, ch = 0;
    for (int i = 0; i < 128; ++i) { cl |= glo[i]; ch |= ghi[i]; }
    int rs = 0, re = 0, cs = 0, ce = 0;
    if (r0 | r1) {
      rs = r0 ? (__ffsll(r0) - 1) : 64 + (__ffsll(r1) - 1);
      re = r1 ? 128 - __clzll(r1) : 64 - __clzll(r0);
      cs = cl ? (__ffsll(cl) - 1) : 64 + (__ffsll(ch) - 1);
      ce = ch ? 128 - __clzll(ch) : 64 - __clzll(cl);
    }
    int x1, y1;
    if (s_ok) { x1 = (rs + re) >> 1; y1 = (cs + ce) >> 1; }
    else      { x1 = s_xm;           y1 = s_ym; }
    xy[b] = x1; xy[8 + b] = y1;
  }
}

// column sums (32 rows) of c2: colsum[b][r in 0..96][c in 0..127]
__global__ __launch_bounds__(256) void k_colsum(const float* __restrict__ c2,
                                                float* __restrict__ cs) {
  int idx = blockIdx.x * 256 + threadIdx.x;
  if (idx >= B * BV * 128) return;
  int cc = idx & 127, r = (idx >> 7) % BV, b = idx / (BV * 128);
  const float* s = c2 + b * N + cc;
  float acc = 0.f;
  #pragma unroll
  for (int dy = 0; dy < WIN; ++dy) acc += s[(r + dy) * 128];
  cs[idx] = acc;
}

// 32x32 box argmax on c2 -> x2,y2
__global__ __launch_bounds__(256) void k_boxargmax(const float* __restrict__ colsum,
                                                   int* __restrict__ xy) {
  int b = blockIdx.x, tid = threadIdx.x;
  const float* cs = colsum + b * BV * 128;
  float bv = NEGINF; int bi = 0;
  for (int p = tid; p < BV * BV; p += 256) {
    int r = p / BV, cc = p % BV;
    const float* row = cs + r * 128 + cc;
    float s = 0.f;
    #pragma unroll
    for (int dx = 0; dx < WIN; ++dx) s += row[dx];
    if (s > bv) { bv = s; bi = p; }
  }
  __shared__ float sv[256]; __shared__ int si[256];
  sv[tid] = bv; si[tid] = bi;
  __syncthreads();
  for (int s = 128; s; s >>= 1) {
    if (tid < s) {
      float ov = sv[tid + s]; int oi = si[tid + s];
      if (ov > sv[tid] || (ov == sv[tid] && oi < si[tid])) { sv[tid] = ov; si[tid] = oi; }
    }
    __syncthreads();
  }
  if (tid == 0) { xy[16 + b] = si[0] / BV + HALF; xy[24 + b] = si[0] % BV + HALF; }
}

// grids -> outputs 2,3
__global__ __launch_bounds__(256) void k_grids(const int* __restrict__ xy,
                                               float* __restrict__ g1, float* __restrict__ g2) {
  int idx = blockIdx.x * 256 + threadIdx.x;   // B*N
  int b = idx >> 14, h = (idx >> 7) & 127, w = idx & 127;
  float x1 = (float)xy[b], y1 = (float)xy[8 + b];
  float x2 = (float)xy[16 + b], y2 = (float)xy[24 + b];
  float bx = (2.f * (float)w + 1.f) / 128.f - 1.f;
  float by = (2.f * (float)h + 1.f) / 128.f - 1.f;
  float m1x = (x1 - x2) / 64.f, m1y = (y1 - y2) / 64.f;
  g1[idx * 2]     = bx + m1x; g1[idx * 2 + 1] = by + m1y;
  g2[idx * 2]     = bx - m1x; g2[idx * 2 + 1] = by - m1y;
}

// color moments of f_e fused with 512->128 resize, LDS-tiled.
// Block = (b, ch, 16x16 output tile); stage 66x66 input tile coalesced,
// then per-pixel window reads hit LDS instead of 16B-stride global
// (which wasted 75% of every cacheline).
__global__ __launch_bounds__(256) void k_moments(const float* __restrict__ fe,
                                                 float* __restrict__ mom) {
  int blk = blockIdx.x;                        // B*3*64
  int tile = blk & 63, ch = (blk >> 6) % 3, b = blk / 192;
  int ti0 = (tile >> 3) * 16, tj0 = (tile & 7) * 16;
  const float* src = fe + (size_t)(b * 3 + ch) * 262144;
  __shared__ float sx[66 * 66];
  int oy0 = 4 * ti0 - 1, ox0 = 4 * tj0 - 1;
  int tid = threadIdx.x;
  for (int l = tid; l < 66 * 66; l += 256) {
    int r = l / 66, cc = l % 66;
    int gy = oy0 + r, gx = ox0 + cc;
    sx[l] = (gy >= 0 && gy < 512 && gx >= 0 && gx < 512) ? src[gy * 512 + gx] : 0.f;
  }
  __syncthreads();
  int ii = tid >> 4, jj = tid & 15;
  int i = ti0 + ii, j = tj0 + jj;
  float s1a[6], s2a[6], s3a[6], s1b[6], s2b[6], s3b[6];
  #pragma unroll
  for (int t = 0; t < 6; ++t) {
    float a1 = 0, a2 = 0, a3 = 0, b1 = 0, b2 = 0, b3 = 0;
    int lx = 4 * jj + t;
    #pragma unroll
    for (int r = 0; r < 6; ++r) {
      float v = sx[(4 * ii + r) * 66 + lx];
      float v2 = v * v, v3 = v2 * v;
      if (r < 5) { a1 += v; a2 += v2; a3 += v3; }
      if (r > 0) { b1 += v; b2 += v2; b3 += v3; }
    }
    s1a[t] = a1; s2a[t] = a2; s3a[t] = a3;
    s1b[t] = b1; s2b[t] = b2; s3b[t] = b3;
  }
  float am = 0, av = 0, as = 0;
  #pragma unroll
  for (int py = 0; py < 2; ++py) {
    #pragma unroll
    for (int px = 0; px < 2; ++px) {
      float s1 = 0, s2 = 0, s3 = 0;
      #pragma unroll
      for (int t = 0; t < 5; ++t) {
        s1 += py ? s1b[px + t] : s1a[px + t];
        s2 += py ? s2b[px + t] : s2a[px + t];
        s3 += py ? s3b[px + t] : s3a[px + t];
      }
      float mean = s1 / 25.f;
      float var  = (s2 - 25.f * mean * mean) / 24.f;
      float m3   = (s3 - 3.f * mean * s2 + 50.f * mean * mean * mean) / 25.f;
      float sq   = sqrtf(fmaxf(var, 0.f));
      float skew = m3 / (sq * sq * sq + 1e-6f);
      am += mean; av += var; as += skew;
    }
  }
  int base = (b * 9 + ch) * N + i * 128 + j;
  mom[base]         = 0.25f * am;
  mom[base + 3 * N] = 0.25f * av;
  mom[base + 6 * N] = 0.25f * as;
}

// edge extraction of f_g fused with resize, LDS-tiled.
// Stage the 3-channel SUM of the 66x66 input tile (coalesced), then the
// separable Gauss-deriv window reads hit LDS.
__global__ __launch_bounds__(256) void k_edge(const float* __restrict__ fg,
                                              float* __restrict__ edge) {
  int blk = blockIdx.x;                        // B*64
  int tile = blk & 63, b = blk >> 6;
  int ti0 = (tile >> 3) * 16, tj0 = (tile & 7) * 16;
  const float* s0 = fg + (size_t)b * 3 * 262144;
  __shared__ float sx[66 * 66];
  int oy0 = 4 * ti0 - 1, ox0 = 4 * tj0 - 1;
  int tid = threadIdx.x;
  for (int l = tid; l < 66 * 66; l += 256) {
    int r = l / 66, cc = l % 66;
    int gy = oy0 + r, gx = ox0 + cc;
    float v = 0.f;
    if (gy >= 0 && gy < 512 && gx >= 0 && gx < 512) {
      int o = gy * 512 + gx;
      v = s0[o] + s0[262144 + o] + s0[524288 + o];
    }
    sx[l] = v;
  }
  __syncthreads();
  int ii = tid >> 4, jj = tid & 15;
  int i = ti0 + ii, j = tj0 + jj;
  const float INV2PI = 0.15915494309189535f;
  float wg[5], ug[5];
  #pragma unroll
  for (int t = 0; t < 5; ++t) {
    float a = (float)t - 2.f;
    float e = expf(-0.5f * a * a);
    wg[t] = e; ug[t] = -a * e;
  }
  float rAa[6], rAb[6], rBa[6], rBb[6];
  #pragma unroll
  for (int t = 0; t < 6; ++t) {
    float aa = 0, ab = 0, ba = 0, bb = 0;
    int lx = 4 * jj + t;
    #pragma unroll
    for (int r = 0; r < 6; ++r) {
      float v = sx[(4 * ii + r) * 66 + lx];
      if (r < 5) { aa += v * wg[r]; ba += v * ug[r]; }
      if (r > 0) { ab += v * wg[r - 1]; bb += v * ug[r - 1]; }
    }
    rAa[t] = aa; rAb[t] = ab; rBa[t] = ba; rBb[t] = bb;
  }
  float acc = 0.f;
  #pragma unroll
  for (int py = 0; py < 2; ++py) {
    #pragma unroll
    for (int px = 0; px < 2; ++px) {
      float h = 0, v = 0;
      #pragma unroll
      for (int t = 0; t < 5; ++t) {
        float A  = py ? rAb[px + t] : rAa[px + t];
        float Bw = py ? rBb[px + t] : rBa[px + t];
        h += A * ug[t];
        v += Bw * wg[t];
      }
      h *= INV2PI; v *= INV2PI;
      acc += tanhf(sqrtf(h * h + v * v + 1e-8f));
    }
  }
  edge[b * N + i * 128 + j] = 0.25f * acc;
}

// feat1_edge = clip(conv3x3(edge(1ch), sum_i conv1_w) + b, 0, 6)
__global__ __launch_bounds__(256) void k_conv1(const float* __restrict__ edge,
                                               const float* __restrict__ w,
                                               const float* __restrict__ bias,
                                               float* __restrict__ out) {
  int b = blockIdx.x >> 6, tile = blockIdx.x & 63;
  int ti0 = (tile >> 3) * 16, tj0 = (tile & 7) * 16;
  __shared__ float et[18 * 18];
  __shared__ float ws1[64 * 12];                // rows padded 9->12 (16B aligned)
  int tid = threadIdx.x;
  for (int l = tid; l < 324; l += 256) {
    int r = l / 18, cc = l % 18;
    int gi = ti0 + r - 1, gj = tj0 + cc - 1;
    et[l] = (gi >= 0 && gi < 128 && gj >= 0 && gj < 128) ? edge[b * N + gi * 128 + gj] : 0.f;
  }
  for (int l = tid; l < 64 * 12; l += 256) {
    int o = l / 12, t = l % 12;
    ws1[l] = (t < 9) ? (w[o * 27 + t] + w[o * 27 + 9 + t] + w[o * 27 + 18 + t]) : 0.f;
  }
  __syncthreads();
  int i = tid >> 4, j = tid & 15;
  float win[12];
  #pragma unroll
  for (int dy = 0; dy < 3; ++dy)
    #pragma unroll
    for (int dx = 0; dx < 3; ++dx)
      win[dy * 3 + dx] = et[(i + dy) * 18 + (j + dx)];
  win[9] = 0.f; win[10] = 0.f; win[11] = 0.f;
  float* o = out + (size_t)b * C * N + (ti0 + i) * 128 + tj0 + j;
  for (int oc = 0; oc < C; ++oc) {
    const float4* wr = (const float4*)(ws1 + oc * 12);
    float acc = bias[oc];
    #pragma unroll
    for (int q = 0; q < 3; ++q) {
      float4 w4 = wr[q];
      acc += w4.x * win[4 * q] + w4.y * win[4 * q + 1]
           + w4.z * win[4 * q + 2] + w4.w * win[4 * q + 3];
    }
    o[oc * N] = fminf(fmaxf(acc, 0.f), 6.f);
  }
}

// feat2_color = conv3x3(moments 9ch) + b (no clip)
__global__ __launch_bounds__(256) void k_conv2(const float* __restrict__ mom,
                                               const float* __restrict__ w,
                                               const float* __restrict__ bias,
                                               float* __restrict__ out) {
  int b = blockIdx.x >> 6, tile = blockIdx.x & 63;
  int ti0 = (tile >> 3) * 16, tj0 = (tile & 7) * 16;
  __shared__ float mt[9 * 324];
  __shared__ float w2s[64 * 84];                // rows padded 81->84 (16B aligned)
  int tid = threadIdx.x;
  for (int l = tid; l < 9 * 324; l += 256) {
    int ic = l / 324, rem = l % 324, r = rem / 18, cc = rem % 18;
    int gi = ti0 + r - 1, gj = tj0 + cc - 1;
    mt[l] = (gi >= 0 && gi < 128 && gj >= 0 && gj < 128) ? mom[(b * 9 + ic) * N + gi * 128 + gj] : 0.f;
  }
  for (int l = tid; l < 64 * 84; l += 256) {
    int o = l / 84, t = l % 84;
    w2s[l] = (t < 81) ? w[o * 81 + t] : 0.f;
  }
  __syncthreads();
  int i = tid >> 4, j = tid & 15;
  float win[84];
  #pragma unroll
  for (int ic = 0; ic < 9; ++ic)
    #pragma unroll
    for (int dy = 0; dy < 3; ++dy)
      #pragma unroll
      for (int dx = 0; dx < 3; ++dx)
        win[ic * 9 + dy * 3 + dx] = mt[ic * 324 + (i + dy) * 18 + (j + dx)];
  win[81] = 0.f; win[82] = 0.f; win[83] = 0.f;
  float* o = out + (size_t)b * C * N + (ti0 + i) * 128 + tj0 + j;
  for (int oc = 0; oc < C; ++oc) {
    const float4* wr = (const float4*)(w2s + oc * 84);
    float acc = bias[oc];
    #pragma unroll
    for (int q = 0; q < 21; ++q) {
      float4 w4 = wr[q];
      acc += w4.x * win[4 * q] + w4.y * win[4 * q + 1]
           + w4.z * win[4 * q + 2] + w4.w * win[4 * q + 3];
    }
    o[oc * N] = acc;
  }
}

// logits[b][c][d] += sum over window of a_shifted[c] * bsrc[d]
// Both mode-0 and mode-1 in one dispatch (blockIdx.y selects).
__global__ __launch_bounds__(256) void k_logits(const float* __restrict__ aB1,
                                                const float* __restrict__ bB1,
                                                float* __restrict__ out1,
                                                const float* __restrict__ aB2,
                                                const float* __restrict__ bB2,
                                                float* __restrict__ out2,
                                                const int* __restrict__ xy) {
  int mode = blockIdx.y;
  const float* aBase = mode ? aB2 : aB1;
  const float* bBase = mode ? bB2 : bB1;
  float* out = mode ? out2 : out1;
  int b = blockIdx.x >> 4, sl = blockIdx.x & 15;
  int x1 = xy[b], y1 = xy[8 + b], x2 = xy[16 + b], y2 = xy[24 + b];
  int dyh, dxw, rlo, rhi, clo, chi;
  if (mode == 0) {
    dyh = y1 - y2; dxw = x1 - x2;
    rlo = max(x1 - HALF, 0); rhi = min(x1 + HALF, SIZE);
    clo = max(y1 - HALF, 0); chi = min(y1 + HALF, SIZE);
  } else {
    dyh = y2 - y1; dxw = x2 - x1;
    rlo = max(x2 - HALF, 0); rhi = min(x2 + HALF, SIZE);
    clo = max(y2 - HALF, 0); chi = min(y2 + HALF, SIZE);
  }
  int hlo = max(0, rlo - dyh), hhi = min(SIZE, rhi - dyh);
  int wlo = max(0, clo - dxw), whi = min(SIZE, chi - dxw);
  int wn = whi - wlo, hn = hhi - hlo;
  int npos = (wn > 0 && hn > 0) ? wn * hn : 0;
  if (sl * 64 >= npos) return;

  __shared__ float aS[64][65];
  __shared__ float bS[64][65];
  int tid = threadIdx.x;
  const float* aB = aBase + (size_t)b * C * N;
  const float* bB = bBase + (size_t)b * C * N;
  for (int l = tid; l < 4096; l += 256) {
    int ch = l >> 6, k = l & 63;
    int p = sl * 64 + k;
    float av = 0.f, bv = 0.f;
    if (p < npos) {
      int h = hlo + p / wn, w = wlo + p % wn;
      av = aB[ch * N + (h + dyh) * 128 + (w + dxw)];
      bv = bB[ch * N + h * 128 + w];
    }
    aS[ch][k] = av; bS[ch][k] = bv;
  }
  __syncthreads();
  int ci = (tid >> 4) << 2, di = (tid & 15) << 2;
  float acc[4][4] = {};
  #pragma unroll 4
  for (int k = 0; k < 64; ++k) {
    float a0 = aS[ci][k], a1 = aS[ci + 1][k], a2 = aS[ci + 2][k], a3 = aS[ci + 3][k];
    float b0 = bS[di][k], b1 = bS[di + 1][k], b2 = bS[di + 2][k], b3 = bS[di + 3][k];
    acc[0][0] += a0 * b0; acc[0][1] += a0 * b1; acc[0][2] += a0 * b2; acc[0][3] += a0 * b3;
    acc[1][0] += a1 * b0; acc[1][1] += a1 * b1; acc[1][2] += a1 * b2; acc[1][3] += a1 * b3;
    acc[2][0] += a2 * b0; acc[2][1] += a2 * b1; acc[2][2] += a2 * b2; acc[2][3] += a2 * b3;
    acc[3][0] += a3 * b0; acc[3][1] += a3 * b1; acc[3][2] += a3 * b2; acc[3][3] += a3 * b3;
  }
  float* o = out + b * 4096;
  #pragma unroll
  for (int u = 0; u < 4; ++u)
    #pragma unroll
    for (int v = 0; v < 4; ++v)
      atomicAdd(&o[(ci + u) * 64 + (di + v)], acc[u][v]);
}

// softmax over last dim (64) of both logit tensors
__global__ void k_softmax(const float* __restrict__ l1, const float* __restrict__ l2,
                          float* __restrict__ o6, float* __restrict__ o7) {
  int row = blockIdx.x;            // 0..511
  const float* src = blockIdx.y ? l2 : l1;
  float* dst = blockIdx.y ? o7 : o6;
  int lane = threadIdx.x;
  float v = src[row * 64 + lane];
  float mx = v;
  for (int off = 32; off; off >>= 1) mx = fmaxf(mx, __shfl_xor(mx, off));
  float e = expf(v - mx);
  float s = e;
  for (int off = 32; off; off >>= 1) s += __shfl_xor(s, off);
  dst[row * 64 + lane] = e / s;
}

// feat_apply_pre[b][c][n] = sum_d attn[b][c][d] * src[b][d][n]
// attn addresses are wave-uniform -> read float4 directly from global
// (compiler scalarizes to s_load / L1 hits); no LDS staging, no barrier.
__global__ __launch_bounds__(256) void k_apply(const float* __restrict__ a1,
                                               const float* __restrict__ s1_,
                                               float* __restrict__ d1,
                                               const float* __restrict__ a2,
                                               const float* __restrict__ s2_,
                                               float* __restrict__ d2) {
  const float* attn; const float* src; float* dst;
  if (blockIdx.y == 0) { attn = a1; src = s1_; dst = d1; }
  else                 { attn = a2; src = s2_; dst = d2; }
  int b = blockIdx.x >> 6, chunk = blockIdx.x & 63;
  int n0 = chunk * 256 + threadIdx.x;
  const float* s = src + (size_t)b * C * N + n0;
  float v[64];
  #pragma unroll
  for (int d = 0; d < 64; ++d) v[d] = s[d * N];
  const float4* at4 = (const float4*)(attn + b * 4096);
  float* o = dst + (size_t)b * C * N + n0;
  for (int c = 0; c < 64; ++c) {
    float acc = 0.f;
    #pragma unroll
    for (int q = 0; q < 16; ++q) {
      float4 w4 = at4[c * 16 + q];
      acc += w4.x * v[4 * q] + w4.y * v[4 * q + 1] + w4.z * v[4 * q + 2] + w4.w * v[4 * q + 3];
    }
    o[c * N] = acc;
  }
}

// ---------------------------------------------------------------------------
// BN stats, two-stage tree reduction.
__global__ __launch_bounds__(256) void k_bnstats1(const float* __restrict__ t0,
                                                  const float* __restrict__ t1,
                                                  float* __restrict__ part) {
  int c = blockIdx.x, b = blockIdx.y, t = blockIdx.z;
  const float* src = (t ? t1 : t0) + (size_t)(b * C + c) * N;
  const float4* s4 = (const float4*)src;
  float s = 0.f, ss = 0.f;
  #pragma unroll
  for (int k = 0; k < 16; ++k) {              // 4096 float4 / 256 threads
    float4 v = s4[k * 256 + threadIdx.x];
    s  += v.x + v.y + v.z + v.w;
    ss += v.x * v.x + v.y * v.y + v.z * v.z + v.w * v.w;
  }
  for (int off = 32; off; off >>= 1) {
    s  += __shfl_xor(s, off);
    ss += __shfl_xor(ss, off);
  }
  __shared__ float as[4], ass[4];
  int wave = threadIdx.x >> 6;
  if ((threadIdx.x & 63) == 0) { as[wave] = s; ass[wave] = ss; }
  __syncthreads();
  if (threadIdx.x == 0) {
    int idx = (t * C + c) * B + b;
    part[idx]        = as[0] + as[1] + as[2] + as[3];
    part[1024 + idx] = ass[0] + ass[1] + ass[2] + ass[3];
  }
}

__global__ void k_bnstats2(const float* __restrict__ part, float* __restrict__ stats) {
  int i = threadIdx.x;                         // 0..127
  int t = i >> 6, c = i & 63;
  float s = 0.f, ss = 0.f;
  #pragma unroll
  for (int b = 0; b < B; ++b) {
    int idx = (t * C + c) * B + b;
    s  += part[idx];
    ss += part[1024 + idx];
  }
  float mean = s / 131072.f;
  float var  = ss / 131072.f - mean * mean;
  stats[t * 128 + c]      = mean;
  stats[t * 128 + 64 + c] = 1.f / sqrtf(var + 1e-5f);
}

__global__ __launch_bounds__(256) void k_bnapply(float* __restrict__ t0, float* __restrict__ t1,
                                                 const float* __restrict__ stats,
                                                 const float* __restrict__ bw,
                                                 const float* __restrict__ bb) {
  int e = blockIdx.x * 256 + threadIdx.x;       // 0..BCN-1
  int t = blockIdx.y;
  float* p = t ? t1 : t0;
  int c = (e >> 14) & 63;
  float m = stats[t * 128 + c], r = stats[t * 128 + 64 + c];
  float y = (p[e] - m) * r * bw[c] + bb[c];
  p[e] = fminf(fmaxf(y, 0.f), 6.f);
}

// both feat copies in one kernel (replaces 2x hipMemcpyAsync D2D)
__global__ __launch_bounds__(256) void k_copy2(const float4* __restrict__ s1, float4* __restrict__ d1,
                                               const float4* __restrict__ s2, float4* __restrict__ d2) {
  int i = blockIdx.x * 256 + threadIdx.x;       // BCN/4
  d1[i] = s1[i];
  d2[i] = s2[i];
}

// ---------------------------------------------------------------------------
extern "C" void kernel_launch(void* const* d_in, const int* in_sizes, int n_in,
                              void* d_out, int out_size, void* d_ws, size_t ws_size,
                              hipStream_t stream) {
  const float* feat1   = (const float*)d_in[1];
  const float* feat2   = (const float*)d_in[2];
  const float* cam1    = (const float*)d_in[3];
  const float* cam2    = (const float*)d_in[4];
  const float* f_g     = (const float*)d_in[5];
  const float* f_e     = (const float*)d_in[6];
  const float* conv1_w = (const float*)d_in[7];
  const float* conv1_b = (const float*)d_in[8];
  const float* conv2_w = (const float*)d_in[9];
  const float* conv2_b = (const float*)d_in[10];
  const float* bn_w    = (const float*)d_in[11];
  const float* bn_b    = (const float*)d_in[12];

  float* out = (float*)d_out;
  float* w = (float*)d_ws;
  int* xy = (int*)(w + WS_XY);

  float* o0 = out + O_APPLY1;
  float* o1 = out + O_APPLY2;
  float* o2 = out + O_GRID1;
  float* o3 = out + O_GRID2;
  float* o4 = out + O_EDGEF;
  float* o5 = out + O_COLORF;
  float* o6 = out + O_ATTN1;
  float* o7 = out + O_ATTN2;
  float* o8 = out + O_FEAT1;
  float* o9 = out + O_FEAT2;

  // zero the atomic logits accumulators (LOG1 + LOG2 contiguous)
  k_init<<<(65536 + 255) / 256, 256, 0, stream>>>(w + WS_LOG1, 65536);

  k_resize_cam<<<1024, 256, 0, stream>>>(cam1, cam2, w + WS_C1, w + WS_C2);
  k_locate<<<B, 256, 0, stream>>>(w + WS_C1, xy);
  k_colsum<<<(B * BV * 128 + 255) / 256, 256, 0, stream>>>(w + WS_C2, w + WS_COLSUM);
  k_boxargmax<<<B, 256, 0, stream>>>(w + WS_COLSUM, xy);
  k_grids<<<B * N / 256, 256, 0, stream>>>(xy, o2, o3);

  k_moments<<<B * 3 * 64, 256, 0, stream>>>(f_e, w + WS_MOM);
  k_edge<<<B * 64, 256, 0, stream>>>(f_g, w + WS_EDGE);
  k_conv1<<<B * 64, 256, 0, stream>>>(w + WS_EDGE, conv1_w, conv1_b, o4);
  k_conv2<<<B * 64, 256, 0, stream>>>(w + WS_MOM, conv2_w, conv2_b, o5);

  k_copy2<<<BCN / 4 / 256, 256, 0, stream>>>((const float4*)feat1, (float4*)o8,
                                             (const float4*)feat2, (float4*)o9);

  // logits1 = f1m . feat2 ; logits2 = f2m . feat1  (one dispatch, 2 modes)
  k_logits<<<dim3(B * 16, 2), 256, 0, stream>>>(o4, feat2, w + WS_LOG1,
                                                o5, feat1, w + WS_LOG2, xy);

  k_softmax<<<dim3(B * C, 2), 64, 0, stream>>>(w + WS_LOG1, w + WS_LOG2, o6, o7);

  // feat1_apply = f2_attn @ feat1 ; feat2_apply = f1_attn @ feat2
  k_apply<<<dim3(B * 64, 2), 256, 0, stream>>>(o7, feat1, o0, o6, feat2, o1);

  // BN stats: two-stage tree (WS_LOG1 is dead after k_softmax)
  k_bnstats1<<<dim3(C, B, 2), 256, 0, stream>>>(o0, o1, w + WS_LOG1);
  k_bnstats2<<<1, 128, 0, stream>>>(w + WS_LOG1, w + WS_BN);

  k_bnapply<<<dim3(BCN / 256, 2), 256, 0, stream>>>(o0, o1, w + WS_BN, bn_w, bn_b);
}

// Round 4
// 635.607 us; speedup vs baseline: 1.0079x; 1.0079x over previous
//
#include <hip/hip_runtime.h>
#include <math.h>

// ---------------------------------------------------------------------------
// Problem constants
#define SIZE 128
#define WIN 32
#define HALF 16
#define B 8
#define C 64
#define N (SIZE*SIZE)        // 16384
#define BCN 8388608          // B*C*N
#define BV 97                // box VALID output size (128-32+1)

// Output offsets (floats)
#define O_APPLY1   0
#define O_APPLY2   8388608
#define O_GRID1    16777216
#define O_GRID2    17039360
#define O_EDGEF    17301504
#define O_COLORF   25690112
#define O_ATTN1    34078720
#define O_ATTN2    34111488
#define O_FEAT1    34144256
#define O_FEAT2    42532864

// Workspace offsets (floats)
// [0 .. 131072)            : bn partials (s at 0, ss at 65536)  -- written by k_applyst
// WS_XY                    : 32 ints
// WS_MOM                   : moments (k_prep->k_conv12), then logits partials (1M floats)
// WS_EDGE                  : edge buffer
// WS_BN                    : stats
#define WS_BNP     0
#define WS_XY      361472
#define WS_MOM     361600    // 1179648 floats available
#define WS_EDGE    1541248   // 131072
#define WS_BN      1737856   // 256

#define NEGINF (-3.402823466e+38f)

typedef unsigned __int128 u128;

// ---------------------------------------------------------------------------
// Kogge-Stone occluded fill (horizontal, 128-bit row)
__device__ __forceinline__ u128 hfill(u128 g, u128 m) {
  u128 p = m;
  g |= p & (g << 1);  p &= p << 1;
  g |= p & (g << 2);  p &= p << 2;
  g |= p & (g << 4);  p &= p << 4;
  g |= p & (g << 8);  p &= p << 8;
  g |= p & (g << 16); p &= p << 16;
  g |= p & (g << 32); p &= p << 32;
  g |= p & (g << 64);
  p = m;
  g |= p & (g >> 1);  p &= p >> 1;
  g |= p & (g >> 2);  p &= p >> 2;
  g |= p & (g >> 4);  p &= p >> 4;
  g |= p & (g >> 8);  p &= p >> 8;
  g |= p & (g >> 16); p &= p >> 16;
  g |= p & (g >> 32); p &= p >> 32;
  g |= p & (g >> 64);
  return g;
}

// ---------------------------------------------------------------------------
// Fused front-end: per batch b (8 blocks):
//   bilinear 64->128 resize of cam1/cam2 (kept in LDS, never hits WS),
//   _locate_region (argmax + gradient mask + flood fill + bbox) -> x1,y1,
//   32x32 box argmax on cam2 -> x2,y2,
//   affine grids -> outputs grid1/grid2.
// LDS: 64KB c1 + 64KB c2 + ~6KB scratch = ~134KB (1 WG/CU; only 8 blocks).
__global__ __launch_bounds__(256) void k_front(
    const float* __restrict__ cam1, const float* __restrict__ cam2,
    int* __restrict__ xy, float* __restrict__ g1, float* __restrict__ g2) {
  int b = blockIdx.x, tid = threadIdx.x;
  __shared__ float sc[N];                       // c1; reused for colsum
  __shared__ float sc2[N];                      // c2
  __shared__ float sv[256]; __shared__ int si[256];
  __shared__ unsigned int maskw[512];
  __shared__ unsigned long long glo[128], ghi[128];
  __shared__ unsigned long long rowany[2];
  __shared__ int s_changed, s_xm, s_ym, s_ok;
  __shared__ int s_x1, s_y1, s_x2, s_y2;

  const float* src1 = cam1 + b * 4096;
  const float* src2 = cam2 + b * 4096;

  // ---- resize both cams into LDS + per-thread argmax of c1
  float bv = NEGINF; int bi = 0;
  for (int k = 0; k < 64; ++k) {
    int pix = k * 256 + tid;
    int i = pix >> 7, j = pix & 127;
    float fy = fminf(fmaxf(0.5f * (float)i - 0.25f, 0.f), 63.f);
    float fx = fminf(fmaxf(0.5f * (float)j - 0.25f, 0.f), 63.f);
    int y0 = (int)fy; float ty = fy - (float)y0; int y1i = min(y0 + 1, 63);
    int x0 = (int)fx; float tx = fx - (float)x0; int x1i = min(x0 + 1, 63);
    float a00 = src1[y0 * 64 + x0],  a01 = src1[y0 * 64 + x1i];
    float a10 = src1[y1i * 64 + x0], a11 = src1[y1i * 64 + x1i];
    float v1 = (1.f - ty) * ((1.f - tx) * a00 + tx * a01)
             + ty * ((1.f - tx) * a10 + tx * a11);
    float c00 = src2[y0 * 64 + x0],  c01 = src2[y0 * 64 + x1i];
    float c10 = src2[y1i * 64 + x0], c11 = src2[y1i * 64 + x1i];
    float v2 = (1.f - ty) * ((1.f - tx) * c00 + tx * c01)
             + ty * ((1.f - tx) * c10 + tx * c11);
    sc[pix] = v1; sc2[pix] = v2;
    if (v1 > bv) { bv = v1; bi = pix; }
  }
  sv[tid] = bv; si[tid] = bi;
  __syncthreads();
  for (int s = 128; s; s >>= 1) {
    if (tid < s) {
      float ov = sv[tid + s]; int oi = si[tid + s];
      if (ov > sv[tid] || (ov == sv[tid] && oi < si[tid])) { sv[tid] = ov; si[tid] = oi; }
    }
    __syncthreads();
  }
  if (tid == 0) { s_xm = si[0] >> 7; s_ym = si[0] & 127; }

  // ---- gradient-magnitude mask, bit-packed
  #pragma unroll
  for (int q = 0; q < 2; ++q) {
    int w = tid + q * 256;
    int row = w >> 2, cb = (w & 3) * 32;
    unsigned int m = 0;
    for (int bit = 0; bit < 32; ++bit) {
      int i = row, j = cb + bit;
      float gx_, gy_;
      if (i == 0)        gx_ = sc[128 + j] - sc[j];
      else if (i == 127) gx_ = sc[127 * 128 + j] - sc[126 * 128 + j];
      else               gx_ = 0.5f * (sc[(i + 1) * 128 + j] - sc[(i - 1) * 128 + j]);
      if (j == 0)        gy_ = sc[i * 128 + 1] - sc[i * 128];
      else if (j == 127) gy_ = sc[i * 128 + 127] - sc[i * 128 + 126];
      else               gy_ = 0.5f * (sc[i * 128 + j + 1] - sc[i * 128 + j - 1]);
      if (hypotf(gx_, gy_) < 0.2f) m |= (1u << bit);
    }
    maskw[w] = m;
  }
  __syncthreads();
  if (tid == 0) {
    int w = (s_xm << 2) + (s_ym >> 5), bit = s_ym & 31;
    s_ok = (maskw[w] >> bit) & 1;
  }
  __syncthreads();

  // ---- flood fill (row-parallel Kogge-Stone)
  int r = tid;
  u128 m = 0, g = 0;
  if (tid < 128) {
    m = ((u128)maskw[r * 4])
      | ((u128)maskw[r * 4 + 1] << 32)
      | ((u128)maskw[r * 4 + 2] << 64)
      | ((u128)maskw[r * 4 + 3] << 96);
    if (s_ok && r == s_xm) g = ((u128)1) << s_ym;
    g = hfill(g, m);
  }
  for (;;) {
    if (tid == 0) s_changed = 0;
    if (tid < 128) { glo[r] = (unsigned long long)g; ghi[r] = (unsigned long long)(g >> 64); }
    __syncthreads();
    if (tid < 128) {
      u128 gn = g;
      if (r > 0)   gn |= ((u128)glo[r - 1]) | ((u128)ghi[r - 1] << 64);
      if (r < 127) gn |= ((u128)glo[r + 1]) | ((u128)ghi[r + 1] << 64);
      gn &= m;
      gn = hfill(gn, m);
      if (gn != g) { g = gn; s_changed = 1; }
    }
    __syncthreads();
    if (!s_changed) break;
  }

  // ---- bbox
  if (tid < 128) {
    unsigned long long ba = __ballot(g != 0);
    if ((tid & 63) == 0) rowany[tid >> 6] = ba;
    glo[r] = (unsigned long long)g; ghi[r] = (unsigned long long)(g >> 64);
  }
  __syncthreads();
  if (tid == 0) {
    unsigned long long r0 = rowany[0], r1 = rowany[1];
    unsigned long long cl = 0, ch = 0;
    for (int i = 0; i < 128; ++i) { cl |= glo[i]; ch |= ghi[i]; }
    int rs = 0, re = 0, cs = 0, ce = 0;
    if (r0 | r1) {
      rs = r0 ? (__ffsll(r0) - 1) : 64 + (__ffsll(r1) - 1);
      re = r1 ? 128 - __clzll(r1) : 64 - __clzll(r0);
      cs = cl ? (__ffsll(cl) - 1) : 64 + (__ffsll(ch) - 1);
      ce = ch ? 128 - __clzll(ch) : 64 - __clzll(cl);
    }
    int x1, y1;
    if (s_ok) { x1 = (rs + re) >> 1; y1 = (cs + ce) >> 1; }
    else      { x1 = s_xm;           y1 = s_ym; }
    xy[b] = x1; xy[8 + b] = y1; s_x1 = x1; s_y1 = y1;
  }
  __syncthreads();

  // ---- colsum of c2 (32-row sums) into sc (c1 is dead now)
  for (int idx = tid; idx < BV * 128; idx += 256) {
    int rr = idx >> 7, cc = idx & 127;
    float acc = 0.f;
    #pragma unroll
    for (int dy = 0; dy < WIN; ++dy) acc += sc2[(rr + dy) * 128 + cc];
    sc[idx] = acc;
  }
  __syncthreads();

  // ---- 32x32 box argmax
  bv = NEGINF; bi = 0;
  for (int p = tid; p < BV * BV; p += 256) {
    int rr = p / BV, cc = p % BV;
    float s = 0.f;
    #pragma unroll
    for (int dx = 0; dx < WIN; ++dx) s += sc[rr * 128 + cc + dx];
    if (s > bv) { bv = s; bi = p; }
  }
  sv[tid] = bv; si[tid] = bi;
  __syncthreads();
  for (int s = 128; s; s >>= 1) {
    if (tid < s) {
      float ov = sv[tid + s]; int oi = si[tid + s];
      if (ov > sv[tid] || (ov == sv[tid] && oi < si[tid])) { sv[tid] = ov; si[tid] = oi; }
    }
    __syncthreads();
  }
  if (tid == 0) {
    int x2 = si[0] / BV + HALF, y2 = si[0] % BV + HALF;
    xy[16 + b] = x2; xy[24 + b] = y2; s_x2 = x2; s_y2 = y2;
  }
  __syncthreads();

  // ---- grids for this batch
  float x1f = (float)s_x1, y1f = (float)s_y1;
  float x2f = (float)s_x2, y2f = (float)s_y2;
  float m1x = (x1f - x2f) / 64.f, m1y = (y1f - y2f) / 64.f;
  float* g1b = g1 + (size_t)b * N * 2;
  float* g2b = g2 + (size_t)b * N * 2;
  for (int k = 0; k < 64; ++k) {
    int pix = k * 256 + tid;
    int h = pix >> 7, w = pix & 127;
    float bx = (2.f * (float)w + 1.f) / 128.f - 1.f;
    float by = (2.f * (float)h + 1.f) / 128.f - 1.f;
    g1b[pix * 2]     = bx + m1x; g1b[pix * 2 + 1] = by + m1y;
    g2b[pix * 2]     = bx - m1x; g2b[pix * 2 + 1] = by - m1y;
  }
}

// ---------------------------------------------------------------------------
// Fused moments + edge (both LDS-tiled 66x66; blockIdx.x selects)
__global__ __launch_bounds__(256) void k_prep(const float* __restrict__ fe,
                                              const float* __restrict__ fg,
                                              float* __restrict__ mom,
                                              float* __restrict__ edge) {
  __shared__ float sx[66 * 66];
  int tid = threadIdx.x;
  if (blockIdx.x < 1536) {
    // ---- moments
    int blk = blockIdx.x;
    int tile = blk & 63, ch = (blk >> 6) % 3, b = blk / 192;
    int ti0 = (tile >> 3) * 16, tj0 = (tile & 7) * 16;
    const float* src = fe + (size_t)(b * 3 + ch) * 262144;
    int oy0 = 4 * ti0 - 1, ox0 = 4 * tj0 - 1;
    for (int l = tid; l < 66 * 66; l += 256) {
      int r = l / 66, cc = l % 66;
      int gy = oy0 + r, gx = ox0 + cc;
      sx[l] = (gy >= 0 && gy < 512 && gx >= 0 && gx < 512) ? src[gy * 512 + gx] : 0.f;
    }
    __syncthreads();
    int ii = tid >> 4, jj = tid & 15;
    int i = ti0 + ii, j = tj0 + jj;
    float s1a[6], s2a[6], s3a[6], s1b[6], s2b[6], s3b[6];
    #pragma unroll
    for (int t = 0; t < 6; ++t) {
      float a1 = 0, a2 = 0, a3 = 0, b1 = 0, b2 = 0, b3 = 0;
      int lx = 4 * jj + t;
      #pragma unroll
      for (int r = 0; r < 6; ++r) {
        float v = sx[(4 * ii + r) * 66 + lx];
        float v2 = v * v, v3 = v2 * v;
        if (r < 5) { a1 += v; a2 += v2; a3 += v3; }
        if (r > 0) { b1 += v; b2 += v2; b3 += v3; }
      }
      s1a[t] = a1; s2a[t] = a2; s3a[t] = a3;
      s1b[t] = b1; s2b[t] = b2; s3b[t] = b3;
    }
    float am = 0, av = 0, as = 0;
    #pragma unroll
    for (int py = 0; py < 2; ++py) {
      #pragma unroll
      for (int px = 0; px < 2; ++px) {
        float s1 = 0, s2 = 0, s3 = 0;
        #pragma unroll
        for (int t = 0; t < 5; ++t) {
          s1 += py ? s1b[px + t] : s1a[px + t];
          s2 += py ? s2b[px + t] : s2a[px + t];
          s3 += py ? s3b[px + t] : s3a[px + t];
        }
        float mean = s1 / 25.f;
        float var  = (s2 - 25.f * mean * mean) / 24.f;
        float m3   = (s3 - 3.f * mean * s2 + 50.f * mean * mean * mean) / 25.f;
        float sq   = sqrtf(fmaxf(var, 0.f));
        float skew = m3 / (sq * sq * sq + 1e-6f);
        am += mean; av += var; as += skew;
      }
    }
    int base = (b * 9 + ch) * N + i * 128 + j;
    mom[base]         = 0.25f * am;
    mom[base + 3 * N] = 0.25f * av;
    mom[base + 6 * N] = 0.25f * as;
  } else {
    // ---- edge
    int blk = blockIdx.x - 1536;
    int tile = blk & 63, b = blk >> 6;
    int ti0 = (tile >> 3) * 16, tj0 = (tile & 7) * 16;
    const float* s0 = fg + (size_t)b * 3 * 262144;
    int oy0 = 4 * ti0 - 1, ox0 = 4 * tj0 - 1;
    for (int l = tid; l < 66 * 66; l += 256) {
      int r = l / 66, cc = l % 66;
      int gy = oy0 + r, gx = ox0 + cc;
      float v = 0.f;
      if (gy >= 0 && gy < 512 && gx >= 0 && gx < 512) {
        int o = gy * 512 + gx;
        v = s0[o] + s0[262144 + o] + s0[524288 + o];
      }
      sx[l] = v;
    }
    __syncthreads();
    int ii = tid >> 4, jj = tid & 15;
    int i = ti0 + ii, j = tj0 + jj;
    const float INV2PI = 0.15915494309189535f;
    float wg[5], ug[5];
    #pragma unroll
    for (int t = 0; t < 5; ++t) {
      float a = (float)t - 2.f;
      float e = expf(-0.5f * a * a);
      wg[t] = e; ug[t] = -a * e;
    }
    float rAa[6], rAb[6], rBa[6], rBb[6];
    #pragma unroll
    for (int t = 0; t < 6; ++t) {
      float aa = 0, ab = 0, ba = 0, bb = 0;
      int lx = 4 * jj + t;
      #pragma unroll
      for (int r = 0; r < 6; ++r) {
        float v = sx[(4 * ii + r) * 66 + lx];
        if (r < 5) { aa += v * wg[r]; ba += v * ug[r]; }
        if (r > 0) { ab += v * wg[r - 1]; bb += v * ug[r - 1]; }
      }
      rAa[t] = aa; rAb[t] = ab; rBa[t] = ba; rBb[t] = bb;
    }
    float acc = 0.f;
    #pragma unroll
    for (int py = 0; py < 2; ++py) {
      #pragma unroll
      for (int px = 0; px < 2; ++px) {
        float h = 0, v = 0;
        #pragma unroll
        for (int t = 0; t < 5; ++t) {
          float A  = py ? rAb[px + t] : rAa[px + t];
          float Bw = py ? rBb[px + t] : rBa[px + t];
          h += A * ug[t];
          v += Bw * wg[t];
        }
        h *= INV2PI; v *= INV2PI;
        acc += tanhf(sqrtf(h * h + v * v + 1e-8f));
      }
    }
    edge[b * N + i * 128 + j] = 0.25f * acc;
  }
}

// ---------------------------------------------------------------------------
// Fused conv1 (y=0) + conv2 (y=1); register-window formulation
__global__ __launch_bounds__(256) void k_conv12(
    const float* __restrict__ edge, const float* __restrict__ w1,
    const float* __restrict__ b1, float* __restrict__ o4,
    const float* __restrict__ mom, const float* __restrict__ w2,
    const float* __restrict__ b2, float* __restrict__ o5) {
  __shared__ float tin[9 * 324];
  __shared__ float wsm[64 * 84];
  int b = blockIdx.x >> 6, tile = blockIdx.x & 63;
  int ti0 = (tile >> 3) * 16, tj0 = (tile & 7) * 16;
  int tid = threadIdx.x;
  int i = tid >> 4, j = tid & 15;
  if (blockIdx.y == 0) {
    for (int l = tid; l < 324; l += 256) {
      int r = l / 18, cc = l % 18;
      int gi = ti0 + r - 1, gj = tj0 + cc - 1;
      tin[l] = (gi >= 0 && gi < 128 && gj >= 0 && gj < 128) ? edge[b * N + gi * 128 + gj] : 0.f;
    }
    for (int l = tid; l < 64 * 12; l += 256) {
      int o = l / 12, t = l % 12;
      wsm[l] = (t < 9) ? (w1[o * 27 + t] + w1[o * 27 + 9 + t] + w1[o * 27 + 18 + t]) : 0.f;
    }
    __syncthreads();
    float win[12];
    #pragma unroll
    for (int dy = 0; dy < 3; ++dy)
      #pragma unroll
      for (int dx = 0; dx < 3; ++dx)
        win[dy * 3 + dx] = tin[(i + dy) * 18 + (j + dx)];
    win[9] = 0.f; win[10] = 0.f; win[11] = 0.f;
    float* o = o4 + (size_t)b * C * N + (ti0 + i) * 128 + tj0 + j;
    for (int oc = 0; oc < C; ++oc) {
      const float4* wr = (const float4*)(wsm + oc * 12);
      float acc = b1[oc];
      #pragma unroll
      for (int q = 0; q < 3; ++q) {
        float4 w4 = wr[q];
        acc += w4.x * win[4 * q] + w4.y * win[4 * q + 1]
             + w4.z * win[4 * q + 2] + w4.w * win[4 * q + 3];
      }
      o[oc * N] = fminf(fmaxf(acc, 0.f), 6.f);
    }
  } else {
    for (int l = tid; l < 9 * 324; l += 256) {
      int ic = l / 324, rem = l % 324, r = rem / 18, cc = rem % 18;
      int gi = ti0 + r - 1, gj = tj0 + cc - 1;
      tin[l] = (gi >= 0 && gi < 128 && gj >= 0 && gj < 128) ? mom[(b * 9 + ic) * N + gi * 128 + gj] : 0.f;
    }
    for (int l = tid; l < 64 * 84; l += 256) {
      int o = l / 84, t = l % 84;
      wsm[l] = (t < 81) ? w2[o * 81 + t] : 0.f;
    }
    __syncthreads();
    float win[84];
    #pragma unroll
    for (int ic = 0; ic < 9; ++ic)
      #pragma unroll
      for (int dy = 0; dy < 3; ++dy)
        #pragma unroll
        for (int dx = 0; dx < 3; ++dx)
          win[ic * 9 + dy * 3 + dx] = tin[ic * 324 + (i + dy) * 18 + (j + dx)];
    win[81] = 0.f; win[82] = 0.f; win[83] = 0.f;
    float* o = o5 + (size_t)b * C * N + (ti0 + i) * 128 + tj0 + j;
    for (int oc = 0; oc < C; ++oc) {
      const float4* wr = (const float4*)(wsm + oc * 84);
      float acc = b2[oc];
      #pragma unroll
      for (int q = 0; q < 21; ++q) {
        float4 w4 = wr[q];
        acc += w4.x * win[4 * q] + w4.y * win[4 * q + 1]
             + w4.z * win[4 * q + 2] + w4.w * win[4 * q + 3];
      }
      o[oc * N] = acc;
    }
  }
}

// ---------------------------------------------------------------------------
// logits partial tiles (atomic-free): block (b,sl,mode) writes its own
// 64x64 partial into lg[((mode*8+b)*16+sl)*4096]. Skipped slices write 0.
__global__ __launch_bounds__(256) void k_logits(const float* __restrict__ aB1,
                                                const float* __restrict__ bB1,
                                                const float* __restrict__ aB2,
                                                const float* __restrict__ bB2,
                                                float* __restrict__ lg,
                                                const int* __restrict__ xy) {
  int mode = blockIdx.y;
  const float* aBase = mode ? aB2 : aB1;
  const float* bBase = mode ? bB2 : bB1;
  int b = blockIdx.x >> 4, sl = blockIdx.x & 15;
  int tid = threadIdx.x;
  int ci = (tid >> 4) << 2, di = (tid & 15) << 2;
  float* o = lg + (size_t)(((mode * 8 + b) * 16 + sl)) * 4096;

  int x1 = xy[b], y1 = xy[8 + b], x2 = xy[16 + b], y2 = xy[24 + b];
  int dyh, dxw, rlo, rhi, clo, chi;
  if (mode == 0) {
    dyh = y1 - y2; dxw = x1 - x2;
    rlo = max(x1 - HALF, 0); rhi = min(x1 + HALF, SIZE);
    clo = max(y1 - HALF, 0); chi = min(y1 + HALF, SIZE);
  } else {
    dyh = y2 - y1; dxw = x2 - x1;
    rlo = max(x2 - HALF, 0); rhi = min(x2 + HALF, SIZE);
    clo = max(y2 - HALF, 0); chi = min(y2 + HALF, SIZE);
  }
  int hlo = max(0, rlo - dyh), hhi = min(SIZE, rhi - dyh);
  int wlo = max(0, clo - dxw), whi = min(SIZE, chi - dxw);
  int wn = whi - wlo, hn = hhi - hlo;
  int npos = (wn > 0 && hn > 0) ? wn * hn : 0;
  if (sl * 64 >= npos) {
    #pragma unroll
    for (int u = 0; u < 4; ++u)
      #pragma unroll
      for (int v = 0; v < 4; ++v)
        o[(ci + u) * 64 + (di + v)] = 0.f;
    return;
  }

  __shared__ float aS[64][65];
  __shared__ float bS[64][65];
  const float* aB = aBase + (size_t)b * C * N;
  const float* bB = bBase + (size_t)b * C * N;
  for (int l = tid; l < 4096; l += 256) {
    int ch = l >> 6, k = l & 63;
    int p = sl * 64 + k;
    float av = 0.f, bv = 0.f;
    if (p < npos) {
      int h = hlo + p / wn, w = wlo + p % wn;
      av = aB[ch * N + (h + dyh) * 128 + (w + dxw)];
      bv = bB[ch * N + h * 128 + w];
    }
    aS[ch][k] = av; bS[ch][k] = bv;
  }
  __syncthreads();
  float acc[4][4] = {};
  #pragma unroll 4
  for (int k = 0; k < 64; ++k) {
    float a0 = aS[ci][k], a1 = aS[ci + 1][k], a2 = aS[ci + 2][k], a3 = aS[ci + 3][k];
    float b0 = bS[di][k], b1v = bS[di + 1][k], b2v = bS[di + 2][k], b3 = bS[di + 3][k];
    acc[0][0] += a0 * b0; acc[0][1] += a0 * b1v; acc[0][2] += a0 * b2v; acc[0][3] += a0 * b3;
    acc[1][0] += a1 * b0; acc[1][1] += a1 * b1v; acc[1][2] += a1 * b2v; acc[1][3] += a1 * b3;
    acc[2][0] += a2 * b0; acc[2][1] += a2 * b1v; acc[2][2] += a2 * b2v; acc[2][3] += a2 * b3;
    acc[3][0] += a3 * b0; acc[3][1] += a3 * b1v; acc[3][2] += a3 * b2v; acc[3][3] += a3 * b3;
  }
  #pragma unroll
  for (int u = 0; u < 4; ++u)
    #pragma unroll
    for (int v = 0; v < 4; ++v)
      o[(ci + u) * 64 + (di + v)] = acc[u][v];
}

// softmax over last dim (64); sums the 16 slice partials first
__global__ void k_softmax(const float* __restrict__ lg,
                          float* __restrict__ o6, float* __restrict__ o7) {
  int row = blockIdx.x;            // 0..511 = b*64+c
  int mode = blockIdx.y;
  float* dst = mode ? o7 : o6;
  int b = row >> 6, c = row & 63;
  int lane = threadIdx.x;
  const float* base = lg + (size_t)((mode * 8 + b) * 16) * 4096 + c * 64 + lane;
  float v = 0.f;
  #pragma unroll
  for (int sl = 0; sl < 16; ++sl) v += base[sl * 4096];
  float mx = v;
  for (int off = 32; off; off >>= 1) mx = fmaxf(mx, __shfl_xor(mx, off));
  float e = expf(v - mx);
  float s = e;
  for (int off = 32; off; off >>= 1) s += __shfl_xor(s, off);
  dst[row * 64 + lane] = e / s;
}

// ---------------------------------------------------------------------------
// apply (attn @ feat) fused with BN-stats partial accumulation.
// bnp layout: s at [(t*64+c)*512 + blk], ss at +65536.
__global__ __launch_bounds__(256) void k_applyst(const float* __restrict__ a1,
                                                 const float* __restrict__ s1_,
                                                 float* __restrict__ d1,
                                                 const float* __restrict__ a2,
                                                 const float* __restrict__ s2_,
                                                 float* __restrict__ d2,
                                                 float* __restrict__ bnp) {
  const float* attn; const float* src; float* dst;
  int t = blockIdx.y;
  if (t == 0) { attn = a1; src = s1_; dst = d1; }
  else        { attn = a2; src = s2_; dst = d2; }
  int b = blockIdx.x >> 6, chunk = blockIdx.x & 63;
  int n0 = chunk * 256 + threadIdx.x;
  const float* s = src + (size_t)b * C * N + n0;
  float v[64];
  #pragma unroll
  for (int d = 0; d < 64; ++d) v[d] = s[d * N];
  const float4* at4 = (const float4*)(attn + b * 4096);
  float* o = dst + (size_t)b * C * N + n0;
  __shared__ float red[64][4], red2[64][4];
  int lane = threadIdx.x & 63, wave = threadIdx.x >> 6;
  for (int c = 0; c < 64; ++c) {
    float acc = 0.f;
    #pragma unroll
    for (int q = 0; q < 16; ++q) {
      float4 w4 = at4[c * 16 + q];
      acc += w4.x * v[4 * q] + w4.y * v[4 * q + 1] + w4.z * v[4 * q + 2] + w4.w * v[4 * q + 3];
    }
    o[c * N] = acc;
    float sr = acc, ssr = acc * acc;
    for (int off = 32; off; off >>= 1) {
      sr  += __shfl_xor(sr, off);
      ssr += __shfl_xor(ssr, off);
    }
    if (lane == 0) { red[c][wave] = sr; red2[c][wave] = ssr; }
  }
  __syncthreads();
  if (threadIdx.x < 64) {
    int c = threadIdx.x;
    float sr  = red[c][0] + red[c][1] + red[c][2] + red[c][3];
    float ssr = red2[c][0] + red2[c][1] + red2[c][2] + red2[c][3];
    int idx = (t * 64 + c) * 512 + blockIdx.x;
    bnp[idx]         = sr;
    bnp[65536 + idx] = ssr;
  }
}

// fold 512 block-partials per (t,c) -> mean/rstd
__global__ void k_bnstats2(const float* __restrict__ bnp, float* __restrict__ stats) {
  __shared__ float sr[128][4], ssr[128][4];
  int tid = threadIdx.x;                       // 0..511
  int combo = tid >> 2, q = tid & 3;           // combo = t*64+c
  float s = 0.f, ss = 0.f;
  for (int k = 0; k < 128; ++k) {
    int idx = combo * 512 + q * 128 + k;
    s  += bnp[idx];
    ss += bnp[65536 + idx];
  }
  sr[combo][q] = s; ssr[combo][q] = ss;
  __syncthreads();
  if (q == 0) {
    float S  = sr[combo][0] + sr[combo][1] + sr[combo][2] + sr[combo][3];
    float SS = ssr[combo][0] + ssr[combo][1] + ssr[combo][2] + ssr[combo][3];
    int t = combo >> 6, c = combo & 63;
    float mean = S / 131072.f;
    float var  = SS / 131072.f - mean * mean;
    stats[t * 128 + c]      = mean;
    stats[t * 128 + 64 + c] = 1.f / sqrtf(var + 1e-5f);
  }
}

// ---------------------------------------------------------------------------
// Fused feat copies + BN apply (float4 throughout)
__global__ __launch_bounds__(256) void k_final(
    const float4* __restrict__ f1, float4* __restrict__ o8,
    const float4* __restrict__ f2, float4* __restrict__ o9,
    float4* __restrict__ o0, float4* __restrict__ o1,
    const float* __restrict__ stats,
    const float* __restrict__ bw, const float* __restrict__ bb) {
  int i = blockIdx.x * 256 + threadIdx.x;       // 0..BCN/4-1
  int t = blockIdx.y;
  if (t == 0) o8[i] = f1[i]; else o9[i] = f2[i];
  float4* p = t ? o1 : o0;
  int c = (i >> 12) & 63;
  float m = stats[t * 128 + c], r = stats[t * 128 + 64 + c];
  float w_ = bw[c], b_ = bb[c];
  float4 v = p[i];
  v.x = fminf(fmaxf((v.x - m) * r * w_ + b_, 0.f), 6.f);
  v.y = fminf(fmaxf((v.y - m) * r * w_ + b_, 0.f), 6.f);
  v.z = fminf(fmaxf((v.z - m) * r * w_ + b_, 0.f), 6.f);
  v.w = fminf(fmaxf((v.w - m) * r * w_ + b_, 0.f), 6.f);
  p[i] = v;
}

// ---------------------------------------------------------------------------
extern "C" void kernel_launch(void* const* d_in, const int* in_sizes, int n_in,
                              void* d_out, int out_size, void* d_ws, size_t ws_size,
                              hipStream_t stream) {
  const float* feat1   = (const float*)d_in[1];
  const float* feat2   = (const float*)d_in[2];
  const float* cam1    = (const float*)d_in[3];
  const float* cam2    = (const float*)d_in[4];
  const float* f_g     = (const float*)d_in[5];
  const float* f_e     = (const float*)d_in[6];
  const float* conv1_w = (const float*)d_in[7];
  const float* conv1_b = (const float*)d_in[8];
  const float* conv2_w = (const float*)d_in[9];
  const float* conv2_b = (const float*)d_in[10];
  const float* bn_w    = (const float*)d_in[11];
  const float* bn_b    = (const float*)d_in[12];

  float* out = (float*)d_out;
  float* w = (float*)d_ws;
  int* xy = (int*)(w + WS_XY);

  float* o0 = out + O_APPLY1;
  float* o1 = out + O_APPLY2;
  float* o2 = out + O_GRID1;
  float* o3 = out + O_GRID2;
  float* o4 = out + O_EDGEF;
  float* o5 = out + O_COLORF;
  float* o6 = out + O_ATTN1;
  float* o7 = out + O_ATTN2;
  float* o8 = out + O_FEAT1;
  float* o9 = out + O_FEAT2;

  // 1. fused front-end (resize + locate + box argmax + grids)
  k_front<<<B, 256, 0, stream>>>(cam1, cam2, xy, o2, o3);

  // 2. fused moments + edge
  k_prep<<<2048, 256, 0, stream>>>(f_e, f_g, w + WS_MOM, w + WS_EDGE);

  // 3. fused conv1 + conv2
  k_conv12<<<dim3(B * 64, 2), 256, 0, stream>>>(w + WS_EDGE, conv1_w, conv1_b, o4,
                                                w + WS_MOM, conv2_w, conv2_b, o5);

  // 4. logits partials (atomic-free; WS_MOM is dead after conv2)
  k_logits<<<dim3(B * 16, 2), 256, 0, stream>>>(o4, feat2, o5, feat1,
                                                w + WS_MOM, xy);

  // 5. softmax (sums 16 partials per row)
  k_softmax<<<dim3(B * C, 2), 64, 0, stream>>>(w + WS_MOM, o6, o7);

  // 6. apply + bn-stats partials
  k_applyst<<<dim3(B * 64, 2), 256, 0, stream>>>(o7, feat1, o0, o6, feat2, o1,
                                                 w + WS_BNP);

  // 7. fold stats
  k_bnstats2<<<1, 512, 0, stream>>>(w + WS_BNP, w + WS_BN);

  // 8. fused feat copies + bn apply
  k_final<<<dim3(BCN / 4 / 256, 2), 256, 0, stream>>>(
      (const float4*)feat1, (float4*)o8, (const float4*)feat2, (float4*)o9,
      (float4*)o0, (float4*)o1, w + WS_BN, bn_w, bn_b);
}

// Round 5
// 631.496 us; speedup vs baseline: 1.0145x; 1.0065x over previous
//
#include <hip/hip_runtime.h>
#include <math.h>

// ---------------------------------------------------------------------------
// Problem constants
#define SIZE 128
#define WIN 32
#define HALF 16
#define B 8
#define C 64
#define N (SIZE*SIZE)        // 16384
#define BCN 8388608          // B*C*N
#define BV 97                // box VALID output size (128-32+1)

// Output offsets (floats)
#define O_APPLY1   0
#define O_APPLY2   8388608
#define O_GRID1    16777216
#define O_GRID2    17039360
#define O_EDGEF    17301504
#define O_COLORF   25690112
#define O_ATTN1    34078720
#define O_ATTN2    34111488
#define O_FEAT1    34144256
#define O_FEAT2    42532864

// Workspace offsets (floats)
#define WS_BNP     0         // bn partials: s at 0, ss at 65536
#define WS_XY      361472    // 32 ints
#define WS_MOM     361600    // moments, then logits partials (1M floats)
#define WS_EDGE    1541248   // 131072
#define WS_BN      1737856   // 256

#define NEGINF (-3.402823466e+38f)

typedef unsigned __int128 u128;

// ---------------------------------------------------------------------------
// Kogge-Stone occluded fill (horizontal, 128-bit row)
__device__ __forceinline__ u128 hfill(u128 g, u128 m) {
  u128 p = m;
  g |= p & (g << 1);  p &= p << 1;
  g |= p & (g << 2);  p &= p << 2;
  g |= p & (g << 4);  p &= p << 4;
  g |= p & (g << 8);  p &= p << 8;
  g |= p & (g << 16); p &= p << 16;
  g |= p & (g << 32); p &= p << 32;
  g |= p & (g << 64);
  p = m;
  g |= p & (g >> 1);  p &= p >> 1;
  g |= p & (g >> 2);  p &= p >> 2;
  g |= p & (g >> 4);  p &= p >> 4;
  g |= p & (g >> 8);  p &= p >> 8;
  g |= p & (g >> 16); p &= p >> 16;
  g |= p & (g >> 32); p &= p >> 32;
  g |= p & (g >> 64);
  return g;
}

// ---------------------------------------------------------------------------
// Fused front-end, per batch b (8 blocks):
//   resize cams into LDS, locate-region, box argmax, grids.
// Rewritten hot spots (was 145us, 528K bank-conflict cycles):
//  - gradient mask via per-pixel predicate + __ballot (stride-1 LDS reads,
//    conflict-free; replaces 32-way-conflict bit loop)
//  - flood fill in ONE wave: lane l owns rows 2l,2l+1 as u128; vertical
//    exchange via 64-bit shfl, no __syncthreads in the iterate loop
__global__ __launch_bounds__(256) void k_front(
    const float* __restrict__ cam1, const float* __restrict__ cam2,
    int* __restrict__ xy, float* __restrict__ g1, float* __restrict__ g2) {
  int b = blockIdx.x, tid = threadIdx.x;
  __shared__ float sc[N];                       // c1 (reused for colsum)
  __shared__ float sc2[N];                      // c2
  __shared__ float sv[256]; __shared__ int si[256];
  __shared__ unsigned long long mask64[256];    // 2 u64 per row
  __shared__ int s_xm, s_ym, s_ok;
  __shared__ int s_x1, s_y1, s_x2, s_y2;

  const float* src1 = cam1 + b * 4096;
  const float* src2 = cam2 + b * 4096;

  // ---- resize both cams into LDS + per-thread argmax of c1
  float bv = NEGINF; int bi = 0;
  for (int k = 0; k < 64; ++k) {
    int pix = k * 256 + tid;
    int i = pix >> 7, j = pix & 127;
    float fy = fminf(fmaxf(0.5f * (float)i - 0.25f, 0.f), 63.f);
    float fx = fminf(fmaxf(0.5f * (float)j - 0.25f, 0.f), 63.f);
    int y0 = (int)fy; float ty = fy - (float)y0; int y1i = min(y0 + 1, 63);
    int x0 = (int)fx; float tx = fx - (float)x0; int x1i = min(x0 + 1, 63);
    float a00 = src1[y0 * 64 + x0],  a01 = src1[y0 * 64 + x1i];
    float a10 = src1[y1i * 64 + x0], a11 = src1[y1i * 64 + x1i];
    float v1 = (1.f - ty) * ((1.f - tx) * a00 + tx * a01)
             + ty * ((1.f - tx) * a10 + tx * a11);
    float c00 = src2[y0 * 64 + x0],  c01 = src2[y0 * 64 + x1i];
    float c10 = src2[y1i * 64 + x0], c11 = src2[y1i * 64 + x1i];
    float v2 = (1.f - ty) * ((1.f - tx) * c00 + tx * c01)
             + ty * ((1.f - tx) * c10 + tx * c11);
    sc[pix] = v1; sc2[pix] = v2;
    if (v1 > bv) { bv = v1; bi = pix; }
  }
  sv[tid] = bv; si[tid] = bi;
  __syncthreads();
  for (int s = 128; s; s >>= 1) {
    if (tid < s) {
      float ov = sv[tid + s]; int oi = si[tid + s];
      if (ov > sv[tid] || (ov == sv[tid] && oi < si[tid])) { sv[tid] = ov; si[tid] = oi; }
    }
    __syncthreads();
  }
  if (tid == 0) { s_xm = si[0] >> 7; s_ym = si[0] & 127; }
  __syncthreads();

  // ---- gradient-magnitude mask via ballot (conflict-free stride-1 reads)
  for (int k = 0; k < 64; ++k) {
    int pix = k * 256 + tid;
    int i = pix >> 7, j = pix & 127;
    float gx_, gy_;
    if (i == 0)        gx_ = sc[128 + j] - sc[j];
    else if (i == 127) gx_ = sc[127 * 128 + j] - sc[126 * 128 + j];
    else               gx_ = 0.5f * (sc[(i + 1) * 128 + j] - sc[(i - 1) * 128 + j]);
    if (j == 0)        gy_ = sc[i * 128 + 1] - sc[i * 128];
    else if (j == 127) gy_ = sc[i * 128 + 127] - sc[i * 128 + 126];
    else               gy_ = 0.5f * (sc[i * 128 + j + 1] - sc[i * 128 + j - 1]);
    bool pred = hypotf(gx_, gy_) < 0.2f;
    unsigned long long bal = __ballot(pred);
    // per wave: i and (j>>6) are lane-uniform; lane 0 stores the word
    if ((tid & 63) == 0) mask64[(i << 1) + (j >> 6)] = bal;
  }
  __syncthreads();
  if (tid == 0) {
    unsigned long long wdd = mask64[(s_xm << 1) + (s_ym >> 6)];
    s_ok = (int)((wdd >> (s_ym & 63)) & 1ull);
  }
  __syncthreads();

  // ---- flood fill: single wave, 2 rows per lane, shfl vertical exchange
  if (tid < 64) {
    int l = tid;
    u128 m0 = ((u128)mask64[4 * l])     | ((u128)mask64[4 * l + 1] << 64);
    u128 m1 = ((u128)mask64[4 * l + 2]) | ((u128)mask64[4 * l + 3] << 64);
    u128 g0 = 0, g1v = 0;
    if (s_ok && (s_xm >> 1) == l) {
      if ((s_xm & 1) == 0) g0  = ((u128)1) << s_ym;
      else                 g1v = ((u128)1) << s_ym;
    }
    g0  = hfill(g0 & m0, m0);
    g1v = hfill(g1v & m1, m1);
    for (;;) {
      unsigned long long ulo = __shfl_up((unsigned long long)g1v, 1);
      unsigned long long uhi = __shfl_up((unsigned long long)(g1v >> 64), 1);
      u128 up = (l > 0) ? (((u128)ulo) | ((u128)uhi << 64)) : (u128)0;
      unsigned long long dlo = __shfl_down((unsigned long long)g0, 1);
      unsigned long long dhi = __shfl_down((unsigned long long)(g0 >> 64), 1);
      u128 dn = (l < 63) ? (((u128)dlo) | ((u128)dhi << 64)) : (u128)0;
      u128 n0 = hfill((g0 | up | g1v) & m0, m0);
      u128 n1 = hfill((g1v | n0 | dn) & m1, m1);
      bool chg = (n0 != g0) || (n1 != g1v);
      g0 = n0; g1v = n1;
      if (!__any(chg)) break;
    }
    // bbox
    unsigned long long be = __ballot(g0 != 0);    // even rows 2l
    unsigned long long bo = __ballot(g1v != 0);   // odd rows 2l+1
    unsigned long long cl = (unsigned long long)(g0 | g1v);
    unsigned long long chh = (unsigned long long)((g0 | g1v) >> 64);
    for (int off = 32; off; off >>= 1) {
      cl  |= __shfl_xor(cl, off);
      chh |= __shfl_xor(chh, off);
    }
    if (l == 0) {
      int rs = 0, re = 0, cs = 0, ce = 0;
      if (be | bo) {
        int af = be ? (__ffsll(be) - 1) : 1000;
        int bf = bo ? (__ffsll(bo) - 1) : 1000;
        rs = min(af * 2, bf * 2 + 1);
        int al = be ? (63 - __clzll(be)) : -1000;
        int bl = bo ? (63 - __clzll(bo)) : -1000;
        re = max(al * 2, bl * 2 + 1) + 1;
        cs = cl ? (__ffsll(cl) - 1) : 64 + (__ffsll(chh) - 1);
        ce = chh ? 128 - __clzll(chh) : 64 - __clzll(cl);
      }
      int x1, y1;
      if (s_ok) { x1 = (rs + re) >> 1; y1 = (cs + ce) >> 1; }
      else      { x1 = s_xm;           y1 = s_ym; }
      xy[b] = x1; xy[8 + b] = y1; s_x1 = x1; s_y1 = y1;
    }
  }
  __syncthreads();

  // ---- colsum of c2 (32-row sums) into sc (c1 dead now)
  for (int idx = tid; idx < BV * 128; idx += 256) {
    int rr = idx >> 7, cc = idx & 127;
    float acc = 0.f;
    #pragma unroll
    for (int dy = 0; dy < WIN; ++dy) acc += sc2[(rr + dy) * 128 + cc];
    sc[idx] = acc;
  }
  __syncthreads();

  // ---- 32x32 box argmax
  bv = NEGINF; bi = 0;
  for (int p = tid; p < BV * BV; p += 256) {
    int rr = p / BV, cc = p % BV;
    float s = 0.f;
    #pragma unroll
    for (int dx = 0; dx < WIN; ++dx) s += sc[rr * 128 + cc + dx];
    if (s > bv) { bv = s; bi = p; }
  }
  sv[tid] = bv; si[tid] = bi;
  __syncthreads();
  for (int s = 128; s; s >>= 1) {
    if (tid < s) {
      float ov = sv[tid + s]; int oi = si[tid + s];
      if (ov > sv[tid] || (ov == sv[tid] && oi < si[tid])) { sv[tid] = ov; si[tid] = oi; }
    }
    __syncthreads();
  }
  if (tid == 0) {
    int x2 = si[0] / BV + HALF, y2 = si[0] % BV + HALF;
    xy[16 + b] = x2; xy[24 + b] = y2; s_x2 = x2; s_y2 = y2;
  }
  __syncthreads();

  // ---- grids for this batch
  float x1f = (float)s_x1, y1f = (float)s_y1;
  float x2f = (float)s_x2, y2f = (float)s_y2;
  float m1x = (x1f - x2f) / 64.f, m1y = (y1f - y2f) / 64.f;
  float* g1b = g1 + (size_t)b * N * 2;
  float* g2b = g2 + (size_t)b * N * 2;
  for (int k = 0; k < 64; ++k) {
    int pix = k * 256 + tid;
    int h = pix >> 7, w = pix & 127;
    float bx = (2.f * (float)w + 1.f) / 128.f - 1.f;
    float by = (2.f * (float)h + 1.f) / 128.f - 1.f;
    g1b[pix * 2]     = bx + m1x; g1b[pix * 2 + 1] = by + m1y;
    g2b[pix * 2]     = bx - m1x; g2b[pix * 2 + 1] = by - m1y;
  }
}

// ---------------------------------------------------------------------------
// Fused moments + edge (both LDS-tiled 66x66; blockIdx.x selects)
__global__ __launch_bounds__(256) void k_prep(const float* __restrict__ fe,
                                              const float* __restrict__ fg,
                                              float* __restrict__ mom,
                                              float* __restrict__ edge) {
  __shared__ float sx[66 * 66];
  int tid = threadIdx.x;
  if (blockIdx.x < 1536) {
    // ---- moments
    int blk = blockIdx.x;
    int tile = blk & 63, ch = (blk >> 6) % 3, b = blk / 192;
    int ti0 = (tile >> 3) * 16, tj0 = (tile & 7) * 16;
    const float* src = fe + (size_t)(b * 3 + ch) * 262144;
    int oy0 = 4 * ti0 - 1, ox0 = 4 * tj0 - 1;
    for (int l = tid; l < 66 * 66; l += 256) {
      int r = l / 66, cc = l % 66;
      int gy = oy0 + r, gx = ox0 + cc;
      sx[l] = (gy >= 0 && gy < 512 && gx >= 0 && gx < 512) ? src[gy * 512 + gx] : 0.f;
    }
    __syncthreads();
    int ii = tid >> 4, jj = tid & 15;
    int i = ti0 + ii, j = tj0 + jj;
    float s1a[6], s2a[6], s3a[6], s1b[6], s2b[6], s3b[6];
    #pragma unroll
    for (int t = 0; t < 6; ++t) {
      float a1 = 0, a2 = 0, a3 = 0, b1 = 0, b2 = 0, b3 = 0;
      int lx = 4 * jj + t;
      #pragma unroll
      for (int r = 0; r < 6; ++r) {
        float v = sx[(4 * ii + r) * 66 + lx];
        float v2 = v * v, v3 = v2 * v;
        if (r < 5) { a1 += v; a2 += v2; a3 += v3; }
        if (r > 0) { b1 += v; b2 += v2; b3 += v3; }
      }
      s1a[t] = a1; s2a[t] = a2; s3a[t] = a3;
      s1b[t] = b1; s2b[t] = b2; s3b[t] = b3;
    }
    float am = 0, av = 0, as = 0;
    #pragma unroll
    for (int py = 0; py < 2; ++py) {
      #pragma unroll
      for (int px = 0; px < 2; ++px) {
        float s1 = 0, s2 = 0, s3 = 0;
        #pragma unroll
        for (int t = 0; t < 5; ++t) {
          s1 += py ? s1b[px + t] : s1a[px + t];
          s2 += py ? s2b[px + t] : s2a[px + t];
          s3 += py ? s3b[px + t] : s3a[px + t];
        }
        float mean = s1 / 25.f;
        float var  = (s2 - 25.f * mean * mean) / 24.f;
        float m3   = (s3 - 3.f * mean * s2 + 50.f * mean * mean * mean) / 25.f;
        float sq   = sqrtf(fmaxf(var, 0.f));
        float skew = m3 / (sq * sq * sq + 1e-6f);
        am += mean; av += var; as += skew;
      }
    }
    int base = (b * 9 + ch) * N + i * 128 + j;
    mom[base]         = 0.25f * am;
    mom[base + 3 * N] = 0.25f * av;
    mom[base + 6 * N] = 0.25f * as;
  } else {
    // ---- edge
    int blk = blockIdx.x - 1536;
    int tile = blk & 63, b = blk >> 6;
    int ti0 = (tile >> 3) * 16, tj0 = (tile & 7) * 16;
    const float* s0 = fg + (size_t)b * 3 * 262144;
    int oy0 = 4 * ti0 - 1, ox0 = 4 * tj0 - 1;
    for (int l = tid; l < 66 * 66; l += 256) {
      int r = l / 66, cc = l % 66;
      int gy = oy0 + r, gx = ox0 + cc;
      float v = 0.f;
      if (gy >= 0 && gy < 512 && gx >= 0 && gx < 512) {
        int o = gy * 512 + gx;
        v = s0[o] + s0[262144 + o] + s0[524288 + o];
      }
      sx[l] = v;
    }
    __syncthreads();
    int ii = tid >> 4, jj = tid & 15;
    int i = ti0 + ii, j = tj0 + jj;
    const float INV2PI = 0.15915494309189535f;
    float wg[5], ug[5];
    #pragma unroll
    for (int t = 0; t < 5; ++t) {
      float a = (float)t - 2.f;
      float e = expf(-0.5f * a * a);
      wg[t] = e; ug[t] = -a * e;
    }
    float rAa[6], rAb[6], rBa[6], rBb[6];
    #pragma unroll
    for (int t = 0; t < 6; ++t) {
      float aa = 0, ab = 0, ba = 0, bb = 0;
      int lx = 4 * jj + t;
      #pragma unroll
      for (int r = 0; r < 6; ++r) {
        float v = sx[(4 * ii + r) * 66 + lx];
        if (r < 5) { aa += v * wg[r]; ba += v * ug[r]; }
        if (r > 0) { ab += v * wg[r - 1]; bb += v * ug[r - 1]; }
      }
      rAa[t] = aa; rAb[t] = ab; rBa[t] = ba; rBb[t] = bb;
    }
    float acc = 0.f;
    #pragma unroll
    for (int py = 0; py < 2; ++py) {
      #pragma unroll
      for (int px = 0; px < 2; ++px) {
        float h = 0, v = 0;
        #pragma unroll
        for (int t = 0; t < 5; ++t) {
          float A  = py ? rAb[px + t] : rAa[px + t];
          float Bw = py ? rBb[px + t] : rBa[px + t];
          h += A * ug[t];
          v += Bw * wg[t];
        }
        h *= INV2PI; v *= INV2PI;
        acc += tanhf(sqrtf(h * h + v * v + 1e-8f));
      }
    }
    edge[b * N + i * 128 + j] = 0.25f * acc;
  }
}

// ---------------------------------------------------------------------------
// Fused conv1 (y=0) + conv2 (y=1); register-window formulation
__global__ __launch_bounds__(256) void k_conv12(
    const float* __restrict__ edge, const float* __restrict__ w1,
    const float* __restrict__ b1, float* __restrict__ o4,
    const float* __restrict__ mom, const float* __restrict__ w2,
    const float* __restrict__ b2, float* __restrict__ o5) {
  __shared__ float tin[9 * 324];
  __shared__ float wsm[64 * 84];
  int b = blockIdx.x >> 6, tile = blockIdx.x & 63;
  int ti0 = (tile >> 3) * 16, tj0 = (tile & 7) * 16;
  int tid = threadIdx.x;
  int i = tid >> 4, j = tid & 15;
  if (blockIdx.y == 0) {
    for (int l = tid; l < 324; l += 256) {
      int r = l / 18, cc = l % 18;
      int gi = ti0 + r - 1, gj = tj0 + cc - 1;
      tin[l] = (gi >= 0 && gi < 128 && gj >= 0 && gj < 128) ? edge[b * N + gi * 128 + gj] : 0.f;
    }
    for (int l = tid; l < 64 * 12; l += 256) {
      int o = l / 12, t = l % 12;
      wsm[l] = (t < 9) ? (w1[o * 27 + t] + w1[o * 27 + 9 + t] + w1[o * 27 + 18 + t]) : 0.f;
    }
    __syncthreads();
    float win[12];
    #pragma unroll
    for (int dy = 0; dy < 3; ++dy)
      #pragma unroll
      for (int dx = 0; dx < 3; ++dx)
        win[dy * 3 + dx] = tin[(i + dy) * 18 + (j + dx)];
    win[9] = 0.f; win[10] = 0.f; win[11] = 0.f;
    float* o = o4 + (size_t)b * C * N + (ti0 + i) * 128 + tj0 + j;
    for (int oc = 0; oc < C; ++oc) {
      const float4* wr = (const float4*)(wsm + oc * 12);
      float acc = b1[oc];
      #pragma unroll
      for (int q = 0; q < 3; ++q) {
        float4 w4 = wr[q];
        acc += w4.x * win[4 * q] + w4.y * win[4 * q + 1]
             + w4.z * win[4 * q + 2] + w4.w * win[4 * q + 3];
      }
      o[oc * N] = fminf(fmaxf(acc, 0.f), 6.f);
    }
  } else {
    for (int l = tid; l < 9 * 324; l += 256) {
      int ic = l / 324, rem = l % 324, r = rem / 18, cc = rem % 18;
      int gi = ti0 + r - 1, gj = tj0 + cc - 1;
      tin[l] = (gi >= 0 && gi < 128 && gj >= 0 && gj < 128) ? mom[(b * 9 + ic) * N + gi * 128 + gj] : 0.f;
    }
    for (int l = tid; l < 64 * 84; l += 256) {
      int o = l / 84, t = l % 84;
      wsm[l] = (t < 81) ? w2[o * 81 + t] : 0.f;
    }
    __syncthreads();
    float win[84];
    #pragma unroll
    for (int ic = 0; ic < 9; ++ic)
      #pragma unroll
      for (int dy = 0; dy < 3; ++dy)
        #pragma unroll
        for (int dx = 0; dx < 3; ++dx)
          win[ic * 9 + dy * 3 + dx] = tin[ic * 324 + (i + dy) * 18 + (j + dx)];
    win[81] = 0.f; win[82] = 0.f; win[83] = 0.f;
    float* o = o5 + (size_t)b * C * N + (ti0 + i) * 128 + tj0 + j;
    for (int oc = 0; oc < C; ++oc) {
      const float4* wr = (const float4*)(wsm + oc * 84);
      float acc = b2[oc];
      #pragma unroll
      for (int q = 0; q < 21; ++q) {
        float4 w4 = wr[q];
        acc += w4.x * win[4 * q] + w4.y * win[4 * q + 1]
             + w4.z * win[4 * q + 2] + w4.w * win[4 * q + 3];
      }
      o[oc * N] = acc;
    }
  }
}

// ---------------------------------------------------------------------------
// logits partial tiles (atomic-free): block (b,sl,mode) writes its own
// 64x64 partial into lg[((mode*8+b)*16+sl)*4096]. Skipped slices write 0.
__global__ __launch_bounds__(256) void k_logits(const float* __restrict__ aB1,
                                                const float* __restrict__ bB1,
                                                const float* __restrict__ aB2,
                                                const float* __restrict__ bB2,
                                                float* __restrict__ lg,
                                                const int* __restrict__ xy) {
  int mode = blockIdx.y;
  const float* aBase = mode ? aB2 : aB1;
  const float* bBase = mode ? bB2 : bB1;
  int b = blockIdx.x >> 4, sl = blockIdx.x & 15;
  int tid = threadIdx.x;
  int ci = (tid >> 4) << 2, di = (tid & 15) << 2;
  float* o = lg + (size_t)(((mode * 8 + b) * 16 + sl)) * 4096;

  int x1 = xy[b], y1 = xy[8 + b], x2 = xy[16 + b], y2 = xy[24 + b];
  int dyh, dxw, rlo, rhi, clo, chi;
  if (mode == 0) {
    dyh = y1 - y2; dxw = x1 - x2;
    rlo = max(x1 - HALF, 0); rhi = min(x1 + HALF, SIZE);
    clo = max(y1 - HALF, 0); chi = min(y1 + HALF, SIZE);
  } else {
    dyh = y2 - y1; dxw = x2 - x1;
    rlo = max(x2 - HALF, 0); rhi = min(x2 + HALF, SIZE);
    clo = max(y2 - HALF, 0); chi = min(y2 + HALF, SIZE);
  }
  int hlo = max(0, rlo - dyh), hhi = min(SIZE, rhi - dyh);
  int wlo = max(0, clo - dxw), whi = min(SIZE, chi - dxw);
  int wn = whi - wlo, hn = hhi - hlo;
  int npos = (wn > 0 && hn > 0) ? wn * hn : 0;
  if (sl * 64 >= npos) {
    #pragma unroll
    for (int u = 0; u < 4; ++u)
      #pragma unroll
      for (int v = 0; v < 4; ++v)
        o[(ci + u) * 64 + (di + v)] = 0.f;
    return;
  }

  __shared__ float aS[64][65];
  __shared__ float bS[64][65];
  const float* aB = aBase + (size_t)b * C * N;
  const float* bB = bBase + (size_t)b * C * N;
  for (int l = tid; l < 4096; l += 256) {
    int ch = l >> 6, k = l & 63;
    int p = sl * 64 + k;
    float av = 0.f, bv = 0.f;
    if (p < npos) {
      int h = hlo + p / wn, w = wlo + p % wn;
      av = aB[ch * N + (h + dyh) * 128 + (w + dxw)];
      bv = bB[ch * N + h * 128 + w];
    }
    aS[ch][k] = av; bS[ch][k] = bv;
  }
  __syncthreads();
  float acc[4][4] = {};
  #pragma unroll 4
  for (int k = 0; k < 64; ++k) {
    float a0 = aS[ci][k], a1 = aS[ci + 1][k], a2 = aS[ci + 2][k], a3 = aS[ci + 3][k];
    float b0 = bS[di][k], b1v = bS[di + 1][k], b2v = bS[di + 2][k], b3 = bS[di + 3][k];
    acc[0][0] += a0 * b0; acc[0][1] += a0 * b1v; acc[0][2] += a0 * b2v; acc[0][3] += a0 * b3;
    acc[1][0] += a1 * b0; acc[1][1] += a1 * b1v; acc[1][2] += a1 * b2v; acc[1][3] += a1 * b3;
    acc[2][0] += a2 * b0; acc[2][1] += a2 * b1v; acc[2][2] += a2 * b2v; acc[2][3] += a2 * b3;
    acc[3][0] += a3 * b0; acc[3][1] += a3 * b1v; acc[3][2] += a3 * b2v; acc[3][3] += a3 * b3;
  }
  #pragma unroll
  for (int u = 0; u < 4; ++u)
    #pragma unroll
    for (int v = 0; v < 4; ++v)
      o[(ci + u) * 64 + (di + v)] = acc[u][v];
}

// softmax over last dim (64); sums the 16 slice partials first
__global__ void k_softmax(const float* __restrict__ lg,
                          float* __restrict__ o6, float* __restrict__ o7) {
  int row = blockIdx.x;            // 0..511 = b*64+c
  int mode = blockIdx.y;
  float* dst = mode ? o7 : o6;
  int b = row >> 6, c = row & 63;
  int lane = threadIdx.x;
  const float* base = lg + (size_t)((mode * 8 + b) * 16) * 4096 + c * 64 + lane;
  float v = 0.f;
  #pragma unroll
  for (int sl = 0; sl < 16; ++sl) v += base[sl * 4096];
  float mx = v;
  for (int off = 32; off; off >>= 1) mx = fmaxf(mx, __shfl_xor(mx, off));
  float e = expf(v - mx);
  float s = e;
  for (int off = 32; off; off >>= 1) s += __shfl_xor(s, off);
  dst[row * 64 + lane] = e / s;
}

// ---------------------------------------------------------------------------
// apply (attn @ feat) fused with BN-stats partial accumulation.
__global__ __launch_bounds__(256) void k_applyst(const float* __restrict__ a1,
                                                 const float* __restrict__ s1_,
                                                 float* __restrict__ d1,
                                                 const float* __restrict__ a2,
                                                 const float* __restrict__ s2_,
                                                 float* __restrict__ d2,
                                                 float* __restrict__ bnp) {
  const float* attn; const float* src; float* dst;
  int t = blockIdx.y;
  if (t == 0) { attn = a1; src = s1_; dst = d1; }
  else        { attn = a2; src = s2_; dst = d2; }
  int b = blockIdx.x >> 6, chunk = blockIdx.x & 63;
  int n0 = chunk * 256 + threadIdx.x;
  const float* s = src + (size_t)b * C * N + n0;
  float v[64];
  #pragma unroll
  for (int d = 0; d < 64; ++d) v[d] = s[d * N];
  const float4* at4 = (const float4*)(attn + b * 4096);
  float* o = dst + (size_t)b * C * N + n0;
  __shared__ float red[64][4], red2[64][4];
  int lane = threadIdx.x & 63, wave = threadIdx.x >> 6;
  for (int c = 0; c < 64; ++c) {
    float acc = 0.f;
    #pragma unroll
    for (int q = 0; q < 16; ++q) {
      float4 w4 = at4[c * 16 + q];
      acc += w4.x * v[4 * q] + w4.y * v[4 * q + 1] + w4.z * v[4 * q + 2] + w4.w * v[4 * q + 3];
    }
    o[c * N] = acc;
    float sr = acc, ssr = acc * acc;
    for (int off = 32; off; off >>= 1) {
      sr  += __shfl_xor(sr, off);
      ssr += __shfl_xor(ssr, off);
    }
    if (lane == 0) { red[c][wave] = sr; red2[c][wave] = ssr; }
  }
  __syncthreads();
  if (threadIdx.x < 64) {
    int c = threadIdx.x;
    float sr  = red[c][0] + red[c][1] + red[c][2] + red[c][3];
    float ssr = red2[c][0] + red2[c][1] + red2[c][2] + red2[c][3];
    int idx = (t * 64 + c) * 512 + blockIdx.x;
    bnp[idx]         = sr;
    bnp[65536 + idx] = ssr;
  }
}

// fold 512 block-partials per (t,c) -> mean/rstd
__global__ void k_bnstats2(const float* __restrict__ bnp, float* __restrict__ stats) {
  __shared__ float sr[128][4], ssr[128][4];
  int tid = threadIdx.x;                       // 0..511
  int combo = tid >> 2, q = tid & 3;           // combo = t*64+c
  float s = 0.f, ss = 0.f;
  for (int k = 0; k < 128; ++k) {
    int idx = combo * 512 + q * 128 + k;
    s  += bnp[idx];
    ss += bnp[65536 + idx];
  }
  sr[combo][q] = s; ssr[combo][q] = ss;
  __syncthreads();
  if (q == 0) {
    float S  = sr[combo][0] + sr[combo][1] + sr[combo][2] + sr[combo][3];
    float SS = ssr[combo][0] + ssr[combo][1] + ssr[combo][2] + ssr[combo][3];
    int t = combo >> 6, c = combo & 63;
    float mean = S / 131072.f;
    float var  = SS / 131072.f - mean * mean;
    stats[t * 128 + c]      = mean;
    stats[t * 128 + 64 + c] = 1.f / sqrtf(var + 1e-5f);
  }
}

// ---------------------------------------------------------------------------
// Fused feat copies + BN apply (float4 throughout)
__global__ __launch_bounds__(256) void k_final(
    const float4* __restrict__ f1, float4* __restrict__ o8,
    const float4* __restrict__ f2, float4* __restrict__ o9,
    float4* __restrict__ o0, float4* __restrict__ o1,
    const float* __restrict__ stats,
    const float* __restrict__ bw, const float* __restrict__ bb) {
  int i = blockIdx.x * 256 + threadIdx.x;       // 0..BCN/4-1
  int t = blockIdx.y;
  if (t == 0) o8[i] = f1[i]; else o9[i] = f2[i];
  float4* p = t ? o1 : o0;
  int c = (i >> 12) & 63;
  float m = stats[t * 128 + c], r = stats[t * 128 + 64 + c];
  float w_ = bw[c], b_ = bb[c];
  float4 v = p[i];
  v.x = fminf(fmaxf((v.x - m) * r * w_ + b_, 0.f), 6.f);
  v.y = fminf(fmaxf((v.y - m) * r * w_ + b_, 0.f), 6.f);
  v.z = fminf(fmaxf((v.z - m) * r * w_ + b_, 0.f), 6.f);
  v.w = fminf(fmaxf((v.w - m) * r * w_ + b_, 0.f), 6.f);
  p[i] = v;
}

// ---------------------------------------------------------------------------
extern "C" void kernel_launch(void* const* d_in, const int* in_sizes, int n_in,
                              void* d_out, int out_size, void* d_ws, size_t ws_size,
                              hipStream_t stream) {
  const float* feat1   = (const float*)d_in[1];
  const float* feat2   = (const float*)d_in[2];
  const float* cam1    = (const float*)d_in[3];
  const float* cam2    = (const float*)d_in[4];
  const float* f_g     = (const float*)d_in[5];
  const float* f_e     = (const float*)d_in[6];
  const float* conv1_w = (const float*)d_in[7];
  const float* conv1_b = (const float*)d_in[8];
  const float* conv2_w = (const float*)d_in[9];
  const float* conv2_b = (const float*)d_in[10];
  const float* bn_w    = (const float*)d_in[11];
  const float* bn_b    = (const float*)d_in[12];

  float* out = (float*)d_out;
  float* w = (float*)d_ws;
  int* xy = (int*)(w + WS_XY);

  float* o0 = out + O_APPLY1;
  float* o1 = out + O_APPLY2;
  float* o2 = out + O_GRID1;
  float* o3 = out + O_GRID2;
  float* o4 = out + O_EDGEF;
  float* o5 = out + O_COLORF;
  float* o6 = out + O_ATTN1;
  float* o7 = out + O_ATTN2;
  float* o8 = out + O_FEAT1;
  float* o9 = out + O_FEAT2;

  // 1. fused front-end (resize + locate + box argmax + grids)
  k_front<<<B, 256, 0, stream>>>(cam1, cam2, xy, o2, o3);

  // 2. fused moments + edge
  k_prep<<<2048, 256, 0, stream>>>(f_e, f_g, w + WS_MOM, w + WS_EDGE);

  // 3. fused conv1 + conv2
  k_conv12<<<dim3(B * 64, 2), 256, 0, stream>>>(w + WS_EDGE, conv1_w, conv1_b, o4,
                                                w + WS_MOM, conv2_w, conv2_b, o5);

  // 4. logits partials (atomic-free; WS_MOM is dead after conv2)
  k_logits<<<dim3(B * 16, 2), 256, 0, stream>>>(o4, feat2, o5, feat1,
                                                w + WS_MOM, xy);

  // 5. softmax (sums 16 partials per row)
  k_softmax<<<dim3(B * C, 2), 64, 0, stream>>>(w + WS_MOM, o6, o7);

  // 6. apply + bn-stats partials
  k_applyst<<<dim3(B * 64, 2), 256, 0, stream>>>(o7, feat1, o0, o6, feat2, o1,
                                                 w + WS_BNP);

  // 7. fold stats
  k_bnstats2<<<1, 512, 0, stream>>>(w + WS_BNP, w + WS_BN);

  // 8. fused feat copies + bn apply
  k_final<<<dim3(BCN / 4 / 256, 2), 256, 0, stream>>>(
      (const float4*)feat1, (float4*)o8, (const float4*)feat2, (float4*)o9,
      (float4*)o0, (float4*)o1, w + WS_BN, bn_w, bn_b);
}

// Round 6
// 590.741 us; speedup vs baseline: 1.0844x; 1.0690x over previous
//
#include <hip/hip_runtime.h>
#include <math.h>

// ---------------------------------------------------------------------------
// Problem constants
#define SIZE 128
#define WIN 32
#define HALF 16
#define B 8
#define C 64
#define N (SIZE*SIZE)        // 16384
#define BCN 8388608          // B*C*N
#define BV 97                // box VALID output size (128-32+1)

// Output offsets (floats)
#define O_APPLY1   0
#define O_APPLY2   8388608
#define O_GRID1    16777216
#define O_GRID2    17039360
#define O_EDGEF    17301504
#define O_COLORF   25690112
#define O_ATTN1    34078720
#define O_ATTN2    34111488
#define O_FEAT1    34144256
#define O_FEAT2    42532864

// Workspace offsets (floats)
#define WS_BNP     0         // bn partials: s at 0, ss at 65536
#define WS_XY      361472    // 32 ints
#define WS_MOM     361600    // moments, then logits partials (1M floats)
#define WS_EDGE    1541248   // 131072
#define WS_BN      1737856   // 256

#define NEGINF (-3.402823466e+38f)

typedef unsigned __int128 u128;

// ---------------------------------------------------------------------------
// Kogge-Stone occluded fill (horizontal, 128-bit row)
__device__ __forceinline__ u128 hfill(u128 g, u128 m) {
  u128 p = m;
  g |= p & (g << 1);  p &= p << 1;
  g |= p & (g << 2);  p &= p << 2;
  g |= p & (g << 4);  p &= p << 4;
  g |= p & (g << 8);  p &= p << 8;
  g |= p & (g << 16); p &= p << 16;
  g |= p & (g << 32); p &= p << 32;
  g |= p & (g << 64);
  p = m;
  g |= p & (g >> 1);  p &= p >> 1;
  g |= p & (g >> 2);  p &= p >> 2;
  g |= p & (g >> 4);  p &= p >> 4;
  g |= p & (g >> 8);  p &= p >> 8;
  g |= p & (g >> 16); p &= p >> 16;
  g |= p & (g >> 32); p &= p >> 32;
  g |= p & (g >> 64);
  return g;
}

// ---------------------------------------------------------------------------
// Stage-1 mega-kernel: three INDEPENDENT jobs overlapped in one dispatch
// (the stream serializes kernels, so front's 145us of 8-block latency-bound
// work would otherwise leave 248 CUs idle):
//   blocks 0..7       : fused front-end (resize+locate+boxargmax+grids)
//   blocks 8..2055    : fused moments+edge (prep)
//   blocks 2056..     : feat1/feat2 -> o8/o9 copies (BW work, no LDS)
// LDS: one carved 135 KB union (front's requirement; prep uses first 17 KB).
#define PREP_BASE 8
#define COPY_BASE 2056
#define COPY_HALF 8192       // BCN/4/256 blocks per tensor
#define STAGE1_GRID (COPY_BASE + 2 * COPY_HALF)

__global__ __launch_bounds__(256) void k_stage1(
    const float* __restrict__ cam1, const float* __restrict__ cam2,
    int* __restrict__ xy, float* __restrict__ g1, float* __restrict__ g2,
    const float* __restrict__ fe, const float* __restrict__ fg,
    float* __restrict__ mom, float* __restrict__ edge,
    const float4* __restrict__ f1, float4* __restrict__ o8,
    const float4* __restrict__ f2, float4* __restrict__ o9) {
  __shared__ __align__(16) float smem[33824];   // 135296 B
  int blk = blockIdx.x;
  int tid = threadIdx.x;

  if (blk >= COPY_BASE) {
    // ---------------- copy path (no LDS, no barrier) ----------------
    int c = blk - COPY_BASE;
    if (c < COPY_HALF) o8[c * 256 + tid] = f1[c * 256 + tid];
    else { int i = (c - COPY_HALF) * 256 + tid; o9[i] = f2[i]; }
    return;
  }

  if (blk >= PREP_BASE) {
    // ---------------- prep path (moments / edge), LDS-tiled ----------------
    float* sx = smem;                           // 66*66 = 4356 floats
    int pblk = blk - PREP_BASE;
    if (pblk < 1536) {
      // moments
      int tile = pblk & 63, ch = (pblk >> 6) % 3, b = pblk / 192;
      int ti0 = (tile >> 3) * 16, tj0 = (tile & 7) * 16;
      const float* src = fe + (size_t)(b * 3 + ch) * 262144;
      int oy0 = 4 * ti0 - 1, ox0 = 4 * tj0 - 1;
      for (int l = tid; l < 66 * 66; l += 256) {
        int r = l / 66, cc = l % 66;
        int gy = oy0 + r, gx = ox0 + cc;
        sx[l] = (gy >= 0 && gy < 512 && gx >= 0 && gx < 512) ? src[gy * 512 + gx] : 0.f;
      }
      __syncthreads();
      int ii = tid >> 4, jj = tid & 15;
      int i = ti0 + ii, j = tj0 + jj;
      float s1a[6], s2a[6], s3a[6], s1b[6], s2b[6], s3b[6];
      #pragma unroll
      for (int t = 0; t < 6; ++t) {
        float a1 = 0, a2 = 0, a3 = 0, b1 = 0, b2 = 0, b3 = 0;
        int lx = 4 * jj + t;
        #pragma unroll
        for (int r = 0; r < 6; ++r) {
          float v = sx[(4 * ii + r) * 66 + lx];
          float v2 = v * v, v3 = v2 * v;
          if (r < 5) { a1 += v; a2 += v2; a3 += v3; }
          if (r > 0) { b1 += v; b2 += v2; b3 += v3; }
        }
        s1a[t] = a1; s2a[t] = a2; s3a[t] = a3;
        s1b[t] = b1; s2b[t] = b2; s3b[t] = b3;
      }
      float am = 0, av = 0, as = 0;
      #pragma unroll
      for (int py = 0; py < 2; ++py) {
        #pragma unroll
        for (int px = 0; px < 2; ++px) {
          float s1 = 0, s2 = 0, s3 = 0;
          #pragma unroll
          for (int t = 0; t < 5; ++t) {
            s1 += py ? s1b[px + t] : s1a[px + t];
            s2 += py ? s2b[px + t] : s2a[px + t];
            s3 += py ? s3b[px + t] : s3a[px + t];
          }
          float mean = s1 / 25.f;
          float var  = (s2 - 25.f * mean * mean) / 24.f;
          float m3   = (s3 - 3.f * mean * s2 + 50.f * mean * mean * mean) / 25.f;
          float sq   = sqrtf(fmaxf(var, 0.f));
          float skew = m3 / (sq * sq * sq + 1e-6f);
          am += mean; av += var; as += skew;
        }
      }
      int base = (b * 9 + ch) * N + i * 128 + j;
      mom[base]         = 0.25f * am;
      mom[base + 3 * N] = 0.25f * av;
      mom[base + 6 * N] = 0.25f * as;
    } else {
      // edge
      int eblk = pblk - 1536;
      int tile = eblk & 63, b = eblk >> 6;
      int ti0 = (tile >> 3) * 16, tj0 = (tile & 7) * 16;
      const float* s0 = fg + (size_t)b * 3 * 262144;
      int oy0 = 4 * ti0 - 1, ox0 = 4 * tj0 - 1;
      for (int l = tid; l < 66 * 66; l += 256) {
        int r = l / 66, cc = l % 66;
        int gy = oy0 + r, gx = ox0 + cc;
        float v = 0.f;
        if (gy >= 0 && gy < 512 && gx >= 0 && gx < 512) {
          int o = gy * 512 + gx;
          v = s0[o] + s0[262144 + o] + s0[524288 + o];
        }
        sx[l] = v;
      }
      __syncthreads();
      int ii = tid >> 4, jj = tid & 15;
      int i = ti0 + ii, j = tj0 + jj;
      const float INV2PI = 0.15915494309189535f;
      float wg[5], ug[5];
      #pragma unroll
      for (int t = 0; t < 5; ++t) {
        float a = (float)t - 2.f;
        float e = expf(-0.5f * a * a);
        wg[t] = e; ug[t] = -a * e;
      }
      float rAa[6], rAb[6], rBa[6], rBb[6];
      #pragma unroll
      for (int t = 0; t < 6; ++t) {
        float aa = 0, ab = 0, ba = 0, bb = 0;
        int lx = 4 * jj + t;
        #pragma unroll
        for (int r = 0; r < 6; ++r) {
          float v = sx[(4 * ii + r) * 66 + lx];
          if (r < 5) { aa += v * wg[r]; ba += v * ug[r]; }
          if (r > 0) { ab += v * wg[r - 1]; bb += v * ug[r - 1]; }
        }
        rAa[t] = aa; rAb[t] = ab; rBa[t] = ba; rBb[t] = bb;
      }
      float acc = 0.f;
      #pragma unroll
      for (int py = 0; py < 2; ++py) {
        #pragma unroll
        for (int px = 0; px < 2; ++px) {
          float h = 0, v = 0;
          #pragma unroll
          for (int t = 0; t < 5; ++t) {
            float A  = py ? rAb[px + t] : rAa[px + t];
            float Bw = py ? rBb[px + t] : rBa[px + t];
            h += A * ug[t];
            v += Bw * wg[t];
          }
          h *= INV2PI; v *= INV2PI;
          acc += tanhf(sqrtf(h * h + v * v + 1e-8f));
        }
      }
      edge[b * N + i * 128 + j] = 0.25f * acc;
    }
    return;
  }

  // ---------------- front path (blocks 0..7), carved LDS ----------------
  float* sc  = smem;                                  // 16384
  float* sc2 = smem + 16384;                          // 16384
  float* sv  = smem + 32768;                          // 256
  int*   si  = (int*)(smem + 33024);                  // 256
  unsigned long long* mask64 = (unsigned long long*)(smem + 33280); // 256 ull
  int* sint = (int*)(smem + 33792);
  // sint[0]=xm 1=ym 2=ok 3=x1 4=y1 5=x2 6=y2
  int b = blk;
  const float* src1 = cam1 + b * 4096;
  const float* src2 = cam2 + b * 4096;

  // resize both cams into LDS + per-thread argmax of c1
  float bv = NEGINF; int bi = 0;
  for (int k = 0; k < 64; ++k) {
    int pix = k * 256 + tid;
    int i = pix >> 7, j = pix & 127;
    float fy = fminf(fmaxf(0.5f * (float)i - 0.25f, 0.f), 63.f);
    float fx = fminf(fmaxf(0.5f * (float)j - 0.25f, 0.f), 63.f);
    int y0 = (int)fy; float ty = fy - (float)y0; int y1i = min(y0 + 1, 63);
    int x0 = (int)fx; float tx = fx - (float)x0; int x1i = min(x0 + 1, 63);
    float a00 = src1[y0 * 64 + x0],  a01 = src1[y0 * 64 + x1i];
    float a10 = src1[y1i * 64 + x0], a11 = src1[y1i * 64 + x1i];
    float v1 = (1.f - ty) * ((1.f - tx) * a00 + tx * a01)
             + ty * ((1.f - tx) * a10 + tx * a11);
    float c00 = src2[y0 * 64 + x0],  c01 = src2[y0 * 64 + x1i];
    float c10 = src2[y1i * 64 + x0], c11 = src2[y1i * 64 + x1i];
    float v2 = (1.f - ty) * ((1.f - tx) * c00 + tx * c01)
             + ty * ((1.f - tx) * c10 + tx * c11);
    sc[pix] = v1; sc2[pix] = v2;
    if (v1 > bv) { bv = v1; bi = pix; }
  }
  sv[tid] = bv; si[tid] = bi;
  __syncthreads();
  for (int s = 128; s; s >>= 1) {
    if (tid < s) {
      float ov = sv[tid + s]; int oi = si[tid + s];
      if (ov > sv[tid] || (ov == sv[tid] && oi < si[tid])) { sv[tid] = ov; si[tid] = oi; }
    }
    __syncthreads();
  }
  if (tid == 0) { sint[0] = si[0] >> 7; sint[1] = si[0] & 127; }
  __syncthreads();
  int s_xm = sint[0], s_ym = sint[1];

  // gradient-magnitude mask via ballot (conflict-free stride-1 reads)
  for (int k = 0; k < 64; ++k) {
    int pix = k * 256 + tid;
    int i = pix >> 7, j = pix & 127;
    float gx_, gy_;
    if (i == 0)        gx_ = sc[128 + j] - sc[j];
    else if (i == 127) gx_ = sc[127 * 128 + j] - sc[126 * 128 + j];
    else               gx_ = 0.5f * (sc[(i + 1) * 128 + j] - sc[(i - 1) * 128 + j]);
    if (j == 0)        gy_ = sc[i * 128 + 1] - sc[i * 128];
    else if (j == 127) gy_ = sc[i * 128 + 127] - sc[i * 128 + 126];
    else               gy_ = 0.5f * (sc[i * 128 + j + 1] - sc[i * 128 + j - 1]);
    bool pred = hypotf(gx_, gy_) < 0.2f;
    unsigned long long bal = __ballot(pred);
    if ((tid & 63) == 0) mask64[(i << 1) + (j >> 6)] = bal;
  }
  __syncthreads();
  if (tid == 0) {
    unsigned long long wdd = mask64[(s_xm << 1) + (s_ym >> 6)];
    sint[2] = (int)((wdd >> (s_ym & 63)) & 1ull);
  }
  __syncthreads();
  int s_ok = sint[2];

  // flood fill: single wave, 2 rows per lane, shfl vertical exchange
  if (tid < 64) {
    int l = tid;
    u128 m0 = ((u128)mask64[4 * l])     | ((u128)mask64[4 * l + 1] << 64);
    u128 m1 = ((u128)mask64[4 * l + 2]) | ((u128)mask64[4 * l + 3] << 64);
    u128 g0 = 0, g1v = 0;
    if (s_ok && (s_xm >> 1) == l) {
      if ((s_xm & 1) == 0) g0  = ((u128)1) << s_ym;
      else                 g1v = ((u128)1) << s_ym;
    }
    g0  = hfill(g0 & m0, m0);
    g1v = hfill(g1v & m1, m1);
    for (;;) {
      unsigned long long ulo = __shfl_up((unsigned long long)g1v, 1);
      unsigned long long uhi = __shfl_up((unsigned long long)(g1v >> 64), 1);
      u128 up = (l > 0) ? (((u128)ulo) | ((u128)uhi << 64)) : (u128)0;
      unsigned long long dlo = __shfl_down((unsigned long long)g0, 1);
      unsigned long long dhi = __shfl_down((unsigned long long)(g0 >> 64), 1);
      u128 dn = (l < 63) ? (((u128)dlo) | ((u128)dhi << 64)) : (u128)0;
      u128 n0 = hfill((g0 | up | g1v) & m0, m0);
      u128 n1 = hfill((g1v | n0 | dn) & m1, m1);
      bool chg = (n0 != g0) || (n1 != g1v);
      g0 = n0; g1v = n1;
      if (!__any(chg)) break;
    }
    unsigned long long be = __ballot(g0 != 0);
    unsigned long long bo = __ballot(g1v != 0);
    unsigned long long cl = (unsigned long long)(g0 | g1v);
    unsigned long long chh = (unsigned long long)((g0 | g1v) >> 64);
    for (int off = 32; off; off >>= 1) {
      cl  |= __shfl_xor(cl, off);
      chh |= __shfl_xor(chh, off);
    }
    if (l == 0) {
      int rs = 0, re = 0, cs = 0, ce = 0;
      if (be | bo) {
        int af = be ? (__ffsll(be) - 1) : 1000;
        int bf = bo ? (__ffsll(bo) - 1) : 1000;
        rs = min(af * 2, bf * 2 + 1);
        int al = be ? (63 - __clzll(be)) : -1000;
        int bl = bo ? (63 - __clzll(bo)) : -1000;
        re = max(al * 2, bl * 2 + 1) + 1;
        cs = cl ? (__ffsll(cl) - 1) : 64 + (__ffsll(chh) - 1);
        ce = chh ? 128 - __clzll(chh) : 64 - __clzll(cl);
      }
      int x1, y1;
      if (s_ok) { x1 = (rs + re) >> 1; y1 = (cs + ce) >> 1; }
      else      { x1 = s_xm;           y1 = s_ym; }
      xy[b] = x1; xy[8 + b] = y1; sint[3] = x1; sint[4] = y1;
    }
  }
  __syncthreads();

  // colsum of c2 (32-row sums) into sc (c1 dead now)
  for (int idx = tid; idx < BV * 128; idx += 256) {
    int rr = idx >> 7, cc = idx & 127;
    float acc = 0.f;
    #pragma unroll
    for (int dy = 0; dy < WIN; ++dy) acc += sc2[(rr + dy) * 128 + cc];
    sc[idx] = acc;
  }
  __syncthreads();

  // 32x32 box argmax
  bv = NEGINF; bi = 0;
  for (int p = tid; p < BV * BV; p += 256) {
    int rr = p / BV, cc = p % BV;
    float s = 0.f;
    #pragma unroll
    for (int dx = 0; dx < WIN; ++dx) s += sc[rr * 128 + cc + dx];
    if (s > bv) { bv = s; bi = p; }
  }
  sv[tid] = bv; si[tid] = bi;
  __syncthreads();
  for (int s = 128; s; s >>= 1) {
    if (tid < s) {
      float ov = sv[tid + s]; int oi = si[tid + s];
      if (ov > sv[tid] || (ov == sv[tid] && oi < si[tid])) { sv[tid] = ov; si[tid] = oi; }
    }
    __syncthreads();
  }
  if (tid == 0) {
    int x2 = si[0] / BV + HALF, y2 = si[0] % BV + HALF;
    xy[16 + b] = x2; xy[24 + b] = y2; sint[5] = x2; sint[6] = y2;
  }
  __syncthreads();

  // grids for this batch
  float x1f = (float)sint[3], y1f = (float)sint[4];
  float x2f = (float)sint[5], y2f = (float)sint[6];
  float m1x = (x1f - x2f) / 64.f, m1y = (y1f - y2f) / 64.f;
  float* g1b = g1 + (size_t)b * N * 2;
  float* g2b = g2 + (size_t)b * N * 2;
  for (int k = 0; k < 64; ++k) {
    int pix = k * 256 + tid;
    int h = pix >> 7, w = pix & 127;
    float bx = (2.f * (float)w + 1.f) / 128.f - 1.f;
    float by = (2.f * (float)h + 1.f) / 128.f - 1.f;
    g1b[pix * 2]     = bx + m1x; g1b[pix * 2 + 1] = by + m1y;
    g2b[pix * 2]     = bx - m1x; g2b[pix * 2 + 1] = by - m1y;
  }
}

// ---------------------------------------------------------------------------
// Fused conv1 (y=0) + conv2 (y=1); register-window formulation
__global__ __launch_bounds__(256) void k_conv12(
    const float* __restrict__ edge, const float* __restrict__ w1,
    const float* __restrict__ b1, float* __restrict__ o4,
    const float* __restrict__ mom, const float* __restrict__ w2,
    const float* __restrict__ b2, float* __restrict__ o5) {
  __shared__ float tin[9 * 324];
  __shared__ float wsm[64 * 84];
  int b = blockIdx.x >> 6, tile = blockIdx.x & 63;
  int ti0 = (tile >> 3) * 16, tj0 = (tile & 7) * 16;
  int tid = threadIdx.x;
  int i = tid >> 4, j = tid & 15;
  if (blockIdx.y == 0) {
    for (int l = tid; l < 324; l += 256) {
      int r = l / 18, cc = l % 18;
      int gi = ti0 + r - 1, gj = tj0 + cc - 1;
      tin[l] = (gi >= 0 && gi < 128 && gj >= 0 && gj < 128) ? edge[b * N + gi * 128 + gj] : 0.f;
    }
    for (int l = tid; l < 64 * 12; l += 256) {
      int o = l / 12, t = l % 12;
      wsm[l] = (t < 9) ? (w1[o * 27 + t] + w1[o * 27 + 9 + t] + w1[o * 27 + 18 + t]) : 0.f;
    }
    __syncthreads();
    float win[12];
    #pragma unroll
    for (int dy = 0; dy < 3; ++dy)
      #pragma unroll
      for (int dx = 0; dx < 3; ++dx)
        win[dy * 3 + dx] = tin[(i + dy) * 18 + (j + dx)];
    win[9] = 0.f; win[10] = 0.f; win[11] = 0.f;
    float* o = o4 + (size_t)b * C * N + (ti0 + i) * 128 + tj0 + j;
    for (int oc = 0; oc < C; ++oc) {
      const float4* wr = (const float4*)(wsm + oc * 12);
      float acc = b1[oc];
      #pragma unroll
      for (int q = 0; q < 3; ++q) {
        float4 w4 = wr[q];
        acc += w4.x * win[4 * q] + w4.y * win[4 * q + 1]
             + w4.z * win[4 * q + 2] + w4.w * win[4 * q + 3];
      }
      o[oc * N] = fminf(fmaxf(acc, 0.f), 6.f);
    }
  } else {
    for (int l = tid; l < 9 * 324; l += 256) {
      int ic = l / 324, rem = l % 324, r = rem / 18, cc = rem % 18;
      int gi = ti0 + r - 1, gj = tj0 + cc - 1;
      tin[l] = (gi >= 0 && gi < 128 && gj >= 0 && gj < 128) ? mom[(b * 9 + ic) * N + gi * 128 + gj] : 0.f;
    }
    for (int l = tid; l < 64 * 84; l += 256) {
      int o = l / 84, t = l % 84;
      wsm[l] = (t < 81) ? w2[o * 81 + t] : 0.f;
    }
    __syncthreads();
    float win[84];
    #pragma unroll
    for (int ic = 0; ic < 9; ++ic)
      #pragma unroll
      for (int dy = 0; dy < 3; ++dy)
        #pragma unroll
        for (int dx = 0; dx < 3; ++dx)
          win[ic * 9 + dy * 3 + dx] = tin[ic * 324 + (i + dy) * 18 + (j + dx)];
    win[81] = 0.f; win[82] = 0.f; win[83] = 0.f;
    float* o = o5 + (size_t)b * C * N + (ti0 + i) * 128 + tj0 + j;
    for (int oc = 0; oc < C; ++oc) {
      const float4* wr = (const float4*)(wsm + oc * 84);
      float acc = b2[oc];
      #pragma unroll
      for (int q = 0; q < 21; ++q) {
        float4 w4 = wr[q];
        acc += w4.x * win[4 * q] + w4.y * win[4 * q + 1]
             + w4.z * win[4 * q + 2] + w4.w * win[4 * q + 3];
      }
      o[oc * N] = acc;
    }
  }
}

// ---------------------------------------------------------------------------
// logits partial tiles (atomic-free): block (b,sl,mode) writes its own
// 64x64 partial into lg[((mode*8+b)*16+sl)*4096]. Skipped slices write 0.
__global__ __launch_bounds__(256) void k_logits(const float* __restrict__ aB1,
                                                const float* __restrict__ bB1,
                                                const float* __restrict__ aB2,
                                                const float* __restrict__ bB2,
                                                float* __restrict__ lg,
                                                const int* __restrict__ xy) {
  int mode = blockIdx.y;
  const float* aBase = mode ? aB2 : aB1;
  const float* bBase = mode ? bB2 : bB1;
  int b = blockIdx.x >> 4, sl = blockIdx.x & 15;
  int tid = threadIdx.x;
  int ci = (tid >> 4) << 2, di = (tid & 15) << 2;
  float* o = lg + (size_t)(((mode * 8 + b) * 16 + sl)) * 4096;

  int x1 = xy[b], y1 = xy[8 + b], x2 = xy[16 + b], y2 = xy[24 + b];
  int dyh, dxw, rlo, rhi, clo, chi;
  if (mode == 0) {
    dyh = y1 - y2; dxw = x1 - x2;
    rlo = max(x1 - HALF, 0); rhi = min(x1 + HALF, SIZE);
    clo = max(y1 - HALF, 0); chi = min(y1 + HALF, SIZE);
  } else {
    dyh = y2 - y1; dxw = x2 - x1;
    rlo = max(x2 - HALF, 0); rhi = min(x2 + HALF, SIZE);
    clo = max(y2 - HALF, 0); chi = min(y2 + HALF, SIZE);
  }
  int hlo = max(0, rlo - dyh), hhi = min(SIZE, rhi - dyh);
  int wlo = max(0, clo - dxw), whi = min(SIZE, chi - dxw);
  int wn = whi - wlo, hn = hhi - hlo;
  int npos = (wn > 0 && hn > 0) ? wn * hn : 0;
  if (sl * 64 >= npos) {
    #pragma unroll
    for (int u = 0; u < 4; ++u)
      #pragma unroll
      for (int v = 0; v < 4; ++v)
        o[(ci + u) * 64 + (di + v)] = 0.f;
    return;
  }

  __shared__ float aS[64][65];
  __shared__ float bS[64][65];
  const float* aB = aBase + (size_t)b * C * N;
  const float* bB = bBase + (size_t)b * C * N;
  for (int l = tid; l < 4096; l += 256) {
    int ch = l >> 6, k = l & 63;
    int p = sl * 64 + k;
    float av = 0.f, bv = 0.f;
    if (p < npos) {
      int h = hlo + p / wn, w = wlo + p % wn;
      av = aB[ch * N + (h + dyh) * 128 + (w + dxw)];
      bv = bB[ch * N + h * 128 + w];
    }
    aS[ch][k] = av; bS[ch][k] = bv;
  }
  __syncthreads();
  float acc[4][4] = {};
  #pragma unroll 4
  for (int k = 0; k < 64; ++k) {
    float a0 = aS[ci][k], a1 = aS[ci + 1][k], a2 = aS[ci + 2][k], a3 = aS[ci + 3][k];
    float b0 = bS[di][k], b1v = bS[di + 1][k], b2v = bS[di + 2][k], b3 = bS[di + 3][k];
    acc[0][0] += a0 * b0; acc[0][1] += a0 * b1v; acc[0][2] += a0 * b2v; acc[0][3] += a0 * b3;
    acc[1][0] += a1 * b0; acc[1][1] += a1 * b1v; acc[1][2] += a1 * b2v; acc[1][3] += a1 * b3;
    acc[2][0] += a2 * b0; acc[2][1] += a2 * b1v; acc[2][2] += a2 * b2v; acc[2][3] += a2 * b3;
    acc[3][0] += a3 * b0; acc[3][1] += a3 * b1v; acc[3][2] += a3 * b2v; acc[3][3] += a3 * b3;
  }
  #pragma unroll
  for (int u = 0; u < 4; ++u)
    #pragma unroll
    for (int v = 0; v < 4; ++v)
      o[(ci + u) * 64 + (di + v)] = acc[u][v];
}

// softmax over last dim (64); sums the 16 slice partials first
__global__ void k_softmax(const float* __restrict__ lg,
                          float* __restrict__ o6, float* __restrict__ o7) {
  int row = blockIdx.x;            // 0..511 = b*64+c
  int mode = blockIdx.y;
  float* dst = mode ? o7 : o6;
  int b = row >> 6, c = row & 63;
  int lane = threadIdx.x;
  const float* base = lg + (size_t)((mode * 8 + b) * 16) * 4096 + c * 64 + lane;
  float v = 0.f;
  #pragma unroll
  for (int sl = 0; sl < 16; ++sl) v += base[sl * 4096];
  float mx = v;
  for (int off = 32; off; off >>= 1) mx = fmaxf(mx, __shfl_xor(mx, off));
  float e = expf(v - mx);
  float s = e;
  for (int off = 32; off; off >>= 1) s += __shfl_xor(s, off);
  dst[row * 64 + lane] = e / s;
}

// ---------------------------------------------------------------------------
// apply (attn @ feat) fused with BN-stats partial accumulation.
__global__ __launch_bounds__(256) void k_applyst(const float* __restrict__ a1,
                                                 const float* __restrict__ s1_,
                                                 float* __restrict__ d1,
                                                 const float* __restrict__ a2,
                                                 const float* __restrict__ s2_,
                                                 float* __restrict__ d2,
                                                 float* __restrict__ bnp) {
  const float* attn; const float* src; float* dst;
  int t = blockIdx.y;
  if (t == 0) { attn = a1; src = s1_; dst = d1; }
  else        { attn = a2; src = s2_; dst = d2; }
  int b = blockIdx.x >> 6, chunk = blockIdx.x & 63;
  int n0 = chunk * 256 + threadIdx.x;
  const float* s = src + (size_t)b * C * N + n0;
  float v[64];
  #pragma unroll
  for (int d = 0; d < 64; ++d) v[d] = s[d * N];
  const float4* at4 = (const float4*)(attn + b * 4096);
  float* o = dst + (size_t)b * C * N + n0;
  __shared__ float red[64][4], red2[64][4];
  int lane = threadIdx.x & 63, wave = threadIdx.x >> 6;
  for (int c = 0; c < 64; ++c) {
    float acc = 0.f;
    #pragma unroll
    for (int q = 0; q < 16; ++q) {
      float4 w4 = at4[c * 16 + q];
      acc += w4.x * v[4 * q] + w4.y * v[4 * q + 1] + w4.z * v[4 * q + 2] + w4.w * v[4 * q + 3];
    }
    o[c * N] = acc;
    float sr = acc, ssr = acc * acc;
    for (int off = 32; off; off >>= 1) {
      sr  += __shfl_xor(sr, off);
      ssr += __shfl_xor(ssr, off);
    }
    if (lane == 0) { red[c][wave] = sr; red2[c][wave] = ssr; }
  }
  __syncthreads();
  if (threadIdx.x < 64) {
    int c = threadIdx.x;
    float sr  = red[c][0] + red[c][1] + red[c][2] + red[c][3];
    float ssr = red2[c][0] + red2[c][1] + red2[c][2] + red2[c][3];
    int idx = (t * 64 + c) * 512 + blockIdx.x;
    bnp[idx]         = sr;
    bnp[65536 + idx] = ssr;
  }
}

// fold 512 block-partials per (t,c) -> mean/rstd
__global__ void k_bnstats2(const float* __restrict__ bnp, float* __restrict__ stats) {
  __shared__ float sr[128][4], ssr[128][4];
  int tid = threadIdx.x;                       // 0..511
  int combo = tid >> 2, q = tid & 3;           // combo = t*64+c
  float s = 0.f, ss = 0.f;
  for (int k = 0; k < 128; ++k) {
    int idx = combo * 512 + q * 128 + k;
    s  += bnp[idx];
    ss += bnp[65536 + idx];
  }
  sr[combo][q] = s; ssr[combo][q] = ss;
  __syncthreads();
  if (q == 0) {
    float S  = sr[combo][0] + sr[combo][1] + sr[combo][2] + sr[combo][3];
    float SS = ssr[combo][0] + ssr[combo][1] + ssr[combo][2] + ssr[combo][3];
    int t = combo >> 6, c = combo & 63;
    float mean = S / 131072.f;
    float var  = SS / 131072.f - mean * mean;
    stats[t * 128 + c]      = mean;
    stats[t * 128 + 64 + c] = 1.f / sqrtf(var + 1e-5f);
  }
}

// ---------------------------------------------------------------------------
// BN apply only (copies moved to k_stage1)
__global__ __launch_bounds__(256) void k_bnapply(
    float4* __restrict__ o0, float4* __restrict__ o1,
    const float* __restrict__ stats,
    const float* __restrict__ bw, const float* __restrict__ bb) {
  int i = blockIdx.x * 256 + threadIdx.x;       // 0..BCN/4-1
  int t = blockIdx.y;
  float4* p = t ? o1 : o0;
  int c = (i >> 12) & 63;
  float m = stats[t * 128 + c], r = stats[t * 128 + 64 + c];
  float w_ = bw[c], b_ = bb[c];
  float4 v = p[i];
  v.x = fminf(fmaxf((v.x - m) * r * w_ + b_, 0.f), 6.f);
  v.y = fminf(fmaxf((v.y - m) * r * w_ + b_, 0.f), 6.f);
  v.z = fminf(fmaxf((v.z - m) * r * w_ + b_, 0.f), 6.f);
  v.w = fminf(fmaxf((v.w - m) * r * w_ + b_, 0.f), 6.f);
  p[i] = v;
}

// ---------------------------------------------------------------------------
extern "C" void kernel_launch(void* const* d_in, const int* in_sizes, int n_in,
                              void* d_out, int out_size, void* d_ws, size_t ws_size,
                              hipStream_t stream) {
  const float* feat1   = (const float*)d_in[1];
  const float* feat2   = (const float*)d_in[2];
  const float* cam1    = (const float*)d_in[3];
  const float* cam2    = (const float*)d_in[4];
  const float* f_g     = (const float*)d_in[5];
  const float* f_e     = (const float*)d_in[6];
  const float* conv1_w = (const float*)d_in[7];
  const float* conv1_b = (const float*)d_in[8];
  const float* conv2_w = (const float*)d_in[9];
  const float* conv2_b = (const float*)d_in[10];
  const float* bn_w    = (const float*)d_in[11];
  const float* bn_b    = (const float*)d_in[12];

  float* out = (float*)d_out;
  float* w = (float*)d_ws;
  int* xy = (int*)(w + WS_XY);

  float* o0 = out + O_APPLY1;
  float* o1 = out + O_APPLY2;
  float* o2 = out + O_GRID1;
  float* o3 = out + O_GRID2;
  float* o4 = out + O_EDGEF;
  float* o5 = out + O_COLORF;
  float* o6 = out + O_ATTN1;
  float* o7 = out + O_ATTN2;
  float* o8 = out + O_FEAT1;
  float* o9 = out + O_FEAT2;

  // 1. stage1: front-end || moments+edge || feat copies (one dispatch)
  k_stage1<<<STAGE1_GRID, 256, 0, stream>>>(
      cam1, cam2, xy, o2, o3,
      f_e, f_g, w + WS_MOM, w + WS_EDGE,
      (const float4*)feat1, (float4*)o8, (const float4*)feat2, (float4*)o9);

  // 2. fused conv1 + conv2
  k_conv12<<<dim3(B * 64, 2), 256, 0, stream>>>(w + WS_EDGE, conv1_w, conv1_b, o4,
                                                w + WS_MOM, conv2_w, conv2_b, o5);

  // 3. logits partials (atomic-free; WS_MOM is dead after conv2)
  k_logits<<<dim3(B * 16, 2), 256, 0, stream>>>(o4, feat2, o5, feat1,
                                                w + WS_MOM, xy);

  // 4. softmax (sums 16 partials per row)
  k_softmax<<<dim3(B * C, 2), 64, 0, stream>>>(w + WS_MOM, o6, o7);

  // 5. apply + bn-stats partials
  k_applyst<<<dim3(B * 64, 2), 256, 0, stream>>>(o7, feat1, o0, o6, feat2, o1,
                                                 w + WS_BNP);

  // 6. fold stats
  k_bnstats2<<<1, 512, 0, stream>>>(w + WS_BNP, w + WS_BN);

  // 7. bn apply
  k_bnapply<<<dim3(BCN / 4 / 256, 2), 256, 0, stream>>>(
      (float4*)o0, (float4*)o1, w + WS_BN, bn_w, bn_b);
}

// Round 7
// 587.699 us; speedup vs baseline: 1.0901x; 1.0052x over previous
//
#include <hip/hip_runtime.h>
#include <math.h>

// ---------------------------------------------------------------------------
// Problem constants
#define SIZE 128
#define WIN 32
#define HALF 16
#define B 8
#define C 64
#define N (SIZE*SIZE)        // 16384
#define BCN 8388608          // B*C*N
#define BV 97                // box VALID output size (128-32+1)

// Output offsets (floats)
#define O_APPLY1   0
#define O_APPLY2   8388608
#define O_GRID1    16777216
#define O_GRID2    17039360
#define O_EDGEF    17301504
#define O_COLORF   25690112
#define O_ATTN1    34078720
#define O_ATTN2    34111488
#define O_FEAT1    34144256
#define O_FEAT2    42532864

// Workspace offsets (floats)
#define WS_BNP     0         // bn partials: s at 0, ss at 65536
#define WS_XY      361472    // 32 ints
#define WS_MOM     361600    // moments, then logits partials (1M floats)
#define WS_EDGE    1541248   // 131072
#define WS_BN      1737856   // 256

#define NEGINF (-3.402823466e+38f)

typedef unsigned __int128 u128;

// ---------------------------------------------------------------------------
// Kogge-Stone occluded fill (horizontal, 128-bit row)
__device__ __forceinline__ u128 hfill(u128 g, u128 m) {
  u128 p = m;
  g |= p & (g << 1);  p &= p << 1;
  g |= p & (g << 2);  p &= p << 2;
  g |= p & (g << 4);  p &= p << 4;
  g |= p & (g << 8);  p &= p << 8;
  g |= p & (g << 16); p &= p << 16;
  g |= p & (g << 32); p &= p << 32;
  g |= p & (g << 64);
  p = m;
  g |= p & (g >> 1);  p &= p >> 1;
  g |= p & (g >> 2);  p &= p >> 2;
  g |= p & (g >> 4);  p &= p >> 4;
  g |= p & (g >> 8);  p &= p >> 8;
  g |= p & (g >> 16); p &= p >> 16;
  g |= p & (g >> 32); p &= p >> 32;
  g |= p & (g >> 64);
  return g;
}

// bilinear 64->128 sample from LDS-staged 64x64 cam
__device__ __forceinline__ float resamp(const float* raw, int i, int j) {
  float fy = fminf(fmaxf(0.5f * (float)i - 0.25f, 0.f), 63.f);
  float fx = fminf(fmaxf(0.5f * (float)j - 0.25f, 0.f), 63.f);
  int y0 = (int)fy; float ty = fy - (float)y0; int y1i = min(y0 + 1, 63);
  int x0 = (int)fx; float tx = fx - (float)x0; int x1i = min(x0 + 1, 63);
  float a00 = raw[y0 * 64 + x0],  a01 = raw[y0 * 64 + x1i];
  float a10 = raw[y1i * 64 + x0], a11 = raw[y1i * 64 + x1i];
  return (1.f - ty) * ((1.f - tx) * a00 + tx * a01)
       + ty * ((1.f - tx) * a10 + tx * a11);
}

// ---------------------------------------------------------------------------
// Stage-1 mega-kernel, four independent jobs in one dispatch:
//   blocks 0..7    : A = resize cam1 + locate-region -> x1,y1
//   blocks 8..15   : B = resize cam2 + colsum + box argmax -> x2,y2
//   blocks 16..2063: prep (moments / edge), LDS-tiled
//   blocks 2064..  : feat1/feat2 -> o8/o9 copies
// A and B per batch run CONCURRENTLY (were serialized in one block before).
// Cams are LDS-staged with coalesced float4 loads before resampling
// (kills the scattered-global-load latency chain).
#define FRONT_B   8
#define PREP_BASE 16
#define COPY_BASE 2064
#define COPY_HALF 8192       // BCN/4/256 blocks per tensor
#define STAGE1_GRID (COPY_BASE + 2 * COPY_HALF)

__global__ __launch_bounds__(256) void k_stage1(
    const float* __restrict__ cam1, const float* __restrict__ cam2,
    int* __restrict__ xy,
    const float* __restrict__ fe, const float* __restrict__ fg,
    float* __restrict__ mom, float* __restrict__ edge,
    const float4* __restrict__ f1, float4* __restrict__ o8,
    const float4* __restrict__ f2, float4* __restrict__ o9) {
  __shared__ __align__(16) float smem[33824];   // 135296 B
  int blk = blockIdx.x;
  int tid = threadIdx.x;

  if (blk >= COPY_BASE) {
    // ---------------- copy path (no LDS, no barrier) ----------------
    int c = blk - COPY_BASE;
    if (c < COPY_HALF) o8[c * 256 + tid] = f1[c * 256 + tid];
    else { int i = (c - COPY_HALF) * 256 + tid; o9[i] = f2[i]; }
    return;
  }

  if (blk >= PREP_BASE) {
    // ---------------- prep path (moments / edge), LDS-tiled ----------------
    float* sx = smem;                           // 66*66 = 4356 floats
    int pblk = blk - PREP_BASE;
    if (pblk < 1536) {
      // moments
      int tile = pblk & 63, ch = (pblk >> 6) % 3, b = pblk / 192;
      int ti0 = (tile >> 3) * 16, tj0 = (tile & 7) * 16;
      const float* src = fe + (size_t)(b * 3 + ch) * 262144;
      int oy0 = 4 * ti0 - 1, ox0 = 4 * tj0 - 1;
      for (int l = tid; l < 66 * 66; l += 256) {
        int r = l / 66, cc = l % 66;
        int gy = oy0 + r, gx = ox0 + cc;
        sx[l] = (gy >= 0 && gy < 512 && gx >= 0 && gx < 512) ? src[gy * 512 + gx] : 0.f;
      }
      __syncthreads();
      int ii = tid >> 4, jj = tid & 15;
      int i = ti0 + ii, j = tj0 + jj;
      float s1a[6], s2a[6], s3a[6], s1b[6], s2b[6], s3b[6];
      #pragma unroll
      for (int t = 0; t < 6; ++t) {
        float a1 = 0, a2 = 0, a3 = 0, b1 = 0, b2 = 0, b3 = 0;
        int lx = 4 * jj + t;
        #pragma unroll
        for (int r = 0; r < 6; ++r) {
          float v = sx[(4 * ii + r) * 66 + lx];
          float v2 = v * v, v3 = v2 * v;
          if (r < 5) { a1 += v; a2 += v2; a3 += v3; }
          if (r > 0) { b1 += v; b2 += v2; b3 += v3; }
        }
        s1a[t] = a1; s2a[t] = a2; s3a[t] = a3;
        s1b[t] = b1; s2b[t] = b2; s3b[t] = b3;
      }
      float am = 0, av = 0, as = 0;
      #pragma unroll
      for (int py = 0; py < 2; ++py) {
        #pragma unroll
        for (int px = 0; px < 2; ++px) {
          float s1 = 0, s2 = 0, s3 = 0;
          #pragma unroll
          for (int t = 0; t < 5; ++t) {
            s1 += py ? s1b[px + t] : s1a[px + t];
            s2 += py ? s2b[px + t] : s2a[px + t];
            s3 += py ? s3b[px + t] : s3a[px + t];
          }
          float mean = s1 / 25.f;
          float var  = (s2 - 25.f * mean * mean) / 24.f;
          float m3   = (s3 - 3.f * mean * s2 + 50.f * mean * mean * mean) / 25.f;
          float sq   = sqrtf(fmaxf(var, 0.f));
          float skew = m3 / (sq * sq * sq + 1e-6f);
          am += mean; av += var; as += skew;
        }
      }
      int base = (b * 9 + ch) * N + i * 128 + j;
      mom[base]         = 0.25f * am;
      mom[base + 3 * N] = 0.25f * av;
      mom[base + 6 * N] = 0.25f * as;
    } else {
      // edge
      int eblk = pblk - 1536;
      int tile = eblk & 63, b = eblk >> 6;
      int ti0 = (tile >> 3) * 16, tj0 = (tile & 7) * 16;
      const float* s0 = fg + (size_t)b * 3 * 262144;
      int oy0 = 4 * ti0 - 1, ox0 = 4 * tj0 - 1;
      for (int l = tid; l < 66 * 66; l += 256) {
        int r = l / 66, cc = l % 66;
        int gy = oy0 + r, gx = ox0 + cc;
        float v = 0.f;
        if (gy >= 0 && gy < 512 && gx >= 0 && gx < 512) {
          int o = gy * 512 + gx;
          v = s0[o] + s0[262144 + o] + s0[524288 + o];
        }
        sx[l] = v;
      }
      __syncthreads();
      int ii = tid >> 4, jj = tid & 15;
      int i = ti0 + ii, j = tj0 + jj;
      const float INV2PI = 0.15915494309189535f;
      float wg[5], ug[5];
      #pragma unroll
      for (int t = 0; t < 5; ++t) {
        float a = (float)t - 2.f;
        float e = expf(-0.5f * a * a);
        wg[t] = e; ug[t] = -a * e;
      }
      float rAa[6], rAb[6], rBa[6], rBb[6];
      #pragma unroll
      for (int t = 0; t < 6; ++t) {
        float aa = 0, ab = 0, ba = 0, bb = 0;
        int lx = 4 * jj + t;
        #pragma unroll
        for (int r = 0; r < 6; ++r) {
          float v = sx[(4 * ii + r) * 66 + lx];
          if (r < 5) { aa += v * wg[r]; ba += v * ug[r]; }
          if (r > 0) { ab += v * wg[r - 1]; bb += v * ug[r - 1]; }
        }
        rAa[t] = aa; rAb[t] = ab; rBa[t] = ba; rBb[t] = bb;
      }
      float acc = 0.f;
      #pragma unroll
      for (int py = 0; py < 2; ++py) {
        #pragma unroll
        for (int px = 0; px < 2; ++px) {
          float h = 0, v = 0;
          #pragma unroll
          for (int t = 0; t < 5; ++t) {
            float A  = py ? rAb[px + t] : rAa[px + t];
            float Bw = py ? rBb[px + t] : rBa[px + t];
            h += A * ug[t];
            v += Bw * wg[t];
          }
          h *= INV2PI; v *= INV2PI;
          acc += tanhf(sqrtf(h * h + v * v + 1e-8f));
        }
      }
      edge[b * N + i * 128 + j] = 0.25f * acc;
    }
    return;
  }

  if (blk >= FRONT_B) {
    // ---------------- B path: resize cam2 + colsum + box argmax ----------------
    int b = blk - FRONT_B;
    float* raw = smem;                          // 4096
    float* sc2 = smem + 4096;                   // 16384
    float* cs  = smem + 20480;                  // 12416
    float* sv  = smem + 32896;                  // 256
    int*   si  = (int*)(smem + 33152);          // 256

    const float4* c4 = (const float4*)(cam2 + b * 4096);
    float4* r4 = (float4*)raw;
    #pragma unroll
    for (int k = 0; k < 4; ++k) r4[k * 256 + tid] = c4[k * 256 + tid];
    __syncthreads();
    for (int k = 0; k < 64; ++k) {
      int pix = k * 256 + tid;
      sc2[pix] = resamp(raw, pix >> 7, pix & 127);
    }
    __syncthreads();

    // colsum (exact ordered 32-row sums, same as before)
    for (int idx = tid; idx < BV * 128; idx += 256) {
      int rr = idx >> 7, cc = idx & 127;
      float acc = 0.f;
      #pragma unroll
      for (int dy = 0; dy < WIN; ++dy) acc += sc2[(rr + dy) * 128 + cc];
      cs[idx] = acc;
    }
    __syncthreads();

    // 32x32 box argmax
    float bv = NEGINF; int bi = 0;
    for (int p = tid; p < BV * BV; p += 256) {
      int rr = p / BV, cc = p % BV;
      float s = 0.f;
      #pragma unroll
      for (int dx = 0; dx < WIN; ++dx) s += cs[rr * 128 + cc + dx];
      if (s > bv) { bv = s; bi = p; }
    }
    sv[tid] = bv; si[tid] = bi;
    __syncthreads();
    for (int s = 128; s; s >>= 1) {
      if (tid < s) {
        float ov = sv[tid + s]; int oi = si[tid + s];
        if (ov > sv[tid] || (ov == sv[tid] && oi < si[tid])) { sv[tid] = ov; si[tid] = oi; }
      }
      __syncthreads();
    }
    if (tid == 0) {
      xy[16 + b] = si[0] / BV + HALF;
      xy[24 + b] = si[0] % BV + HALF;
    }
    return;
  }

  // ---------------- A path: resize cam1 + locate-region ----------------
  {
    int b = blk;
    float* raw = smem;                                  // 4096
    float* sc  = smem + 4096;                           // 16384
    float* sv  = smem + 20480;                          // 256
    int*   si  = (int*)(smem + 20736);                  // 256
    unsigned long long* mask64 = (unsigned long long*)(smem + 20992); // 256 ull
    int* sint = (int*)(smem + 21504);                   // 8

    const float4* c4 = (const float4*)(cam1 + b * 4096);
    float4* r4 = (float4*)raw;
    #pragma unroll
    for (int k = 0; k < 4; ++k) r4[k * 256 + tid] = c4[k * 256 + tid];
    __syncthreads();

    // resize from LDS + per-thread argmax
    float bv = NEGINF; int bi = 0;
    for (int k = 0; k < 64; ++k) {
      int pix = k * 256 + tid;
      float v1 = resamp(raw, pix >> 7, pix & 127);
      sc[pix] = v1;
      if (v1 > bv) { bv = v1; bi = pix; }
    }
    sv[tid] = bv; si[tid] = bi;
    __syncthreads();
    for (int s = 128; s; s >>= 1) {
      if (tid < s) {
        float ov = sv[tid + s]; int oi = si[tid + s];
        if (ov > sv[tid] || (ov == sv[tid] && oi < si[tid])) { sv[tid] = ov; si[tid] = oi; }
      }
      __syncthreads();
    }
    if (tid == 0) { sint[0] = si[0] >> 7; sint[1] = si[0] & 127; }
    __syncthreads();
    int s_xm = sint[0], s_ym = sint[1];

    // gradient-magnitude mask via ballot (stride-1 LDS reads)
    for (int k = 0; k < 64; ++k) {
      int pix = k * 256 + tid;
      int i = pix >> 7, j = pix & 127;
      float gx_, gy_;
      if (i == 0)        gx_ = sc[128 + j] - sc[j];
      else if (i == 127) gx_ = sc[127 * 128 + j] - sc[126 * 128 + j];
      else               gx_ = 0.5f * (sc[(i + 1) * 128 + j] - sc[(i - 1) * 128 + j]);
      if (j == 0)        gy_ = sc[i * 128 + 1] - sc[i * 128];
      else if (j == 127) gy_ = sc[i * 128 + 127] - sc[i * 128 + 126];
      else               gy_ = 0.5f * (sc[i * 128 + j + 1] - sc[i * 128 + j - 1]);
      bool pred = hypotf(gx_, gy_) < 0.2f;
      unsigned long long bal = __ballot(pred);
      if ((tid & 63) == 0) mask64[(i << 1) + (j >> 6)] = bal;
    }
    __syncthreads();
    if (tid == 0) {
      unsigned long long wdd = mask64[(s_xm << 1) + (s_ym >> 6)];
      sint[2] = (int)((wdd >> (s_ym & 63)) & 1ull);
    }
    __syncthreads();
    int s_ok = sint[2];

    // flood fill: single wave, 2 rows per lane, shfl vertical exchange
    if (tid < 64) {
      int l = tid;
      u128 m0 = ((u128)mask64[4 * l])     | ((u128)mask64[4 * l + 1] << 64);
      u128 m1 = ((u128)mask64[4 * l + 2]) | ((u128)mask64[4 * l + 3] << 64);
      u128 g0 = 0, g1v = 0;
      if (s_ok && (s_xm >> 1) == l) {
        if ((s_xm & 1) == 0) g0  = ((u128)1) << s_ym;
        else                 g1v = ((u128)1) << s_ym;
      }
      g0  = hfill(g0 & m0, m0);
      g1v = hfill(g1v & m1, m1);
      for (;;) {
        unsigned long long ulo = __shfl_up((unsigned long long)g1v, 1);
        unsigned long long uhi = __shfl_up((unsigned long long)(g1v >> 64), 1);
        u128 up = (l > 0) ? (((u128)ulo) | ((u128)uhi << 64)) : (u128)0;
        unsigned long long dlo = __shfl_down((unsigned long long)g0, 1);
        unsigned long long dhi = __shfl_down((unsigned long long)(g0 >> 64), 1);
        u128 dn = (l < 63) ? (((u128)dlo) | ((u128)dhi << 64)) : (u128)0;
        u128 n0 = hfill((g0 | up | g1v) & m0, m0);
        u128 n1 = hfill((g1v | n0 | dn) & m1, m1);
        bool chg = (n0 != g0) || (n1 != g1v);
        g0 = n0; g1v = n1;
        if (!__any(chg)) break;
      }
      unsigned long long be = __ballot(g0 != 0);
      unsigned long long bo = __ballot(g1v != 0);
      unsigned long long cl = (unsigned long long)(g0 | g1v);
      unsigned long long chh = (unsigned long long)((g0 | g1v) >> 64);
      for (int off = 32; off; off >>= 1) {
        cl  |= __shfl_xor(cl, off);
        chh |= __shfl_xor(chh, off);
      }
      if (l == 0) {
        int rs = 0, re = 0, cs_ = 0, ce = 0;
        if (be | bo) {
          int af = be ? (__ffsll(be) - 1) : 1000;
          int bf = bo ? (__ffsll(bo) - 1) : 1000;
          rs = min(af * 2, bf * 2 + 1);
          int al = be ? (63 - __clzll(be)) : -1000;
          int bl = bo ? (63 - __clzll(bo)) : -1000;
          re = max(al * 2, bl * 2 + 1) + 1;
          cs_ = cl ? (__ffsll(cl) - 1) : 64 + (__ffsll(chh) - 1);
          ce = chh ? 128 - __clzll(chh) : 64 - __clzll(cl);
        }
        int x1, y1;
        if (s_ok) { x1 = (rs + re) >> 1; y1 = (cs_ + ce) >> 1; }
        else      { x1 = s_xm;           y1 = s_ym; }
        xy[b] = x1; xy[8 + b] = y1;
      }
    }
  }
}

// ---------------------------------------------------------------------------
// Fused conv1 (y=0) + conv2 (y=1) + grids (x>=512, y=0)
__global__ __launch_bounds__(256) void k_conv12(
    const float* __restrict__ edge, const float* __restrict__ w1,
    const float* __restrict__ b1, float* __restrict__ o4,
    const float* __restrict__ mom, const float* __restrict__ w2,
    const float* __restrict__ b2, float* __restrict__ o5,
    const int* __restrict__ xy, float* __restrict__ g1, float* __restrict__ g2) {
  __shared__ float tin[9 * 324];
  __shared__ float wsm[64 * 84];
  int tid = threadIdx.x;

  if (blockIdx.x >= 512) {
    // ---- grids path (needs xy from stage1's A and B blocks)
    if (blockIdx.y != 0) return;
    int b = blockIdx.x - 512;
    float x1f = (float)xy[b], y1f = (float)xy[8 + b];
    float x2f = (float)xy[16 + b], y2f = (float)xy[24 + b];
    float m1x = (x1f - x2f) / 64.f, m1y = (y1f - y2f) / 64.f;
    float* g1b = g1 + (size_t)b * N * 2;
    float* g2b = g2 + (size_t)b * N * 2;
    for (int k = 0; k < 64; ++k) {
      int pix = k * 256 + tid;
      int h = pix >> 7, w = pix & 127;
      float bx = (2.f * (float)w + 1.f) / 128.f - 1.f;
      float by = (2.f * (float)h + 1.f) / 128.f - 1.f;
      g1b[pix * 2]     = bx + m1x; g1b[pix * 2 + 1] = by + m1y;
      g2b[pix * 2]     = bx - m1x; g2b[pix * 2 + 1] = by - m1y;
    }
    return;
  }

  int b = blockIdx.x >> 6, tile = blockIdx.x & 63;
  int ti0 = (tile >> 3) * 16, tj0 = (tile & 7) * 16;
  int i = tid >> 4, j = tid & 15;
  if (blockIdx.y == 0) {
    for (int l = tid; l < 324; l += 256) {
      int r = l / 18, cc = l % 18;
      int gi = ti0 + r - 1, gj = tj0 + cc - 1;
      tin[l] = (gi >= 0 && gi < 128 && gj >= 0 && gj < 128) ? edge[b * N + gi * 128 + gj] : 0.f;
    }
    for (int l = tid; l < 64 * 12; l += 256) {
      int o = l / 12, t = l % 12;
      wsm[l] = (t < 9) ? (w1[o * 27 + t] + w1[o * 27 + 9 + t] + w1[o * 27 + 18 + t]) : 0.f;
    }
    __syncthreads();
    float win[12];
    #pragma unroll
    for (int dy = 0; dy < 3; ++dy)
      #pragma unroll
      for (int dx = 0; dx < 3; ++dx)
        win[dy * 3 + dx] = tin[(i + dy) * 18 + (j + dx)];
    win[9] = 0.f; win[10] = 0.f; win[11] = 0.f;
    float* o = o4 + (size_t)b * C * N + (ti0 + i) * 128 + tj0 + j;
    for (int oc = 0; oc < C; ++oc) {
      const float4* wr = (const float4*)(wsm + oc * 12);
      float acc = b1[oc];
      #pragma unroll
      for (int q = 0; q < 3; ++q) {
        float4 w4 = wr[q];
        acc += w4.x * win[4 * q] + w4.y * win[4 * q + 1]
             + w4.z * win[4 * q + 2] + w4.w * win[4 * q + 3];
      }
      o[oc * N] = fminf(fmaxf(acc, 0.f), 6.f);
    }
  } else {
    for (int l = tid; l < 9 * 324; l += 256) {
      int ic = l / 324, rem = l % 324, r = rem / 18, cc = rem % 18;
      int gi = ti0 + r - 1, gj = tj0 + cc - 1;
      tin[l] = (gi >= 0 && gi < 128 && gj >= 0 && gj < 128) ? mom[(b * 9 + ic) * N + gi * 128 + gj] : 0.f;
    }
    for (int l = tid; l < 64 * 84; l += 256) {
      int o = l / 84, t = l % 84;
      wsm[l] = (t < 81) ? w2[o * 81 + t] : 0.f;
    }
    __syncthreads();
    float win[84];
    #pragma unroll
    for (int ic = 0; ic < 9; ++ic)
      #pragma unroll
      for (int dy = 0; dy < 3; ++dy)
        #pragma unroll
        for (int dx = 0; dx < 3; ++dx)
          win[ic * 9 + dy * 3 + dx] = tin[ic * 324 + (i + dy) * 18 + (j + dx)];
    win[81] = 0.f; win[82] = 0.f; win[83] = 0.f;
    float* o = o5 + (size_t)b * C * N + (ti0 + i) * 128 + tj0 + j;
    for (int oc = 0; oc < C; ++oc) {
      const float4* wr = (const float4*)(wsm + oc * 84);
      float acc = b2[oc];
      #pragma unroll
      for (int q = 0; q < 21; ++q) {
        float4 w4 = wr[q];
        acc += w4.x * win[4 * q] + w4.y * win[4 * q + 1]
             + w4.z * win[4 * q + 2] + w4.w * win[4 * q + 3];
      }
      o[oc * N] = acc;
    }
  }
}

// ---------------------------------------------------------------------------
// logits partial tiles (atomic-free): block (b,sl,mode) writes its own
// 64x64 partial into lg[((mode*8+b)*16+sl)*4096]. Skipped slices write 0.
__global__ __launch_bounds__(256) void k_logits(const float* __restrict__ aB1,
                                                const float* __restrict__ bB1,
                                                const float* __restrict__ aB2,
                                                const float* __restrict__ bB2,
                                                float* __restrict__ lg,
                                                const int* __restrict__ xy) {
  int mode = blockIdx.y;
  const float* aBase = mode ? aB2 : aB1;
  const float* bBase = mode ? bB2 : bB1;
  int b = blockIdx.x >> 4, sl = blockIdx.x & 15;
  int tid = threadIdx.x;
  int ci = (tid >> 4) << 2, di = (tid & 15) << 2;
  float* o = lg + (size_t)(((mode * 8 + b) * 16 + sl)) * 4096;

  int x1 = xy[b], y1 = xy[8 + b], x2 = xy[16 + b], y2 = xy[24 + b];
  int dyh, dxw, rlo, rhi, clo, chi;
  if (mode == 0) {
    dyh = y1 - y2; dxw = x1 - x2;
    rlo = max(x1 - HALF, 0); rhi = min(x1 + HALF, SIZE);
    clo = max(y1 - HALF, 0); chi = min(y1 + HALF, SIZE);
  } else {
    dyh = y2 - y1; dxw = x2 - x1;
    rlo = max(x2 - HALF, 0); rhi = min(x2 + HALF, SIZE);
    clo = max(y2 - HALF, 0); chi = min(y2 + HALF, SIZE);
  }
  int hlo = max(0, rlo - dyh), hhi = min(SIZE, rhi - dyh);
  int wlo = max(0, clo - dxw), whi = min(SIZE, chi - dxw);
  int wn = whi - wlo, hn = hhi - hlo;
  int npos = (wn > 0 && hn > 0) ? wn * hn : 0;
  if (sl * 64 >= npos) {
    #pragma unroll
    for (int u = 0; u < 4; ++u)
      #pragma unroll
      for (int v = 0; v < 4; ++v)
        o[(ci + u) * 64 + (di + v)] = 0.f;
    return;
  }

  __shared__ float aS[64][65];
  __shared__ float bS[64][65];
  const float* aB = aBase + (size_t)b * C * N;
  const float* bB = bBase + (size_t)b * C * N;
  for (int l = tid; l < 4096; l += 256) {
    int ch = l >> 6, k = l & 63;
    int p = sl * 64 + k;
    float av = 0.f, bv = 0.f;
    if (p < npos) {
      int h = hlo + p / wn, w = wlo + p % wn;
      av = aB[ch * N + (h + dyh) * 128 + (w + dxw)];
      bv = bB[ch * N + h * 128 + w];
    }
    aS[ch][k] = av; bS[ch][k] = bv;
  }
  __syncthreads();
  float acc[4][4] = {};
  #pragma unroll 4
  for (int k = 0; k < 64; ++k) {
    float a0 = aS[ci][k], a1 = aS[ci + 1][k], a2 = aS[ci + 2][k], a3 = aS[ci + 3][k];
    float b0 = bS[di][k], b1v = bS[di + 1][k], b2v = bS[di + 2][k], b3 = bS[di + 3][k];
    acc[0][0] += a0 * b0; acc[0][1] += a0 * b1v; acc[0][2] += a0 * b2v; acc[0][3] += a0 * b3;
    acc[1][0] += a1 * b0; acc[1][1] += a1 * b1v; acc[1][2] += a1 * b2v; acc[1][3] += a1 * b3;
    acc[2][0] += a2 * b0; acc[2][1] += a2 * b1v; acc[2][2] += a2 * b2v; acc[2][3] += a2 * b3;
    acc[3][0] += a3 * b0; acc[3][1] += a3 * b1v; acc[3][2] += a3 * b2v; acc[3][3] += a3 * b3;
  }
  #pragma unroll
  for (int u = 0; u < 4; ++u)
    #pragma unroll
    for (int v = 0; v < 4; ++v)
      o[(ci + u) * 64 + (di + v)] = acc[u][v];
}

// softmax over last dim (64); sums the 16 slice partials first
__global__ void k_softmax(const float* __restrict__ lg,
                          float* __restrict__ o6, float* __restrict__ o7) {
  int row = blockIdx.x;            // 0..511 = b*64+c
  int mode = blockIdx.y;
  float* dst = mode ? o7 : o6;
  int b = row >> 6, c = row & 63;
  int lane = threadIdx.x;
  const float* base = lg + (size_t)((mode * 8 + b) * 16) * 4096 + c * 64 + lane;
  float v = 0.f;
  #pragma unroll
  for (int sl = 0; sl < 16; ++sl) v += base[sl * 4096];
  float mx = v;
  for (int off = 32; off; off >>= 1) mx = fmaxf(mx, __shfl_xor(mx, off));
  float e = expf(v - mx);
  float s = e;
  for (int off = 32; off; off >>= 1) s += __shfl_xor(s, off);
  dst[row * 64 + lane] = e / s;
}

// ---------------------------------------------------------------------------
// apply (attn @ feat) fused with BN-stats partial accumulation.
__global__ __launch_bounds__(256) void k_applyst(const float* __restrict__ a1,
                                                 const float* __restrict__ s1_,
                                                 float* __restrict__ d1,
                                                 const float* __restrict__ a2,
                                                 const float* __restrict__ s2_,
                                                 float* __restrict__ d2,
                                                 float* __restrict__ bnp) {
  const float* attn; const float* src; float* dst;
  int t = blockIdx.y;
  if (t == 0) { attn = a1; src = s1_; dst = d1; }
  else        { attn = a2; src = s2_; dst = d2; }
  int b = blockIdx.x >> 6, chunk = blockIdx.x & 63;
  int n0 = chunk * 256 + threadIdx.x;
  const float* s = src + (size_t)b * C * N + n0;
  float v[64];
  #pragma unroll
  for (int d = 0; d < 64; ++d) v[d] = s[d * N];
  const float4* at4 = (const float4*)(attn + b * 4096);
  float* o = dst + (size_t)b * C * N + n0;
  __shared__ float red[64][4], red2[64][4];
  int lane = threadIdx.x & 63, wave = threadIdx.x >> 6;
  for (int c = 0; c < 64; ++c) {
    float acc = 0.f;
    #pragma unroll
    for (int q = 0; q < 16; ++q) {
      float4 w4 = at4[c * 16 + q];
      acc += w4.x * v[4 * q] + w4.y * v[4 * q + 1] + w4.z * v[4 * q + 2] + w4.w * v[4 * q + 3];
    }
    o[c * N] = acc;
    float sr = acc, ssr = acc * acc;
    for (int off = 32; off; off >>= 1) {
      sr  += __shfl_xor(sr, off);
      ssr += __shfl_xor(ssr, off);
    }
    if (lane == 0) { red[c][wave] = sr; red2[c][wave] = ssr; }
  }
  __syncthreads();
  if (threadIdx.x < 64) {
    int c = threadIdx.x;
    float sr  = red[c][0] + red[c][1] + red[c][2] + red[c][3];
    float ssr = red2[c][0] + red2[c][1] + red2[c][2] + red2[c][3];
    int idx = (t * 64 + c) * 512 + blockIdx.x;
    bnp[idx]         = sr;
    bnp[65536 + idx] = ssr;
  }
}

// fold 512 block-partials per (t,c) -> mean/rstd
__global__ void k_bnstats2(const float* __restrict__ bnp, float* __restrict__ stats) {
  __shared__ float sr[128][4], ssr[128][4];
  int tid = threadIdx.x;                       // 0..511
  int combo = tid >> 2, q = tid & 3;           // combo = t*64+c
  float s = 0.f, ss = 0.f;
  for (int k = 0; k < 128; ++k) {
    int idx = combo * 512 + q * 128 + k;
    s  += bnp[idx];
    ss += bnp[65536 + idx];
  }
  sr[combo][q] = s; ssr[combo][q] = ss;
  __syncthreads();
  if (q == 0) {
    float S  = sr[combo][0] + sr[combo][1] + sr[combo][2] + sr[combo][3];
    float SS = ssr[combo][0] + ssr[combo][1] + ssr[combo][2] + ssr[combo][3];
    int t = combo >> 6, c = combo & 63;
    float mean = S / 131072.f;
    float var  = SS / 131072.f - mean * mean;
    stats[t * 128 + c]      = mean;
    stats[t * 128 + 64 + c] = 1.f / sqrtf(var + 1e-5f);
  }
}

// ---------------------------------------------------------------------------
// BN apply only (copies live in k_stage1)
__global__ __launch_bounds__(256) void k_bnapply(
    float4* __restrict__ o0, float4* __restrict__ o1,
    const float* __restrict__ stats,
    const float* __restrict__ bw, const float* __restrict__ bb) {
  int i = blockIdx.x * 256 + threadIdx.x;       // 0..BCN/4-1
  int t = blockIdx.y;
  float4* p = t ? o1 : o0;
  int c = (i >> 12) & 63;
  float m = stats[t * 128 + c], r = stats[t * 128 + 64 + c];
  float w_ = bw[c], b_ = bb[c];
  float4 v = p[i];
  v.x = fminf(fmaxf((v.x - m) * r * w_ + b_, 0.f), 6.f);
  v.y = fminf(fmaxf((v.y - m) * r * w_ + b_, 0.f), 6.f);
  v.z = fminf(fmaxf((v.z - m) * r * w_ + b_, 0.f), 6.f);
  v.w = fminf(fmaxf((v.w - m) * r * w_ + b_, 0.f), 6.f);
  p[i] = v;
}

// ---------------------------------------------------------------------------
extern "C" void kernel_launch(void* const* d_in, const int* in_sizes, int n_in,
                              void* d_out, int out_size, void* d_ws, size_t ws_size,
                              hipStream_t stream) {
  const float* feat1   = (const float*)d_in[1];
  const float* feat2   = (const float*)d_in[2];
  const float* cam1    = (const float*)d_in[3];
  const float* cam2    = (const float*)d_in[4];
  const float* f_g     = (const float*)d_in[5];
  const float* f_e     = (const float*)d_in[6];
  const float* conv1_w = (const float*)d_in[7];
  const float* conv1_b = (const float*)d_in[8];
  const float* conv2_w = (const float*)d_in[9];
  const float* conv2_b = (const float*)d_in[10];
  const float* bn_w    = (const float*)d_in[11];
  const float* bn_b    = (const float*)d_in[12];

  float* out = (float*)d_out;
  float* w = (float*)d_ws;
  int* xy = (int*)(w + WS_XY);

  float* o0 = out + O_APPLY1;
  float* o1 = out + O_APPLY2;
  float* o2 = out + O_GRID1;
  float* o3 = out + O_GRID2;
  float* o4 = out + O_EDGEF;
  float* o5 = out + O_COLORF;
  float* o6 = out + O_ATTN1;
  float* o7 = out + O_ATTN2;
  float* o8 = out + O_FEAT1;
  float* o9 = out + O_FEAT2;

  // 1. stage1: locate-A || boxfind-B || moments+edge || feat copies
  k_stage1<<<STAGE1_GRID, 256, 0, stream>>>(
      cam1, cam2, xy,
      f_e, f_g, w + WS_MOM, w + WS_EDGE,
      (const float4*)feat1, (float4*)o8, (const float4*)feat2, (float4*)o9);

  // 2. fused conv1 + conv2 + grids
  k_conv12<<<dim3(520, 2), 256, 0, stream>>>(w + WS_EDGE, conv1_w, conv1_b, o4,
                                             w + WS_MOM, conv2_w, conv2_b, o5,
                                             xy, o2, o3);

  // 3. logits partials (atomic-free; WS_MOM is dead after conv2)
  k_logits<<<dim3(B * 16, 2), 256, 0, stream>>>(o4, feat2, o5, feat1,
                                                w + WS_MOM, xy);

  // 4. softmax (sums 16 partials per row)
  k_softmax<<<dim3(B * C, 2), 64, 0, stream>>>(w + WS_MOM, o6, o7);

  // 5. apply + bn-stats partials
  k_applyst<<<dim3(B * 64, 2), 256, 0, stream>>>(o7, feat1, o0, o6, feat2, o1,
                                                 w + WS_BNP);

  // 6. fold stats
  k_bnstats2<<<1, 512, 0, stream>>>(w + WS_BNP, w + WS_BN);

  // 7. bn apply
  k_bnapply<<<dim3(BCN / 4 / 256, 2), 256, 0, stream>>>(
      (float4*)o0, (float4*)o1, w + WS_BN, bn_w, bn_b);
}

// Round 8
// 536.021 us; speedup vs baseline: 1.1951x; 1.0964x over previous
//
#include <hip/hip_runtime.h>
#include <math.h>

// ---------------------------------------------------------------------------
// Problem constants
#define SIZE 128
#define WIN 32
#define HALF 16
#define B 8
#define C 64
#define N (SIZE*SIZE)        // 16384
#define BCN 8388608          // B*C*N
#define BV 97                // box VALID output size (128-32+1)

// Output offsets (floats)
#define O_APPLY1   0
#define O_APPLY2   8388608
#define O_GRID1    16777216
#define O_GRID2    17039360
#define O_EDGEF    17301504
#define O_COLORF   25690112
#define O_ATTN1    34078720
#define O_ATTN2    34111488
#define O_FEAT1    34144256
#define O_FEAT2    42532864

// Workspace offsets (floats)
#define WS_BNP     0         // bn partials: s at 0, ss at 65536
#define WS_XY      361472    // 32 ints
#define WS_MOM     361600    // moments, then logits partials (1M floats)
#define WS_EDGE    1541248   // 131072
#define WS_BN      1737856   // 256

#define NEGINF (-3.402823466e+38f)

typedef unsigned __int128 u128;

// ---------------------------------------------------------------------------
// Kogge-Stone occluded fill (horizontal, 128-bit row)
__device__ __forceinline__ u128 hfill(u128 g, u128 m) {
  u128 p = m;
  g |= p & (g << 1);  p &= p << 1;
  g |= p & (g << 2);  p &= p << 2;
  g |= p & (g << 4);  p &= p << 4;
  g |= p & (g << 8);  p &= p << 8;
  g |= p & (g << 16); p &= p << 16;
  g |= p & (g << 32); p &= p << 32;
  g |= p & (g << 64);
  p = m;
  g |= p & (g >> 1);  p &= p >> 1;
  g |= p & (g >> 2);  p &= p >> 2;
  g |= p & (g >> 4);  p &= p >> 4;
  g |= p & (g >> 8);  p &= p >> 8;
  g |= p & (g >> 16); p &= p >> 16;
  g |= p & (g >> 32); p &= p >> 32;
  g |= p & (g >> 64);
  return g;
}

// bilinear 64->128 sample from LDS-staged 64x64 cam (bit-identical to the
// original resize formula; deterministic, so recompute == stored value)
__device__ __forceinline__ float resamp(const float* raw, int i, int j) {
  float fy = fminf(fmaxf(0.5f * (float)i - 0.25f, 0.f), 63.f);
  float fx = fminf(fmaxf(0.5f * (float)j - 0.25f, 0.f), 63.f);
  int y0 = (int)fy; float ty = fy - (float)y0; int y1i = min(y0 + 1, 63);
  int x0 = (int)fx; float tx = fx - (float)x0; int x1i = min(x0 + 1, 63);
  float a00 = raw[y0 * 64 + x0],  a01 = raw[y0 * 64 + x1i];
  float a10 = raw[y1i * 64 + x0], a11 = raw[y1i * 64 + x1i];
  return (1.f - ty) * ((1.f - tx) * a00 + tx * a01)
       + ty * ((1.f - tx) * a10 + tx * a11);
}

// ---------------------------------------------------------------------------
// Stage-1 mega-kernel. KEY CHANGE vs r7: kernel-wide LDS cut 135KB -> 22.5KB
// (the 135KB union gave 1 WG/CU to ALL 18K blocks, strangling the BW paths
// at 920 GB/s). A-path recomputes resamp on the fly (no 64KB resized buf);
// B-path does chunked colsum (8 rows at a time). launch_bounds(256,4) caps
// VGPR at 128 (occupancy cliff) -> 4 WG/CU, 16 waves.
//   blocks 0..7    : A = locate-region on resampled cam1 -> x1,y1
//   blocks 8..15   : B = chunked colsum + box argmax on cam2 -> x2,y2
//   blocks 16..2063: prep (moments / edge), LDS-tiled
//   blocks 2064..  : feat copies, 8 float4/thread (8-deep MLP)
#define FRONT_B   8
#define PREP_BASE 16
#define COPY_BASE 2064
#define COPY_BLKS 1024       // per tensor; each block moves 2048 float4
#define STAGE1_GRID (COPY_BASE + 2 * COPY_BLKS)

__global__ __launch_bounds__(256, 4) void k_stage1(
    const float* __restrict__ cam1, const float* __restrict__ cam2,
    int* __restrict__ xy,
    const float* __restrict__ fe, const float* __restrict__ fg,
    float* __restrict__ mom, float* __restrict__ edge,
    const float4* __restrict__ f1, float4* __restrict__ o8,
    const float4* __restrict__ f2, float4* __restrict__ o9) {
  __shared__ __align__(16) float smem[5632];    // 22528 B
  int blk = blockIdx.x;
  int tid = threadIdx.x;

  if (blk >= COPY_BASE) {
    // ---------------- copy path: 8 float4 per thread, loads batched -------
    int c = blk - COPY_BASE;
    const float4* s; float4* d;
    if (c < COPY_BLKS) { s = f1; d = o8; }
    else               { s = f2; d = o9; c -= COPY_BLKS; }
    int base = c * 2048 + tid;
    float4 v0 = s[base];
    float4 v1 = s[base + 256];
    float4 v2 = s[base + 512];
    float4 v3 = s[base + 768];
    float4 v4 = s[base + 1024];
    float4 v5 = s[base + 1280];
    float4 v6 = s[base + 1536];
    float4 v7 = s[base + 1792];
    d[base]        = v0;
    d[base + 256]  = v1;
    d[base + 512]  = v2;
    d[base + 768]  = v3;
    d[base + 1024] = v4;
    d[base + 1280] = v5;
    d[base + 1536] = v6;
    d[base + 1792] = v7;
    return;
  }

  if (blk >= PREP_BASE) {
    // ---------------- prep path (moments / edge), LDS-tiled ----------------
    float* sx = smem;                           // 66*66 = 4356 floats
    int pblk = blk - PREP_BASE;
    if (pblk < 1536) {
      // moments
      int tile = pblk & 63, ch = (pblk >> 6) % 3, b = pblk / 192;
      int ti0 = (tile >> 3) * 16, tj0 = (tile & 7) * 16;
      const float* src = fe + (size_t)(b * 3 + ch) * 262144;
      int oy0 = 4 * ti0 - 1, ox0 = 4 * tj0 - 1;
      for (int l = tid; l < 66 * 66; l += 256) {
        int r = l / 66, cc = l % 66;
        int gy = oy0 + r, gx = ox0 + cc;
        sx[l] = (gy >= 0 && gy < 512 && gx >= 0 && gx < 512) ? src[gy * 512 + gx] : 0.f;
      }
      __syncthreads();
      int ii = tid >> 4, jj = tid & 15;
      int i = ti0 + ii, j = tj0 + jj;
      float s1a[6], s2a[6], s3a[6], s1b[6], s2b[6], s3b[6];
      #pragma unroll
      for (int t = 0; t < 6; ++t) {
        float a1 = 0, a2 = 0, a3 = 0, b1 = 0, b2 = 0, b3 = 0;
        int lx = 4 * jj + t;
        #pragma unroll
        for (int r = 0; r < 6; ++r) {
          float v = sx[(4 * ii + r) * 66 + lx];
          float v2 = v * v, v3 = v2 * v;
          if (r < 5) { a1 += v; a2 += v2; a3 += v3; }
          if (r > 0) { b1 += v; b2 += v2; b3 += v3; }
        }
        s1a[t] = a1; s2a[t] = a2; s3a[t] = a3;
        s1b[t] = b1; s2b[t] = b2; s3b[t] = b3;
      }
      float am = 0, av = 0, as = 0;
      #pragma unroll
      for (int py = 0; py < 2; ++py) {
        #pragma unroll
        for (int px = 0; px < 2; ++px) {
          float s1 = 0, s2 = 0, s3 = 0;
          #pragma unroll
          for (int t = 0; t < 5; ++t) {
            s1 += py ? s1b[px + t] : s1a[px + t];
            s2 += py ? s2b[px + t] : s2a[px + t];
            s3 += py ? s3b[px + t] : s3a[px + t];
          }
          float mean = s1 / 25.f;
          float var  = (s2 - 25.f * mean * mean) / 24.f;
          float m3   = (s3 - 3.f * mean * s2 + 50.f * mean * mean * mean) / 25.f;
          float sq   = sqrtf(fmaxf(var, 0.f));
          float skew = m3 / (sq * sq * sq + 1e-6f);
          am += mean; av += var; as += skew;
        }
      }
      int base = (b * 9 + ch) * N + i * 128 + j;
      mom[base]         = 0.25f * am;
      mom[base + 3 * N] = 0.25f * av;
      mom[base + 6 * N] = 0.25f * as;
    } else {
      // edge
      int eblk = pblk - 1536;
      int tile = eblk & 63, b = eblk >> 6;
      int ti0 = (tile >> 3) * 16, tj0 = (tile & 7) * 16;
      const float* s0 = fg + (size_t)b * 3 * 262144;
      int oy0 = 4 * ti0 - 1, ox0 = 4 * tj0 - 1;
      for (int l = tid; l < 66 * 66; l += 256) {
        int r = l / 66, cc = l % 66;
        int gy = oy0 + r, gx = ox0 + cc;
        float v = 0.f;
        if (gy >= 0 && gy < 512 && gx >= 0 && gx < 512) {
          int o = gy * 512 + gx;
          v = s0[o] + s0[262144 + o] + s0[524288 + o];
        }
        sx[l] = v;
      }
      __syncthreads();
      int ii = tid >> 4, jj = tid & 15;
      int i = ti0 + ii, j = tj0 + jj;
      const float INV2PI = 0.15915494309189535f;
      float wg[5], ug[5];
      #pragma unroll
      for (int t = 0; t < 5; ++t) {
        float a = (float)t - 2.f;
        float e = expf(-0.5f * a * a);
        wg[t] = e; ug[t] = -a * e;
      }
      float rAa[6], rAb[6], rBa[6], rBb[6];
      #pragma unroll
      for (int t = 0; t < 6; ++t) {
        float aa = 0, ab = 0, ba = 0, bb = 0;
        int lx = 4 * jj + t;
        #pragma unroll
        for (int r = 0; r < 6; ++r) {
          float v = sx[(4 * ii + r) * 66 + lx];
          if (r < 5) { aa += v * wg[r]; ba += v * ug[r]; }
          if (r > 0) { ab += v * wg[r - 1]; bb += v * ug[r - 1]; }
        }
        rAa[t] = aa; rAb[t] = ab; rBa[t] = ba; rBb[t] = bb;
      }
      float acc = 0.f;
      #pragma unroll
      for (int py = 0; py < 2; ++py) {
        #pragma unroll
        for (int px = 0; px < 2; ++px) {
          float h = 0, v = 0;
          #pragma unroll
          for (int t = 0; t < 5; ++t) {
            float A  = py ? rAb[px + t] : rAa[px + t];
            float Bw = py ? rBb[px + t] : rBa[px + t];
            h += A * ug[t];
            v += Bw * wg[t];
          }
          h *= INV2PI; v *= INV2PI;
          acc += tanhf(sqrtf(h * h + v * v + 1e-8f));
        }
      }
      edge[b * N + i * 128 + j] = 0.25f * acc;
    }
    return;
  }

  if (blk >= FRONT_B) {
    // ---------------- B path: chunked colsum + box argmax on cam2 --------
    // LDS: raw[0..4096) buf[4096..5120) sv[5120..5376) si[5376..5632)
    int b = blk - FRONT_B;
    float* raw = smem;
    float* buf = smem + 4096;                   // 8 x 128 colsum chunk
    float* sv  = smem + 5120;
    int*   si  = (int*)(smem + 5376);

    const float4* c4 = (const float4*)(cam2 + b * 4096);
    float4* r4 = (float4*)raw;
    #pragma unroll
    for (int k = 0; k < 4; ++k) r4[k * 256 + tid] = c4[k * 256 + tid];
    __syncthreads();

    float bv = NEGINF; int bi = 0;
    for (int r0 = 0; r0 < BV; r0 += 8) {
      int nr = min(8, BV - r0);
      // colsum rows r0..r0+nr-1 (exact dy=0..31 order -> bit-identical)
      for (int idx = tid; idx < nr * 128; idx += 256) {
        int rr = r0 + (idx >> 7), cc = idx & 127;
        float acc = 0.f;
        for (int dy = 0; dy < WIN; ++dy) acc += resamp(raw, rr + dy, cc);
        buf[idx] = acc;
      }
      __syncthreads();
      // box sums for this chunk (dx=0..31 order preserved)
      for (int q = tid; q < nr * BV; q += 256) {
        int rr = q / BV, cc = q % BV;
        float s = 0.f;
        #pragma unroll
        for (int dx = 0; dx < WIN; ++dx) s += buf[rr * 128 + cc + dx];
        if (s > bv) { bv = s; bi = (r0 + rr) * BV + cc; }
      }
      __syncthreads();
    }
    sv[tid] = bv; si[tid] = bi;
    __syncthreads();
    for (int s = 128; s; s >>= 1) {
      if (tid < s) {
        float ov = sv[tid + s]; int oi = si[tid + s];
        if (ov > sv[tid] || (ov == sv[tid] && oi < si[tid])) { sv[tid] = ov; si[tid] = oi; }
      }
      __syncthreads();
    }
    if (tid == 0) {
      xy[16 + b] = si[0] / BV + HALF;
      xy[24 + b] = si[0] % BV + HALF;
    }
    return;
  }

  // ---------------- A path: locate-region on resampled cam1 ----------------
  // LDS: raw[0..4096) sv[4096..4352) si[4352..4608) mask64[4608..5120) sint[5120..)
  {
    int b = blk;
    float* raw = smem;
    float* sv  = smem + 4096;
    int*   si  = (int*)(smem + 4352);
    unsigned long long* mask64 = (unsigned long long*)(smem + 4608); // 256 ull
    int* sint = (int*)(smem + 5120);

    const float4* c4 = (const float4*)(cam1 + b * 4096);
    float4* r4 = (float4*)raw;
    #pragma unroll
    for (int k = 0; k < 4; ++k) r4[k * 256 + tid] = c4[k * 256 + tid];
    __syncthreads();

    // argmax of resampled cam1 (values recomputed, not stored)
    float bv = NEGINF; int bi = 0;
    for (int k = 0; k < 64; ++k) {
      int pix = k * 256 + tid;
      float v1 = resamp(raw, pix >> 7, pix & 127);
      if (v1 > bv) { bv = v1; bi = pix; }
    }
    sv[tid] = bv; si[tid] = bi;
    __syncthreads();
    for (int s = 128; s; s >>= 1) {
      if (tid < s) {
        float ov = sv[tid + s]; int oi = si[tid + s];
        if (ov > sv[tid] || (ov == sv[tid] && oi < si[tid])) { sv[tid] = ov; si[tid] = oi; }
      }
      __syncthreads();
    }
    if (tid == 0) { sint[0] = si[0] >> 7; sint[1] = si[0] & 127; }
    __syncthreads();
    int s_xm = sint[0], s_ym = sint[1];

    // gradient-magnitude mask via ballot; neighbors recomputed via resamp
    for (int k = 0; k < 64; ++k) {
      int pix = k * 256 + tid;
      int i = pix >> 7, j = pix & 127;
      float gx_, gy_;
      if (i == 0)        gx_ = resamp(raw, 1, j) - resamp(raw, 0, j);
      else if (i == 127) gx_ = resamp(raw, 127, j) - resamp(raw, 126, j);
      else               gx_ = 0.5f * (resamp(raw, i + 1, j) - resamp(raw, i - 1, j));
      if (j == 0)        gy_ = resamp(raw, i, 1) - resamp(raw, i, 0);
      else if (j == 127) gy_ = resamp(raw, i, 127) - resamp(raw, i, 126);
      else               gy_ = 0.5f * (resamp(raw, i, j + 1) - resamp(raw, i, j - 1));
      bool pred = hypotf(gx_, gy_) < 0.2f;
      unsigned long long bal = __ballot(pred);
      if ((tid & 63) == 0) mask64[(i << 1) + (j >> 6)] = bal;
    }
    __syncthreads();
    if (tid == 0) {
      unsigned long long wdd = mask64[(s_xm << 1) + (s_ym >> 6)];
      sint[2] = (int)((wdd >> (s_ym & 63)) & 1ull);
    }
    __syncthreads();
    int s_ok = sint[2];

    // flood fill: single wave, 2 rows per lane, shfl vertical exchange
    if (tid < 64) {
      int l = tid;
      u128 m0 = ((u128)mask64[4 * l])     | ((u128)mask64[4 * l + 1] << 64);
      u128 m1 = ((u128)mask64[4 * l + 2]) | ((u128)mask64[4 * l + 3] << 64);
      u128 g0 = 0, g1v = 0;
      if (s_ok && (s_xm >> 1) == l) {
        if ((s_xm & 1) == 0) g0  = ((u128)1) << s_ym;
        else                 g1v = ((u128)1) << s_ym;
      }
      g0  = hfill(g0 & m0, m0);
      g1v = hfill(g1v & m1, m1);
      for (;;) {
        unsigned long long ulo = __shfl_up((unsigned long long)g1v, 1);
        unsigned long long uhi = __shfl_up((unsigned long long)(g1v >> 64), 1);
        u128 up = (l > 0) ? (((u128)ulo) | ((u128)uhi << 64)) : (u128)0;
        unsigned long long dlo = __shfl_down((unsigned long long)g0, 1);
        unsigned long long dhi = __shfl_down((unsigned long long)(g0 >> 64), 1);
        u128 dn = (l < 63) ? (((u128)dlo) | ((u128)dhi << 64)) : (u128)0;
        u128 n0 = hfill((g0 | up | g1v) & m0, m0);
        u128 n1 = hfill((g1v | n0 | dn) & m1, m1);
        bool chg = (n0 != g0) || (n1 != g1v);
        g0 = n0; g1v = n1;
        if (!__any(chg)) break;
      }
      unsigned long long be = __ballot(g0 != 0);
      unsigned long long bo = __ballot(g1v != 0);
      unsigned long long cl = (unsigned long long)(g0 | g1v);
      unsigned long long chh = (unsigned long long)((g0 | g1v) >> 64);
      for (int off = 32; off; off >>= 1) {
        cl  |= __shfl_xor(cl, off);
        chh |= __shfl_xor(chh, off);
      }
      if (l == 0) {
        int rs = 0, re = 0, cs_ = 0, ce = 0;
        if (be | bo) {
          int af = be ? (__ffsll(be) - 1) : 1000;
          int bf = bo ? (__ffsll(bo) - 1) : 1000;
          rs = min(af * 2, bf * 2 + 1);
          int al = be ? (63 - __clzll(be)) : -1000;
          int bl = bo ? (63 - __clzll(bo)) : -1000;
          re = max(al * 2, bl * 2 + 1) + 1;
          cs_ = cl ? (__ffsll(cl) - 1) : 64 + (__ffsll(chh) - 1);
          ce = chh ? 128 - __clzll(chh) : 64 - __clzll(cl);
        }
        int x1, y1;
        if (s_ok) { x1 = (rs + re) >> 1; y1 = (cs_ + ce) >> 1; }
        else      { x1 = s_xm;           y1 = s_ym; }
        xy[b] = x1; xy[8 + b] = y1;
      }
    }
  }
}

// ---------------------------------------------------------------------------
// Fused conv1 (y=0) + conv2 (y=1) + grids (x>=512, y=0)
__global__ __launch_bounds__(256) void k_conv12(
    const float* __restrict__ edge, const float* __restrict__ w1,
    const float* __restrict__ b1, float* __restrict__ o4,
    const float* __restrict__ mom, const float* __restrict__ w2,
    const float* __restrict__ b2, float* __restrict__ o5,
    const int* __restrict__ xy, float* __restrict__ g1, float* __restrict__ g2) {
  __shared__ float tin[9 * 324];
  __shared__ float wsm[64 * 84];
  int tid = threadIdx.x;

  if (blockIdx.x >= 512) {
    // ---- grids path (needs xy from stage1's A and B blocks)
    if (blockIdx.y != 0) return;
    int b = blockIdx.x - 512;
    float x1f = (float)xy[b], y1f = (float)xy[8 + b];
    float x2f = (float)xy[16 + b], y2f = (float)xy[24 + b];
    float m1x = (x1f - x2f) / 64.f, m1y = (y1f - y2f) / 64.f;
    float* g1b = g1 + (size_t)b * N * 2;
    float* g2b = g2 + (size_t)b * N * 2;
    for (int k = 0; k < 64; ++k) {
      int pix = k * 256 + tid;
      int h = pix >> 7, w = pix & 127;
      float bx = (2.f * (float)w + 1.f) / 128.f - 1.f;
      float by = (2.f * (float)h + 1.f) / 128.f - 1.f;
      g1b[pix * 2]     = bx + m1x; g1b[pix * 2 + 1] = by + m1y;
      g2b[pix * 2]     = bx - m1x; g2b[pix * 2 + 1] = by - m1y;
    }
    return;
  }

  int b = blockIdx.x >> 6, tile = blockIdx.x & 63;
  int ti0 = (tile >> 3) * 16, tj0 = (tile & 7) * 16;
  int i = tid >> 4, j = tid & 15;
  if (blockIdx.y == 0) {
    for (int l = tid; l < 324; l += 256) {
      int r = l / 18, cc = l % 18;
      int gi = ti0 + r - 1, gj = tj0 + cc - 1;
      tin[l] = (gi >= 0 && gi < 128 && gj >= 0 && gj < 128) ? edge[b * N + gi * 128 + gj] : 0.f;
    }
    for (int l = tid; l < 64 * 12; l += 256) {
      int o = l / 12, t = l % 12;
      wsm[l] = (t < 9) ? (w1[o * 27 + t] + w1[o * 27 + 9 + t] + w1[o * 27 + 18 + t]) : 0.f;
    }
    __syncthreads();
    float win[12];
    #pragma unroll
    for (int dy = 0; dy < 3; ++dy)
      #pragma unroll
      for (int dx = 0; dx < 3; ++dx)
        win[dy * 3 + dx] = tin[(i + dy) * 18 + (j + dx)];
    win[9] = 0.f; win[10] = 0.f; win[11] = 0.f;
    float* o = o4 + (size_t)b * C * N + (ti0 + i) * 128 + tj0 + j;
    for (int oc = 0; oc < C; ++oc) {
      const float4* wr = (const float4*)(wsm + oc * 12);
      float acc = b1[oc];
      #pragma unroll
      for (int q = 0; q < 3; ++q) {
        float4 w4 = wr[q];
        acc += w4.x * win[4 * q] + w4.y * win[4 * q + 1]
             + w4.z * win[4 * q + 2] + w4.w * win[4 * q + 3];
      }
      o[oc * N] = fminf(fmaxf(acc, 0.f), 6.f);
    }
  } else {
    for (int l = tid; l < 9 * 324; l += 256) {
      int ic = l / 324, rem = l % 324, r = rem / 18, cc = rem % 18;
      int gi = ti0 + r - 1, gj = tj0 + cc - 1;
      tin[l] = (gi >= 0 && gi < 128 && gj >= 0 && gj < 128) ? mom[(b * 9 + ic) * N + gi * 128 + gj] : 0.f;
    }
    for (int l = tid; l < 64 * 84; l += 256) {
      int o = l / 84, t = l % 84;
      wsm[l] = (t < 81) ? w2[o * 81 + t] : 0.f;
    }
    __syncthreads();
    float win[84];
    #pragma unroll
    for (int ic = 0; ic < 9; ++ic)
      #pragma unroll
      for (int dy = 0; dy < 3; ++dy)
        #pragma unroll
        for (int dx = 0; dx < 3; ++dx)
          win[ic * 9 + dy * 3 + dx] = tin[ic * 324 + (i + dy) * 18 + (j + dx)];
    win[81] = 0.f; win[82] = 0.f; win[83] = 0.f;
    float* o = o5 + (size_t)b * C * N + (ti0 + i) * 128 + tj0 + j;
    for (int oc = 0; oc < C; ++oc) {
      const float4* wr = (const float4*)(wsm + oc * 84);
      float acc = b2[oc];
      #pragma unroll
      for (int q = 0; q < 21; ++q) {
        float4 w4 = wr[q];
        acc += w4.x * win[4 * q] + w4.y * win[4 * q + 1]
             + w4.z * win[4 * q + 2] + w4.w * win[4 * q + 3];
      }
      o[oc * N] = acc;
    }
  }
}

// ---------------------------------------------------------------------------
// logits partial tiles (atomic-free): block (b,sl,mode) writes its own
// 64x64 partial into lg[((mode*8+b)*16+sl)*4096]. Skipped slices write 0.
__global__ __launch_bounds__(256) void k_logits(const float* __restrict__ aB1,
                                                const float* __restrict__ bB1,
                                                const float* __restrict__ aB2,
                                                const float* __restrict__ bB2,
                                                float* __restrict__ lg,
                                                const int* __restrict__ xy) {
  int mode = blockIdx.y;
  const float* aBase = mode ? aB2 : aB1;
  const float* bBase = mode ? bB2 : bB1;
  int b = blockIdx.x >> 4, sl = blockIdx.x & 15;
  int tid = threadIdx.x;
  int ci = (tid >> 4) << 2, di = (tid & 15) << 2;
  float* o = lg + (size_t)(((mode * 8 + b) * 16 + sl)) * 4096;

  int x1 = xy[b], y1 = xy[8 + b], x2 = xy[16 + b], y2 = xy[24 + b];
  int dyh, dxw, rlo, rhi, clo, chi;
  if (mode == 0) {
    dyh = y1 - y2; dxw = x1 - x2;
    rlo = max(x1 - HALF, 0); rhi = min(x1 + HALF, SIZE);
    clo = max(y1 - HALF, 0); chi = min(y1 + HALF, SIZE);
  } else {
    dyh = y2 - y1; dxw = x2 - x1;
    rlo = max(x2 - HALF, 0); rhi = min(x2 + HALF, SIZE);
    clo = max(y2 - HALF, 0); chi = min(y2 + HALF, SIZE);
  }
  int hlo = max(0, rlo - dyh), hhi = min(SIZE, rhi - dyh);
  int wlo = max(0, clo - dxw), whi = min(SIZE, chi - dxw);
  int wn = whi - wlo, hn = hhi - hlo;
  int npos = (wn > 0 && hn > 0) ? wn * hn : 0;
  if (sl * 64 >= npos) {
    #pragma unroll
    for (int u = 0; u < 4; ++u)
      #pragma unroll
      for (int v = 0; v < 4; ++v)
        o[(ci + u) * 64 + (di + v)] = 0.f;
    return;
  }

  __shared__ float aS[64][65];
  __shared__ float bS[64][65];
  const float* aB = aBase + (size_t)b * C * N;
  const float* bB = bBase + (size_t)b * C * N;
  for (int l = tid; l < 4096; l += 256) {
    int ch = l >> 6, k = l & 63;
    int p = sl * 64 + k;
    float av = 0.f, bv = 0.f;
    if (p < npos) {
      int h = hlo + p / wn, w = wlo + p % wn;
      av = aB[ch * N + (h + dyh) * 128 + (w + dxw)];
      bv = bB[ch * N + h * 128 + w];
    }
    aS[ch][k] = av; bS[ch][k] = bv;
  }
  __syncthreads();
  float acc[4][4] = {};
  #pragma unroll 4
  for (int k = 0; k < 64; ++k) {
    float a0 = aS[ci][k], a1 = aS[ci + 1][k], a2 = aS[ci + 2][k], a3 = aS[ci + 3][k];
    float b0 = bS[di][k], b1v = bS[di + 1][k], b2v = bS[di + 2][k], b3 = bS[di + 3][k];
    acc[0][0] += a0 * b0; acc[0][1] += a0 * b1v; acc[0][2] += a0 * b2v; acc[0][3] += a0 * b3;
    acc[1][0] += a1 * b0; acc[1][1] += a1 * b1v; acc[1][2] += a1 * b2v; acc[1][3] += a1 * b3;
    acc[2][0] += a2 * b0; acc[2][1] += a2 * b1v; acc[2][2] += a2 * b2v; acc[2][3] += a2 * b3;
    acc[3][0] += a3 * b0; acc[3][1] += a3 * b1v; acc[3][2] += a3 * b2v; acc[3][3] += a3 * b3;
  }
  #pragma unroll
  for (int u = 0; u < 4; ++u)
    #pragma unroll
    for (int v = 0; v < 4; ++v)
      o[(ci + u) * 64 + (di + v)] = acc[u][v];
}

// softmax over last dim (64); sums the 16 slice partials first
__global__ void k_softmax(const float* __restrict__ lg,
                          float* __restrict__ o6, float* __restrict__ o7) {
  int row = blockIdx.x;            // 0..511 = b*64+c
  int mode = blockIdx.y;
  float* dst = mode ? o7 : o6;
  int b = row >> 6, c = row & 63;
  int lane = threadIdx.x;
  const float* base = lg + (size_t)((mode * 8 + b) * 16) * 4096 + c * 64 + lane;
  float v = 0.f;
  #pragma unroll
  for (int sl = 0; sl < 16; ++sl) v += base[sl * 4096];
  float mx = v;
  for (int off = 32; off; off >>= 1) mx = fmaxf(mx, __shfl_xor(mx, off));
  float e = expf(v - mx);
  float s = e;
  for (int off = 32; off; off >>= 1) s += __shfl_xor(s, off);
  dst[row * 64 + lane] = e / s;
}

// ---------------------------------------------------------------------------
// apply (attn @ feat) fused with BN-stats partial accumulation.
__global__ __launch_bounds__(256) void k_applyst(const float* __restrict__ a1,
                                                 const float* __restrict__ s1_,
                                                 float* __restrict__ d1,
                                                 const float* __restrict__ a2,
                                                 const float* __restrict__ s2_,
                                                 float* __restrict__ d2,
                                                 float* __restrict__ bnp) {
  const float* attn; const float* src; float* dst;
  int t = blockIdx.y;
  if (t == 0) { attn = a1; src = s1_; dst = d1; }
  else        { attn = a2; src = s2_; dst = d2; }
  int b = blockIdx.x >> 6, chunk = blockIdx.x & 63;
  int n0 = chunk * 256 + threadIdx.x;
  const float* s = src + (size_t)b * C * N + n0;
  float v[64];
  #pragma unroll
  for (int d = 0; d < 64; ++d) v[d] = s[d * N];
  const float4* at4 = (const float4*)(attn + b * 4096);
  float* o = dst + (size_t)b * C * N + n0;
  __shared__ float red[64][4], red2[64][4];
  int lane = threadIdx.x & 63, wave = threadIdx.x >> 6;
  for (int c = 0; c < 64; ++c) {
    float acc = 0.f;
    #pragma unroll
    for (int q = 0; q < 16; ++q) {
      float4 w4 = at4[c * 16 + q];
      acc += w4.x * v[4 * q] + w4.y * v[4 * q + 1] + w4.z * v[4 * q + 2] + w4.w * v[4 * q + 3];
    }
    o[c * N] = acc;
    float sr = acc, ssr = acc * acc;
    for (int off = 32; off; off >>= 1) {
      sr  += __shfl_xor(sr, off);
      ssr += __shfl_xor(ssr, off);
    }
    if (lane == 0) { red[c][wave] = sr; red2[c][wave] = ssr; }
  }
  __syncthreads();
  if (threadIdx.x < 64) {
    int c = threadIdx.x;
    float sr  = red[c][0] + red[c][1] + red[c][2] + red[c][3];
    float ssr = red2[c][0] + red2[c][1] + red2[c][2] + red2[c][3];
    int idx = (t * 64 + c) * 512 + blockIdx.x;
    bnp[idx]         = sr;
    bnp[65536 + idx] = ssr;
  }
}

// fold 512 block-partials per (t,c) -> mean/rstd
__global__ void k_bnstats2(const float* __restrict__ bnp, float* __restrict__ stats) {
  __shared__ float sr[128][4], ssr[128][4];
  int tid = threadIdx.x;                       // 0..511
  int combo = tid >> 2, q = tid & 3;           // combo = t*64+c
  float s = 0.f, ss = 0.f;
  for (int k = 0; k < 128; ++k) {
    int idx = combo * 512 + q * 128 + k;
    s  += bnp[idx];
    ss += bnp[65536 + idx];
  }
  sr[combo][q] = s; ssr[combo][q] = ss;
  __syncthreads();
  if (q == 0) {
    float S  = sr[combo][0] + sr[combo][1] + sr[combo][2] + sr[combo][3];
    float SS = ssr[combo][0] + ssr[combo][1] + ssr[combo][2] + ssr[combo][3];
    int t = combo >> 6, c = combo & 63;
    float mean = S / 131072.f;
    float var  = SS / 131072.f - mean * mean;
    stats[t * 128 + c]      = mean;
    stats[t * 128 + 64 + c] = 1.f / sqrtf(var + 1e-5f);
  }
}

// ---------------------------------------------------------------------------
// BN apply only (copies live in k_stage1)
__global__ __launch_bounds__(256) void k_bnapply(
    float4* __restrict__ o0, float4* __restrict__ o1,
    const float* __restrict__ stats,
    const float* __restrict__ bw, const float* __restrict__ bb) {
  int i = blockIdx.x * 256 + threadIdx.x;       // 0..BCN/4-1
  int t = blockIdx.y;
  float4* p = t ? o1 : o0;
  int c = (i >> 12) & 63;
  float m = stats[t * 128 + c], r = stats[t * 128 + 64 + c];
  float w_ = bw[c], b_ = bb[c];
  float4 v = p[i];
  v.x = fminf(fmaxf((v.x - m) * r * w_ + b_, 0.f), 6.f);
  v.y = fminf(fmaxf((v.y - m) * r * w_ + b_, 0.f), 6.f);
  v.z = fminf(fmaxf((v.z - m) * r * w_ + b_, 0.f), 6.f);
  v.w = fminf(fmaxf((v.w - m) * r * w_ + b_, 0.f), 6.f);
  p[i] = v;
}

// ---------------------------------------------------------------------------
extern "C" void kernel_launch(void* const* d_in, const int* in_sizes, int n_in,
                              void* d_out, int out_size, void* d_ws, size_t ws_size,
                              hipStream_t stream) {
  const float* feat1   = (const float*)d_in[1];
  const float* feat2   = (const float*)d_in[2];
  const float* cam1    = (const float*)d_in[3];
  const float* cam2    = (const float*)d_in[4];
  const float* f_g     = (const float*)d_in[5];
  const float* f_e     = (const float*)d_in[6];
  const float* conv1_w = (const float*)d_in[7];
  const float* conv1_b = (const float*)d_in[8];
  const float* conv2_w = (const float*)d_in[9];
  const float* conv2_b = (const float*)d_in[10];
  const float* bn_w    = (const float*)d_in[11];
  const float* bn_b    = (const float*)d_in[12];

  float* out = (float*)d_out;
  float* w = (float*)d_ws;
  int* xy = (int*)(w + WS_XY);

  float* o0 = out + O_APPLY1;
  float* o1 = out + O_APPLY2;
  float* o2 = out + O_GRID1;
  float* o3 = out + O_GRID2;
  float* o4 = out + O_EDGEF;
  float* o5 = out + O_COLORF;
  float* o6 = out + O_ATTN1;
  float* o7 = out + O_ATTN2;
  float* o8 = out + O_FEAT1;
  float* o9 = out + O_FEAT2;

  // 1. stage1: locate-A || boxfind-B || moments+edge || feat copies
  k_stage1<<<STAGE1_GRID, 256, 0, stream>>>(
      cam1, cam2, xy,
      f_e, f_g, w + WS_MOM, w + WS_EDGE,
      (const float4*)feat1, (float4*)o8, (const float4*)feat2, (float4*)o9);

  // 2. fused conv1 + conv2 + grids
  k_conv12<<<dim3(520, 2), 256, 0, stream>>>(w + WS_EDGE, conv1_w, conv1_b, o4,
                                             w + WS_MOM, conv2_w, conv2_b, o5,
                                             xy, o2, o3);

  // 3. logits partials (atomic-free; WS_MOM is dead after conv2)
  k_logits<<<dim3(B * 16, 2), 256, 0, stream>>>(o4, feat2, o5, feat1,
                                                w + WS_MOM, xy);

  // 4. softmax (sums 16 partials per row)
  k_softmax<<<dim3(B * C, 2), 64, 0, stream>>>(w + WS_MOM, o6, o7);

  // 5. apply + bn-stats partials
  k_applyst<<<dim3(B * 64, 2), 256, 0, stream>>>(o7, feat1, o0, o6, feat2, o1,
                                                 w + WS_BNP);

  // 6. fold stats
  k_bnstats2<<<1, 512, 0, stream>>>(w + WS_BNP, w + WS_BN);

  // 7. bn apply
  k_bnapply<<<dim3(BCN / 4 / 256, 2), 256, 0, stream>>>(
      (float4*)o0, (float4*)o1, w + WS_BN, bn_w, bn_b);
}